// Round 2
// baseline (2216.578 us; speedup 1.0000x reference)
//
#include <hip/hip_runtime.h>
#include <math.h>

#define LNODES 2048
#define NEDGE 16384
#define GBIG 32
#define GSM 4
#define NCOUT 256
#define BN_EPS 1e-5f

// ---------------- setup: degree, dis, CSR ----------------

__global__ __launch_bounds__(256) void count_deg_k(const int* __restrict__ ei,
                                                   float* __restrict__ deg,
                                                   int* __restrict__ cnt) {
  int e = blockIdx.x * 256 + threadIdx.x;
  if (e < NEDGE) {
    int d = ei[NEDGE + e];
    atomicAdd(&deg[d], 1.0f);
    atomicAdd(&cnt[d], 1);
  }
}

__global__ __launch_bounds__(256) void dis_k(const float* __restrict__ deg,
                                             float* __restrict__ dis,
                                             float* __restrict__ selfn) {
  int i = blockIdx.x * 256 + threadIdx.x;
  if (i < LNODES) {
    float di = rsqrtf(deg[i] + 2.0f);  // improved=True: +2 self loop, always > 0
    dis[i] = di;
    selfn[i] = 2.0f * di * di;
  }
}

// single block: exclusive prefix over 2048 per-node counts -> row_ptr[0..2048]
__global__ __launch_bounds__(256) void scan_k(const int* __restrict__ cnt,
                                              int* __restrict__ rp) {
  __shared__ int part[256];
  int t = threadIdx.x;
  int base = t * 8;
  int loc[8];
  int s = 0;
#pragma unroll
  for (int j = 0; j < 8; ++j) { loc[j] = s; s += cnt[base + j]; }
  part[t] = s;
  __syncthreads();
  for (int off = 1; off < 256; off <<= 1) {
    int v = (t >= off) ? part[t - off] : 0;
    __syncthreads();
    part[t] += v;
    __syncthreads();
  }
  int excl = (t == 0) ? 0 : part[t - 1];
#pragma unroll
  for (int j = 0; j < 8; ++j) rp[base + j] = excl + loc[j];
  if (t == 255) rp[LNODES] = part[255];
}

__global__ __launch_bounds__(256) void fill_k(const int* __restrict__ ei,
                                              const int* __restrict__ rp,
                                              int* __restrict__ fillc,
                                              const float* __restrict__ dis,
                                              int* __restrict__ col,
                                              float* __restrict__ wn) {
  int e = blockIdx.x * 256 + threadIdx.x;
  if (e < NEDGE) {
    int s = ei[e], d = ei[NEDGE + e];
    int pos = rp[d] + atomicAdd(&fillc[d], 1);
    col[pos] = s;
    wn[pos] = dis[s] * dis[d];
  }
}

// ---------------- max-pool over N=8 ----------------
// X: [4, 8, Cin, L] -> XP: [4, Cin, L], float4 per thread
__global__ __launch_bounds__(256) void pool_k(const float* __restrict__ X,
                                              float* __restrict__ XP, int Cin) {
  int i = blockIdx.x * 256 + threadIdx.x;
  int per = Cin * LNODES;
  int total4 = GSM * per / 4;
  if (i >= total4) return;
  int f = i * 4;
  int b = f / per;
  int rem = f - b * per;
  const float* base = X + (size_t)b * 8 * per + rem;
  float4 m = *reinterpret_cast<const float4*>(base);
#pragma unroll
  for (int j = 1; j < 8; ++j) {
    float4 v = *reinterpret_cast<const float4*>(base + (size_t)j * per);
    m.x = fmaxf(m.x, v.x); m.y = fmaxf(m.y, v.y);
    m.z = fmaxf(m.z, v.z); m.w = fmaxf(m.w, v.w);
  }
  *reinterpret_cast<float4*>(XP + (size_t)b * per + rem) = m;
}

// ---------------- fp32 GEMM: C[g,co,n] = sum_ci X[g,ci,n] * W[ci,co] ----------------
// grid (L/64, Cout/64, G), 256 threads, 4x4 per-thread tile, BK=16
__global__ __launch_bounds__(256) void gemm_k(const float* __restrict__ X,
                                              const float* __restrict__ W,
                                              float* __restrict__ C,
                                              int Cin, int Cout) {
  __shared__ float Wsh[16][64];  // [k][co]
  __shared__ float Xsh[16][64];  // [k][n]
  const int g = blockIdx.z;
  const int co0 = blockIdx.y * 64;
  const int n0 = blockIdx.x * 64;
  const int tid = threadIdx.x;
  const int tm = (tid & 15) * 4;  // co offset within tile
  const int tn = (tid >> 4) * 4;  // n offset within tile
  float acc[4][4] = {};
  const float* Xg = X + (size_t)g * Cin * LNODES;
  const int li = tid * 4;
  const int lk = li >> 6;   // 0..15
  const int lc = li & 63;   // 0..63, multiple of 4
  for (int k0 = 0; k0 < Cin; k0 += 16) {
    *reinterpret_cast<float4*>(&Wsh[lk][lc]) =
        *reinterpret_cast<const float4*>(&W[(size_t)(k0 + lk) * Cout + co0 + lc]);
    *reinterpret_cast<float4*>(&Xsh[lk][lc]) =
        *reinterpret_cast<const float4*>(&Xg[(size_t)(k0 + lk) * LNODES + n0 + lc]);
    __syncthreads();
#pragma unroll
    for (int k = 0; k < 16; ++k) {
      float4 a = *reinterpret_cast<const float4*>(&Wsh[k][tm]);
      float4 b = *reinterpret_cast<const float4*>(&Xsh[k][tn]);
      float av[4] = {a.x, a.y, a.z, a.w};
      float bv[4] = {b.x, b.y, b.z, b.w};
#pragma unroll
      for (int i = 0; i < 4; ++i)
#pragma unroll
        for (int j = 0; j < 4; ++j) acc[i][j] += av[i] * bv[j];
    }
    __syncthreads();
  }
#pragma unroll
  for (int i = 0; i < 4; ++i) {
    float4 r = {acc[i][0], acc[i][1], acc[i][2], acc[i][3]};
    *reinterpret_cast<float4*>(&C[((size_t)g * Cout + co0 + tm + i) * LNODES + n0 + tn]) = r;
  }
}

// ---------------- GCN aggregation (gather by dst via CSR) ----------------
// AGG[g,co,d] = selfn[d]*HW[g,co,d] + sum_e wn[e]*HW[g,co,col[e]]
// grid (L/256, Cout, G)
__global__ __launch_bounds__(256) void agg_k(const float* __restrict__ HW,
                                             const int* __restrict__ col,
                                             const float* __restrict__ wn,
                                             const int* __restrict__ rp,
                                             const float* __restrict__ selfn,
                                             float* __restrict__ AGG, int Cout) {
  int d = blockIdx.x * 256 + threadIdx.x;
  int co = blockIdx.y;
  int g = blockIdx.z;
  const float* row = HW + ((size_t)g * Cout + co) * LNODES;
  int e0 = rp[d], e1 = rp[d + 1];
  float s = selfn[d] * row[d];
  for (int e = e0; e < e1; ++e) s += wn[e] * row[col[e]];
  AGG[((size_t)g * Cout + co) * LNODES + d] = s;
}

// ---------------- BN statistics ----------------
// grid (Cout, G): one block reduces one [g,co] row, atomics combine over g
__global__ __launch_bounds__(256) void bnstat_k(const float* __restrict__ Xv,
                                                float* __restrict__ sum,
                                                float* __restrict__ sq, int Cout) {
  int co = blockIdx.x;
  int g = blockIdx.y;
  const float* row = Xv + ((size_t)g * Cout + co) * LNODES;
  float s = 0.f, q = 0.f;
  for (int n = threadIdx.x; n < LNODES; n += 256) {
    float v = row[n];
    s += v;
    q += v * v;
  }
  __shared__ float ss[256], qq[256];
  ss[threadIdx.x] = s; qq[threadIdx.x] = q;
  __syncthreads();
  for (int off = 128; off > 0; off >>= 1) {
    if (threadIdx.x < off) {
      ss[threadIdx.x] += ss[threadIdx.x + off];
      qq[threadIdx.x] += qq[threadIdx.x + off];
    }
    __syncthreads();
  }
  if (threadIdx.x == 0) {
    atomicAdd(&sum[co], ss[0]);
    atomicAdd(&sq[co], qq[0]);
  }
}

__global__ __launch_bounds__(256) void bnfinal_k(const float* __restrict__ sum1,
                                                 const float* __restrict__ sq1,
                                                 const float* __restrict__ sum2,
                                                 const float* __restrict__ sq2,
                                                 float* __restrict__ m1, float* __restrict__ r1,
                                                 float* __restrict__ m2, float* __restrict__ r2) {
  int co = threadIdx.x;  // 256 threads
  const float c1 = (float)(GBIG * LNODES), c2 = (float)(GSM * LNODES);
  float mA = sum1[co] / c1;
  float vA = sq1[co] / c1 - mA * mA;
  m1[co] = mA;
  r1[co] = rsqrtf(vA + BN_EPS);
  float mB = sum2[co] / c2;
  float vB = sq2[co] / c2 - mB * mB;
  m2[co] = mB;
  r2[co] = rsqrtf(vB + BN_EPS);
}

// ---------------- fused BN-apply + BN-apply + add + ReLU ----------------
// O[g,co,n] = relu( ga*r1*(A1-m1)+be  +  gs*r2*(A2[b]-m2)+bes ), b = g/8
__global__ __launch_bounds__(256) void fuse_k(const float* __restrict__ A1,
                                              const float* __restrict__ A2,
                                              const float* __restrict__ m1, const float* __restrict__ r1,
                                              const float* __restrict__ m2, const float* __restrict__ r2,
                                              const float* __restrict__ ga, const float* __restrict__ be,
                                              const float* __restrict__ gs, const float* __restrict__ bes,
                                              float* __restrict__ O) {
  size_t i = (size_t)blockIdx.x * 256 + threadIdx.x;
  size_t f = i * 4;  // total = 32*256*2048
  int g = (int)(f / ((size_t)NCOUT * LNODES));
  int co = (int)((f / LNODES) % NCOUT);
  int n = (int)(f % LNODES);
  int b = g >> 3;
  float4 a1 = *reinterpret_cast<const float4*>(A1 + f);
  float4 a2 = *reinterpret_cast<const float4*>(A2 + ((size_t)b * NCOUT + co) * LNODES + n);
  float k1 = ga[co] * r1[co];
  float c1 = be[co] - k1 * m1[co];
  float k2 = gs[co] * r2[co];
  float c2 = bes[co] - k2 * m2[co] + c1;
  float4 o;
  o.x = fmaxf(k1 * a1.x + k2 * a2.x + c2, 0.f);
  o.y = fmaxf(k1 * a1.y + k2 * a2.y + c2, 0.f);
  o.z = fmaxf(k1 * a1.z + k2 * a2.z + c2, 0.f);
  o.w = fmaxf(k1 * a1.w + k2 * a2.w + c2, 0.f);
  *reinterpret_cast<float4*>(O + f) = o;
}

// ---------------- launch ----------------

extern "C" void kernel_launch(void* const* d_in, const int* in_sizes, int n_in,
                              void* d_out, int out_size, void* d_ws, size_t ws_size,
                              hipStream_t stream) {
  const float* x_in = (const float*)d_in[0];
  const int* ei = (const int*)d_in[1];
  const float* W[3]   = {(const float*)d_in[2],  (const float*)d_in[4],  (const float*)d_in[6]};
  const float* Wsym[3]= {(const float*)d_in[8],  (const float*)d_in[10], (const float*)d_in[12]};
  const float* ga[3]  = {(const float*)d_in[14], (const float*)d_in[16], (const float*)d_in[18]};
  const float* be[3]  = {(const float*)d_in[15], (const float*)d_in[17], (const float*)d_in[19]};
  const float* gs[3]  = {(const float*)d_in[20], (const float*)d_in[22], (const float*)d_in[24]};
  const float* bes[3] = {(const float*)d_in[21], (const float*)d_in[23], (const float*)d_in[25]};

  const size_t SBIG = (size_t)GBIG * NCOUT * LNODES * sizeof(float);  // 64 MiB
  const size_t SP = (size_t)GSM * NCOUT * LNODES * sizeof(float);     // 8 MiB
  // bufA aliases d_out (exactly SBIG bytes); rotation ensures d_out's final
  // writer is the layer-2 fuse. Workspace demand drops to ~90 MiB.
  float* bufA = (float*)d_out;
  char* p = (char*)d_ws;
  float* bufB = (float*)p; p += SBIG;
  float* xp   = (float*)p; p += SP;
  float* hw2  = (float*)p; p += SP;
  float* agg2 = (float*)p; p += SP;
  int*   col  = (int*)p;   p += NEDGE * 4;
  float* wn   = (float*)p; p += NEDGE * 4;
  int*   rp   = (int*)p;   p += 2064 * 4;
  float* dis  = (float*)p; p += LNODES * 4;
  float* selfn= (float*)p; p += LNODES * 4;
  char* zbase = p;
  float* deg  = (float*)p; p += LNODES * 4;
  int*   cnt  = (int*)p;   p += LNODES * 4;
  int*   fillc= (int*)p;   p += LNODES * 4;
  size_t zsize = (size_t)(p - zbase);
  char* statbase = p;
  float* sum1 = (float*)p; p += 1024;
  float* sq1  = (float*)p; p += 1024;
  float* sum2 = (float*)p; p += 1024;
  float* sq2  = (float*)p; p += 1024;
  float* m1 = (float*)p; p += 1024;
  float* r1 = (float*)p; p += 1024;
  float* m2 = (float*)p; p += 1024;
  float* r2 = (float*)p; p += 1024;

  // ---- graph setup (recomputed every call; ws is re-poisoned) ----
  hipMemsetAsync(zbase, 0, zsize, stream);
  count_deg_k<<<NEDGE / 256, 256, 0, stream>>>(ei, deg, cnt);
  dis_k<<<LNODES / 256, 256, 0, stream>>>(deg, dis, selfn);
  scan_k<<<1, 256, 0, stream>>>(cnt, rp);
  fill_k<<<NEDGE / 256, 256, 0, stream>>>(ei, rp, fillc, dis, col, wn);

  // ping-pong: layer0 x=d_in, hw->A, agg->B, out->A; layer1 x=A, hw->B, agg->A, out->B;
  // layer2 x=B, hw->A, agg->B, out->d_out(=A)
  const float* xs[3]  = {x_in, bufA, bufB};
  float* hw1p[3] = {bufA, bufB, bufA};
  float* agg1p[3]= {bufB, bufA, bufB};
  float* outp[3] = {bufA, bufB, (float*)d_out};

  for (int l = 0; l < 3; ++l) {
    const int Cin = (l == 0) ? 128 : 256;
    // pooled branch: max over N, then GEMM
    int npool4 = GSM * Cin * LNODES / 4;
    pool_k<<<npool4 / 256, 256, 0, stream>>>(xs[l], xp, Cin);
    dim3 gg2(LNODES / 64, NCOUT / 64, GSM);
    gemm_k<<<gg2, 256, 0, stream>>>(xp, Wsym[l], hw2, Cin, NCOUT);
    // per-element branch GEMM
    dim3 gg1(LNODES / 64, NCOUT / 64, GBIG);
    gemm_k<<<gg1, 256, 0, stream>>>(xs[l], W[l], hw1p[l], Cin, NCOUT);
    // aggregations (bias skipped: cancels in training-mode BN)
    dim3 ag1(LNODES / 256, NCOUT, GBIG);
    agg_k<<<ag1, 256, 0, stream>>>(hw1p[l], col, wn, rp, selfn, agg1p[l], NCOUT);
    dim3 ag2(LNODES / 256, NCOUT, GSM);
    agg_k<<<ag2, 256, 0, stream>>>(hw2, col, wn, rp, selfn, agg2, NCOUT);
    // BN stats
    hipMemsetAsync(statbase, 0, 4096, stream);
    bnstat_k<<<dim3(NCOUT, GBIG), 256, 0, stream>>>(agg1p[l], sum1, sq1, NCOUT);
    bnstat_k<<<dim3(NCOUT, GSM), 256, 0, stream>>>(agg2, sum2, sq2, NCOUT);
    bnfinal_k<<<1, 256, 0, stream>>>(sum1, sq1, sum2, sq2, m1, r1, m2, r2);
    // fused BN + BN + add + ReLU
    int nf = (GBIG * NCOUT * LNODES / 4) / 256;
    fuse_k<<<nf, 256, 0, stream>>>(agg1p[l], agg2, m1, r1, m2, r2,
                                   ga[l], be[l], gs[l], bes[l], outp[l]);
  }
}

// Round 3
// 1216.090 us; speedup vs baseline: 1.8227x; 1.8227x over previous
//
#include <hip/hip_runtime.h>
#include <math.h>

#define LNODES 2048
#define NEDGE 16384
#define GBIG 32
#define GSM 4
#define NCOUT 256
#define BN_EPS 1e-5f
#define ND 32  // dst nodes per agg block

// ---------------- setup: degree, dis, CSR ----------------

__global__ __launch_bounds__(256) void count_deg_k(const int* __restrict__ ei,
                                                   float* __restrict__ deg,
                                                   int* __restrict__ cnt) {
  int e = blockIdx.x * 256 + threadIdx.x;
  if (e < NEDGE) {
    int d = ei[NEDGE + e];
    atomicAdd(&deg[d], 1.0f);
    atomicAdd(&cnt[d], 1);
  }
}

__global__ __launch_bounds__(256) void dis_k(const float* __restrict__ deg,
                                             float* __restrict__ dis,
                                             float* __restrict__ selfn) {
  int i = blockIdx.x * 256 + threadIdx.x;
  if (i < LNODES) {
    float di = rsqrtf(deg[i] + 2.0f);  // improved=True: +2 self loop, always > 0
    dis[i] = di;
    selfn[i] = 2.0f * di * di;
  }
}

// single block: exclusive prefix over 2048 per-node counts -> row_ptr[0..2048]
__global__ __launch_bounds__(256) void scan_k(const int* __restrict__ cnt,
                                              int* __restrict__ rp) {
  __shared__ int part[256];
  int t = threadIdx.x;
  int base = t * 8;
  int loc[8];
  int s = 0;
#pragma unroll
  for (int j = 0; j < 8; ++j) { loc[j] = s; s += cnt[base + j]; }
  part[t] = s;
  __syncthreads();
  for (int off = 1; off < 256; off <<= 1) {
    int v = (t >= off) ? part[t - off] : 0;
    __syncthreads();
    part[t] += v;
    __syncthreads();
  }
  int excl = (t == 0) ? 0 : part[t - 1];
#pragma unroll
  for (int j = 0; j < 8; ++j) rp[base + j] = excl + loc[j];
  if (t == 255) rp[LNODES] = part[255];
}

__global__ __launch_bounds__(256) void fill_k(const int* __restrict__ ei,
                                              const int* __restrict__ rp,
                                              int* __restrict__ fillc,
                                              const float* __restrict__ dis,
                                              int* __restrict__ col,
                                              float* __restrict__ wn) {
  int e = blockIdx.x * 256 + threadIdx.x;
  if (e < NEDGE) {
    int s = ei[e], d = ei[NEDGE + e];
    int pos = rp[d] + atomicAdd(&fillc[d], 1);
    col[pos] = s;
    wn[pos] = dis[s] * dis[d];
  }
}

// ---------------- max-pool over N=8 (layout-agnostic: flat [G, 8, per]) ----------------
__global__ __launch_bounds__(256) void pool_k(const float* __restrict__ X,
                                              float* __restrict__ XP, int per) {
  int i = blockIdx.x * 256 + threadIdx.x;
  int total4 = GSM * per / 4;
  if (i >= total4) return;
  int f = i * 4;
  int b = f / per;
  int rem = f - b * per;
  const float* base = X + (size_t)b * 8 * per + rem;
  float4 m = *reinterpret_cast<const float4*>(base);
#pragma unroll
  for (int j = 1; j < 8; ++j) {
    float4 v = *reinterpret_cast<const float4*>(base + (size_t)j * per);
    m.x = fmaxf(m.x, v.x); m.y = fmaxf(m.y, v.y);
    m.z = fmaxf(m.z, v.z); m.w = fmaxf(m.w, v.w);
  }
  *reinterpret_cast<float4*>(XP + (size_t)b * per + rem) = m;
}

// ---------------- fp32 GEMM, node-major output ----------------
// C[g, node, co] = sum_ci A[node, ci] * W[ci, co]
// A: TRANSA=1 -> X[g, ci, node] (channel-major input); TRANSA=0 -> X[g, node, ci]
// grid (L/64, Cout/64, G), 256 threads, 4x4 per-thread tile, BK=16
template <int TRANSA>
__global__ __launch_bounds__(256) void gemm_nm_k(const float* __restrict__ X,
                                                 const float* __restrict__ W,
                                                 float* __restrict__ C, int Cin) {
  __shared__ float Ash[16][68];  // [k][node], +4 pad keeps stores 2-way max
  __shared__ float Bsh[16][64];  // [k][co]
  const int g = blockIdx.z;
  const int n0 = blockIdx.x * 64;  // node
  const int c0 = blockIdx.y * 64;  // co
  const int tid = threadIdx.x;
  const int tco = (tid & 15) * 4;  // co offset
  const int tnd = (tid >> 4) * 4;  // node offset
  float acc[4][4] = {};            // [node_i][co_j]
  const float* Xg = X + (size_t)g * Cin * LNODES;
  const int wl_k = tid >> 4;        // 0..15
  const int wl_c = (tid & 15) * 4;  // 0..60
  for (int k0 = 0; k0 < Cin; k0 += 16) {
    *reinterpret_cast<float4*>(&Bsh[wl_k][wl_c]) =
        *reinterpret_cast<const float4*>(&W[(size_t)(k0 + wl_k) * NCOUT + c0 + wl_c]);
    if (TRANSA) {
      *reinterpret_cast<float4*>(&Ash[wl_k][wl_c]) =
          *reinterpret_cast<const float4*>(&Xg[(size_t)(k0 + wl_k) * LNODES + n0 + wl_c]);
    } else {
      int an = tid >> 2;         // 0..63 node
      int ak = (tid & 3) * 4;    // 0..12 k
      float4 v = *reinterpret_cast<const float4*>(&Xg[(size_t)(n0 + an) * Cin + k0 + ak]);
      Ash[ak + 0][an] = v.x; Ash[ak + 1][an] = v.y;
      Ash[ak + 2][an] = v.z; Ash[ak + 3][an] = v.w;
    }
    __syncthreads();
#pragma unroll
    for (int k = 0; k < 16; ++k) {
      float4 a = *reinterpret_cast<const float4*>(&Ash[k][tnd]);
      float4 b = *reinterpret_cast<const float4*>(&Bsh[k][tco]);
      float av[4] = {a.x, a.y, a.z, a.w};
      float bv[4] = {b.x, b.y, b.z, b.w};
#pragma unroll
      for (int i = 0; i < 4; ++i)
#pragma unroll
        for (int j = 0; j < 4; ++j) acc[i][j] += av[i] * bv[j];
    }
    __syncthreads();
  }
#pragma unroll
  for (int i = 0; i < 4; ++i) {
    float4 r = {acc[i][0], acc[i][1], acc[i][2], acc[i][3]};
    *reinterpret_cast<float4*>(&C[((size_t)g * LNODES + n0 + tnd + i) * NCOUT + c0 + tco]) = r;
  }
}

// ---------------- GCN aggregation, node-major, fused BN statistics ----------------
// AGG[g,d,co] = selfn[d]*HW[g,d,co] + sum_e wn[e]*HW[g,col[e],co]
// thread = channel co; block covers ND dsts; coalesced 1KB vector per edge.
// Per-thread BN partials (s, q) accumulated over ND dsts -> 1 atomicAdd each.
// grid (L/ND, G)
__global__ __launch_bounds__(256) void agg_nm_k(const float* __restrict__ HW,
                                                const int* __restrict__ col,
                                                const float* __restrict__ wn,
                                                const int* __restrict__ rp,
                                                const float* __restrict__ selfn,
                                                float* __restrict__ AGG,
                                                float* __restrict__ sum,
                                                float* __restrict__ sq) {
  const int g = blockIdx.y;
  const int d0 = blockIdx.x * ND;
  const int t = threadIdx.x;  // channel
  const float* base = HW + (size_t)g * LNODES * NCOUT;
  float s = 0.f, q = 0.f;
  for (int i = 0; i < ND; ++i) {
    int d = d0 + i;
    int e0 = rp[d], e1 = rp[d + 1];
    float acc = selfn[d] * base[(size_t)d * NCOUT + t];
    for (int e = e0; e < e1; ++e)
      acc += wn[e] * base[(size_t)col[e] * NCOUT + t];
    AGG[((size_t)g * LNODES + d) * NCOUT + t] = acc;
    s += acc;
    q += acc * acc;
  }
  atomicAdd(&sum[t], s);
  atomicAdd(&sq[t], q);
}

// ---------------- BN finalize: per-channel k1, k2, combined constant cc ----------------
__global__ __launch_bounds__(256) void bnfinal_k(const float* __restrict__ sum1,
                                                 const float* __restrict__ sq1,
                                                 const float* __restrict__ sum2,
                                                 const float* __restrict__ sq2,
                                                 const float* __restrict__ ga,
                                                 const float* __restrict__ be,
                                                 const float* __restrict__ gs,
                                                 const float* __restrict__ bes,
                                                 float* __restrict__ k1,
                                                 float* __restrict__ k2,
                                                 float* __restrict__ cc) {
  int co = threadIdx.x;  // 256 threads
  const float c1 = (float)(GBIG * LNODES), c2 = (float)(GSM * LNODES);
  float mA = sum1[co] / c1;
  float vA = sq1[co] / c1 - mA * mA;
  float kA = ga[co] * rsqrtf(vA + BN_EPS);
  float mB = sum2[co] / c2;
  float vB = sq2[co] / c2 - mB * mB;
  float kB = gs[co] * rsqrtf(vB + BN_EPS);
  k1[co] = kA;
  k2[co] = kB;
  cc[co] = be[co] - kA * mA + bes[co] - kB * mB;
}

// ---------------- fused BN+BN+add+ReLU, node-major output (layers 0,1) ----------------
__global__ __launch_bounds__(256) void fuse_nm_k(const float* __restrict__ A1,
                                                 const float* __restrict__ A2,
                                                 const float* __restrict__ k1,
                                                 const float* __restrict__ k2,
                                                 const float* __restrict__ cc,
                                                 float* __restrict__ O) {
  size_t i = (size_t)blockIdx.x * 256 + threadIdx.x;
  size_t f = i * 4;  // total = 32*2048*256
  int co = (int)(f & (NCOUT - 1));
  int d = (int)((f >> 8) & (LNODES - 1));
  int g = (int)(f >> 19);
  int b = g >> 3;
  float4 a1 = *reinterpret_cast<const float4*>(A1 + f);
  float4 a2 = *reinterpret_cast<const float4*>(A2 + ((size_t)b * LNODES + d) * NCOUT + co);
  float4 K1 = *reinterpret_cast<const float4*>(k1 + co);
  float4 K2 = *reinterpret_cast<const float4*>(k2 + co);
  float4 CC = *reinterpret_cast<const float4*>(cc + co);
  float4 o;
  o.x = fmaxf(K1.x * a1.x + K2.x * a2.x + CC.x, 0.f);
  o.y = fmaxf(K1.y * a1.y + K2.y * a2.y + CC.y, 0.f);
  o.z = fmaxf(K1.z * a1.z + K2.z * a2.z + CC.z, 0.f);
  o.w = fmaxf(K1.w * a1.w + K2.w * a2.w + CC.w, 0.f);
  *reinterpret_cast<float4*>(O + f) = o;
}

// ---------------- fused BN+BN+add+ReLU + transpose to channel-major (layer 2) ----------------
// O[g, co, d] from A1/A2 node-major, via LDS 64x64 tile. grid (L/64, 256/64, G)
__global__ __launch_bounds__(256) void fuse_tr_k(const float* __restrict__ A1,
                                                 const float* __restrict__ A2,
                                                 const float* __restrict__ k1,
                                                 const float* __restrict__ k2,
                                                 const float* __restrict__ cc,
                                                 float* __restrict__ O) {
  __shared__ float T[64][65];
  const int g = blockIdx.z;
  const int d0 = blockIdx.x * 64;
  const int c0 = blockIdx.y * 64;
  const int b = g >> 3;
  const int tr = threadIdx.x >> 4;        // 0..15
  const int tc = (threadIdx.x & 15) * 4;  // 0..60
  float4 K1 = *reinterpret_cast<const float4*>(k1 + c0 + tc);
  float4 K2 = *reinterpret_cast<const float4*>(k2 + c0 + tc);
  float4 CC = *reinterpret_cast<const float4*>(cc + c0 + tc);
#pragma unroll
  for (int p = 0; p < 4; ++p) {
    int d = d0 + tr + p * 16;
    float4 a1 = *reinterpret_cast<const float4*>(&A1[((size_t)g * LNODES + d) * NCOUT + c0 + tc]);
    float4 a2 = *reinterpret_cast<const float4*>(&A2[((size_t)b * LNODES + d) * NCOUT + c0 + tc]);
    T[tr + p * 16][tc + 0] = fmaxf(K1.x * a1.x + K2.x * a2.x + CC.x, 0.f);
    T[tr + p * 16][tc + 1] = fmaxf(K1.y * a1.y + K2.y * a2.y + CC.y, 0.f);
    T[tr + p * 16][tc + 2] = fmaxf(K1.z * a1.z + K2.z * a2.z + CC.z, 0.f);
    T[tr + p * 16][tc + 3] = fmaxf(K1.w * a1.w + K2.w * a2.w + CC.w, 0.f);
  }
  __syncthreads();
#pragma unroll
  for (int p = 0; p < 4; ++p) {
    int c = tr + p * 16;
    float4 o = {T[tc + 0][c], T[tc + 1][c], T[tc + 2][c], T[tc + 3][c]};
    *reinterpret_cast<float4*>(&O[((size_t)g * NCOUT + c0 + c) * LNODES + d0 + tc]) = o;
  }
}

// ---------------- launch ----------------

extern "C" void kernel_launch(void* const* d_in, const int* in_sizes, int n_in,
                              void* d_out, int out_size, void* d_ws, size_t ws_size,
                              hipStream_t stream) {
  const float* x_in = (const float*)d_in[0];
  const int* ei = (const int*)d_in[1];
  const float* W[3]   = {(const float*)d_in[2],  (const float*)d_in[4],  (const float*)d_in[6]};
  const float* Wsym[3]= {(const float*)d_in[8],  (const float*)d_in[10], (const float*)d_in[12]};
  const float* ga[3]  = {(const float*)d_in[14], (const float*)d_in[16], (const float*)d_in[18]};
  const float* be[3]  = {(const float*)d_in[15], (const float*)d_in[17], (const float*)d_in[19]};
  const float* gs[3]  = {(const float*)d_in[20], (const float*)d_in[22], (const float*)d_in[24]};
  const float* bes[3] = {(const float*)d_in[21], (const float*)d_in[23], (const float*)d_in[25]};

  const size_t SBIG = (size_t)GBIG * NCOUT * LNODES * sizeof(float);  // 64 MiB
  const size_t SP = (size_t)GSM * NCOUT * LNODES * sizeof(float);     // 8 MiB
  // bufA aliases d_out (exactly SBIG); rotation guarantees d_out's final writer
  // is the layer-2 fuse_tr.
  float* bufA = (float*)d_out;
  char* p = (char*)d_ws;
  float* bufB = (float*)p; p += SBIG;
  float* xp   = (float*)p; p += SP;
  float* hw2  = (float*)p; p += SP;
  float* agg2 = (float*)p; p += SP;
  int*   col  = (int*)p;   p += NEDGE * 4;
  float* wn   = (float*)p; p += NEDGE * 4;
  int*   rp   = (int*)p;   p += 2064 * 4;
  float* dis  = (float*)p; p += LNODES * 4;
  float* selfn= (float*)p; p += LNODES * 4;
  char* zbase = p;
  float* deg  = (float*)p; p += LNODES * 4;
  int*   cnt  = (int*)p;   p += LNODES * 4;
  int*   fillc= (int*)p;   p += LNODES * 4;
  size_t zsize = (size_t)(p - zbase);
  char* statbase = p;
  float* sum1 = (float*)p; p += 1024;
  float* sq1  = (float*)p; p += 1024;
  float* sum2 = (float*)p; p += 1024;
  float* sq2  = (float*)p; p += 1024;
  float* k1 = (float*)p; p += 1024;
  float* k2 = (float*)p; p += 1024;
  float* cc = (float*)p; p += 1024;

  // ---- graph setup (recomputed every call; ws is re-poisoned) ----
  hipMemsetAsync(zbase, 0, zsize, stream);
  count_deg_k<<<NEDGE / 256, 256, 0, stream>>>(ei, deg, cnt);
  dis_k<<<LNODES / 256, 256, 0, stream>>>(deg, dis, selfn);
  scan_k<<<1, 256, 0, stream>>>(cnt, rp);
  fill_k<<<NEDGE / 256, 256, 0, stream>>>(ei, rp, fillc, dis, col, wn);

  // ping-pong (all node-major internally):
  // layer0 x=d_in(ch-major), hw->A, agg->B, out->A
  // layer1 x=A, hw->B, agg->A, out->B
  // layer2 x=B, hw->A, agg->B, fuse_tr->d_out(=A)
  const float* xs[3]  = {x_in, bufA, bufB};
  float* hw1p[3] = {bufA, bufB, bufA};
  float* agg1p[3]= {bufB, bufA, bufB};
  float* outp[3] = {bufA, bufB, (float*)d_out};

  dim3 gemm_grid_big(LNODES / 64, NCOUT / 64, GBIG);
  dim3 gemm_grid_sm(LNODES / 64, NCOUT / 64, GSM);
  dim3 agg_grid_big(LNODES / ND, GBIG);
  dim3 agg_grid_sm(LNODES / ND, GSM);

  for (int l = 0; l < 3; ++l) {
    const int Cin = (l == 0) ? 128 : 256;
    // pooled branch: max over N (layout-agnostic), then GEMM
    int npool4 = GSM * Cin * LNODES / 4;
    pool_k<<<npool4 / 256, 256, 0, stream>>>(xs[l], xp, Cin * LNODES);
    if (l == 0) {
      gemm_nm_k<1><<<gemm_grid_sm, 256, 0, stream>>>(xp, Wsym[l], hw2, Cin);
      gemm_nm_k<1><<<gemm_grid_big, 256, 0, stream>>>(xs[l], W[l], hw1p[l], Cin);
    } else {
      gemm_nm_k<0><<<gemm_grid_sm, 256, 0, stream>>>(xp, Wsym[l], hw2, Cin);
      gemm_nm_k<0><<<gemm_grid_big, 256, 0, stream>>>(xs[l], W[l], hw1p[l], Cin);
    }
    // BN stats are fused into agg; zero them first
    hipMemsetAsync(statbase, 0, 4096, stream);
    agg_nm_k<<<agg_grid_big, 256, 0, stream>>>(hw1p[l], col, wn, rp, selfn,
                                               agg1p[l], sum1, sq1);
    agg_nm_k<<<agg_grid_sm, 256, 0, stream>>>(hw2, col, wn, rp, selfn,
                                              agg2, sum2, sq2);
    bnfinal_k<<<1, 256, 0, stream>>>(sum1, sq1, sum2, sq2,
                                     ga[l], be[l], gs[l], bes[l], k1, k2, cc);
    if (l < 2) {
      int nf = (GBIG * NCOUT * LNODES / 4) / 256;
      fuse_nm_k<<<nf, 256, 0, stream>>>(agg1p[l], agg2, k1, k2, cc, outp[l]);
    } else {
      dim3 ft(LNODES / 64, NCOUT / 64, GBIG);
      fuse_tr_k<<<ft, 256, 0, stream>>>(agg1p[l], agg2, k1, k2, cc, (float*)d_out);
    }
  }
}

// Round 4
// 955.674 us; speedup vs baseline: 2.3194x; 1.2725x over previous
//
#include <hip/hip_runtime.h>
#include <math.h>

#define LNODES 2048
#define NEDGE 16384
#define GBIG 32
#define GSM 4
#define NCOUT 256
#define BN_EPS 1e-5f
#define ND 32  // dst nodes per agg block

// ---------------- setup: degree, dis, CSR ----------------

__global__ __launch_bounds__(256) void count_deg_k(const int* __restrict__ ei,
                                                   float* __restrict__ deg,
                                                   int* __restrict__ cnt) {
  int e = blockIdx.x * 256 + threadIdx.x;
  if (e < NEDGE) {
    int d = ei[NEDGE + e];
    atomicAdd(&deg[d], 1.0f);
    atomicAdd(&cnt[d], 1);
  }
}

__global__ __launch_bounds__(256) void dis_k(const float* __restrict__ deg,
                                             float* __restrict__ dis,
                                             float* __restrict__ selfn) {
  int i = blockIdx.x * 256 + threadIdx.x;
  if (i < LNODES) {
    float di = rsqrtf(deg[i] + 2.0f);  // improved=True: +2 self loop, always > 0
    dis[i] = di;
    selfn[i] = 2.0f * di * di;
  }
}

// single block: exclusive prefix over 2048 per-node counts -> row_ptr[0..2048]
__global__ __launch_bounds__(256) void scan_k(const int* __restrict__ cnt,
                                              int* __restrict__ rp) {
  __shared__ int part[256];
  int t = threadIdx.x;
  int base = t * 8;
  int loc[8];
  int s = 0;
#pragma unroll
  for (int j = 0; j < 8; ++j) { loc[j] = s; s += cnt[base + j]; }
  part[t] = s;
  __syncthreads();
  for (int off = 1; off < 256; off <<= 1) {
    int v = (t >= off) ? part[t - off] : 0;
    __syncthreads();
    part[t] += v;
    __syncthreads();
  }
  int excl = (t == 0) ? 0 : part[t - 1];
#pragma unroll
  for (int j = 0; j < 8; ++j) rp[base + j] = excl + loc[j];
  if (t == 255) rp[LNODES] = part[255];
}

__global__ __launch_bounds__(256) void fill_k(const int* __restrict__ ei,
                                              const int* __restrict__ rp,
                                              int* __restrict__ fillc,
                                              const float* __restrict__ dis,
                                              int* __restrict__ col,
                                              float* __restrict__ wn) {
  int e = blockIdx.x * 256 + threadIdx.x;
  if (e < NEDGE) {
    int s = ei[e], d = ei[NEDGE + e];
    int pos = rp[d] + atomicAdd(&fillc[d], 1);
    col[pos] = s;
    wn[pos] = dis[s] * dis[d];
  }
}

// ---------------- max-pool over N=8 (layout-agnostic: flat [G, 8, per]) ----------------
__global__ __launch_bounds__(256) void pool_k(const float* __restrict__ X,
                                              float* __restrict__ XP, int per) {
  int i = blockIdx.x * 256 + threadIdx.x;
  int total4 = GSM * per / 4;
  if (i >= total4) return;
  int f = i * 4;
  int b = f / per;
  int rem = f - b * per;
  const float* base = X + (size_t)b * 8 * per + rem;
  float4 m = *reinterpret_cast<const float4*>(base);
#pragma unroll
  for (int j = 1; j < 8; ++j) {
    float4 v = *reinterpret_cast<const float4*>(base + (size_t)j * per);
    m.x = fmaxf(m.x, v.x); m.y = fmaxf(m.y, v.y);
    m.z = fmaxf(m.z, v.z); m.w = fmaxf(m.w, v.w);
  }
  *reinterpret_cast<float4*>(XP + (size_t)b * per + rem) = m;
}

// ---------------- fp32 GEMM, node-major output ----------------
// C[g, node, co] = sum_ci A[node, ci] * W[ci, co]
// A: TRANSA=1 -> X[g, ci, node] (channel-major input); TRANSA=0 -> X[g, node, ci]
// grid (L/64, Cout/64, G), 256 threads, 4x4 per-thread tile, BK=16
template <int TRANSA>
__global__ __launch_bounds__(256) void gemm_nm_k(const float* __restrict__ X,
                                                 const float* __restrict__ W,
                                                 float* __restrict__ C, int Cin) {
  __shared__ float Ash[16][68];  // [k][node], +4 pad keeps stores 2-way max
  __shared__ float Bsh[16][64];  // [k][co]
  const int g = blockIdx.z;
  const int n0 = blockIdx.x * 64;  // node
  const int c0 = blockIdx.y * 64;  // co
  const int tid = threadIdx.x;
  const int tco = (tid & 15) * 4;  // co offset
  const int tnd = (tid >> 4) * 4;  // node offset
  float acc[4][4] = {};            // [node_i][co_j]
  const float* Xg = X + (size_t)g * Cin * LNODES;
  const int wl_k = tid >> 4;        // 0..15
  const int wl_c = (tid & 15) * 4;  // 0..60
  for (int k0 = 0; k0 < Cin; k0 += 16) {
    *reinterpret_cast<float4*>(&Bsh[wl_k][wl_c]) =
        *reinterpret_cast<const float4*>(&W[(size_t)(k0 + wl_k) * NCOUT + c0 + wl_c]);
    if (TRANSA) {
      *reinterpret_cast<float4*>(&Ash[wl_k][wl_c]) =
          *reinterpret_cast<const float4*>(&Xg[(size_t)(k0 + wl_k) * LNODES + n0 + wl_c]);
    } else {
      int an = tid >> 2;         // 0..63 node
      int ak = (tid & 3) * 4;    // 0..12 k
      float4 v = *reinterpret_cast<const float4*>(&Xg[(size_t)(n0 + an) * Cin + k0 + ak]);
      Ash[ak + 0][an] = v.x; Ash[ak + 1][an] = v.y;
      Ash[ak + 2][an] = v.z; Ash[ak + 3][an] = v.w;
    }
    __syncthreads();
#pragma unroll
    for (int k = 0; k < 16; ++k) {
      float4 a = *reinterpret_cast<const float4*>(&Ash[k][tnd]);
      float4 b = *reinterpret_cast<const float4*>(&Bsh[k][tco]);
      float av[4] = {a.x, a.y, a.z, a.w};
      float bv[4] = {b.x, b.y, b.z, b.w};
#pragma unroll
      for (int i = 0; i < 4; ++i)
#pragma unroll
        for (int j = 0; j < 4; ++j) acc[i][j] += av[i] * bv[j];
    }
    __syncthreads();
  }
#pragma unroll
  for (int i = 0; i < 4; ++i) {
    float4 r = {acc[i][0], acc[i][1], acc[i][2], acc[i][3]};
    *reinterpret_cast<float4*>(&C[((size_t)g * LNODES + n0 + tnd + i) * NCOUT + c0 + tco]) = r;
  }
}

// ---------------- GCN aggregation, node-major, float4/lane, XCD-swizzled ----------------
// AGG[g,d,co] = selfn[d]*HW[g,d,co] + sum_e wn[e]*HW[g,col[e],co]
// lane = 4 channels (wave covers the full 256-ch row: one 1KB dwordx4 load per
// row-read -> 4x bytes in flight vs 256B loads). 4 waves split ND dsts.
// 1-D grid, swizzled so all blocks of one g land on one XCD (L2-resident slab).
// BN stats: per-thread partials -> LDS cross-wave reduce -> 512 atomics/block.
template <int NG>
__global__ __launch_bounds__(256) void agg_nm_k(const float* __restrict__ HW,
                                                const int* __restrict__ col,
                                                const float* __restrict__ wn,
                                                const int* __restrict__ rp,
                                                const float* __restrict__ selfn,
                                                float* __restrict__ AGG,
                                                float* __restrict__ sum,
                                                float* __restrict__ sq) {
  int bid = blockIdx.x;
  int g, chunk;
  if (NG == GBIG) {
    // xcd = bid & 7; g%8 == xcd; bijective over (g, chunk)
    int slot = bid >> 3;
    g = (bid & 7) + 8 * (slot >> 6);
    chunk = slot & 63;
  } else {
    g = bid & (NG - 1);
    chunk = bid >> 2;
  }
  const int d0 = chunk * ND;
  const int t = threadIdx.x;
  const int wv = t >> 6;         // wave 0..3
  const int lc = (t & 63) * 4;   // channel
  const float* base = HW + (size_t)g * LNODES * NCOUT;
  float4 s = {0.f, 0.f, 0.f, 0.f}, q = {0.f, 0.f, 0.f, 0.f};
  for (int i = wv; i < ND; i += 4) {
    int d = d0 + i;
    int e0 = rp[d], e1 = rp[d + 1];
    float sw = selfn[d];
    float4 v = *reinterpret_cast<const float4*>(&base[(size_t)d * NCOUT + lc]);
    float4 acc = {sw * v.x, sw * v.y, sw * v.z, sw * v.w};
    for (int e = e0; e < e1; ++e) {
      float w = wn[e];
      float4 u = *reinterpret_cast<const float4*>(&base[(size_t)col[e] * NCOUT + lc]);
      acc.x += w * u.x; acc.y += w * u.y; acc.z += w * u.z; acc.w += w * u.w;
    }
    *reinterpret_cast<float4*>(&AGG[((size_t)g * LNODES + d) * NCOUT + lc]) = acc;
    s.x += acc.x; s.y += acc.y; s.z += acc.z; s.w += acc.w;
    q.x += acc.x * acc.x; q.y += acc.y * acc.y;
    q.z += acc.z * acc.z; q.w += acc.w * acc.w;
  }
  __shared__ float lsum[4][NCOUT], lsq[4][NCOUT];
  *reinterpret_cast<float4*>(&lsum[wv][lc]) = s;
  *reinterpret_cast<float4*>(&lsq[wv][lc]) = q;
  __syncthreads();
  // thread t owns channel t: reduce 4 waves, one atomic each for sum/sq
  float ts = lsum[0][t] + lsum[1][t] + lsum[2][t] + lsum[3][t];
  float tq = lsq[0][t] + lsq[1][t] + lsq[2][t] + lsq[3][t];
  atomicAdd(&sum[t], ts);
  atomicAdd(&sq[t], tq);
}

// ---------------- BN finalize: per-channel k1, k2, combined constant cc ----------------
__global__ __launch_bounds__(256) void bnfinal_k(const float* __restrict__ sum1,
                                                 const float* __restrict__ sq1,
                                                 const float* __restrict__ sum2,
                                                 const float* __restrict__ sq2,
                                                 const float* __restrict__ ga,
                                                 const float* __restrict__ be,
                                                 const float* __restrict__ gs,
                                                 const float* __restrict__ bes,
                                                 float* __restrict__ k1,
                                                 float* __restrict__ k2,
                                                 float* __restrict__ cc) {
  int co = threadIdx.x;  // 256 threads
  const float c1 = (float)(GBIG * LNODES), c2 = (float)(GSM * LNODES);
  float mA = sum1[co] / c1;
  float vA = sq1[co] / c1 - mA * mA;
  float kA = ga[co] * rsqrtf(vA + BN_EPS);
  float mB = sum2[co] / c2;
  float vB = sq2[co] / c2 - mB * mB;
  float kB = gs[co] * rsqrtf(vB + BN_EPS);
  k1[co] = kA;
  k2[co] = kB;
  cc[co] = be[co] - kA * mA + bes[co] - kB * mB;
}

// ---------------- fused BN+BN+add+ReLU, node-major output (layers 0,1) ----------------
__global__ __launch_bounds__(256) void fuse_nm_k(const float* __restrict__ A1,
                                                 const float* __restrict__ A2,
                                                 const float* __restrict__ k1,
                                                 const float* __restrict__ k2,
                                                 const float* __restrict__ cc,
                                                 float* __restrict__ O) {
  size_t i = (size_t)blockIdx.x * 256 + threadIdx.x;
  size_t f = i * 4;  // total = 32*2048*256
  int co = (int)(f & (NCOUT - 1));
  int d = (int)((f >> 8) & (LNODES - 1));
  int g = (int)(f >> 19);
  int b = g >> 3;
  float4 a1 = *reinterpret_cast<const float4*>(A1 + f);
  float4 a2 = *reinterpret_cast<const float4*>(A2 + ((size_t)b * LNODES + d) * NCOUT + co);
  float4 K1 = *reinterpret_cast<const float4*>(k1 + co);
  float4 K2 = *reinterpret_cast<const float4*>(k2 + co);
  float4 CC = *reinterpret_cast<const float4*>(cc + co);
  float4 o;
  o.x = fmaxf(K1.x * a1.x + K2.x * a2.x + CC.x, 0.f);
  o.y = fmaxf(K1.y * a1.y + K2.y * a2.y + CC.y, 0.f);
  o.z = fmaxf(K1.z * a1.z + K2.z * a2.z + CC.z, 0.f);
  o.w = fmaxf(K1.w * a1.w + K2.w * a2.w + CC.w, 0.f);
  *reinterpret_cast<float4*>(O + f) = o;
}

// ---------------- fused BN+BN+add+ReLU + transpose to channel-major (layer 2) ----------------
// O[g, co, d] from A1/A2 node-major, via LDS 64x64 tile. grid (L/64, 256/64, G)
__global__ __launch_bounds__(256) void fuse_tr_k(const float* __restrict__ A1,
                                                 const float* __restrict__ A2,
                                                 const float* __restrict__ k1,
                                                 const float* __restrict__ k2,
                                                 const float* __restrict__ cc,
                                                 float* __restrict__ O) {
  __shared__ float T[64][65];
  const int g = blockIdx.z;
  const int d0 = blockIdx.x * 64;
  const int c0 = blockIdx.y * 64;
  const int b = g >> 3;
  const int tr = threadIdx.x >> 4;        // 0..15
  const int tc = (threadIdx.x & 15) * 4;  // 0..60
  float4 K1 = *reinterpret_cast<const float4*>(k1 + c0 + tc);
  float4 K2 = *reinterpret_cast<const float4*>(k2 + c0 + tc);
  float4 CC = *reinterpret_cast<const float4*>(cc + c0 + tc);
#pragma unroll
  for (int p = 0; p < 4; ++p) {
    int d = d0 + tr + p * 16;
    float4 a1 = *reinterpret_cast<const float4*>(&A1[((size_t)g * LNODES + d) * NCOUT + c0 + tc]);
    float4 a2 = *reinterpret_cast<const float4*>(&A2[((size_t)b * LNODES + d) * NCOUT + c0 + tc]);
    T[tr + p * 16][tc + 0] = fmaxf(K1.x * a1.x + K2.x * a2.x + CC.x, 0.f);
    T[tr + p * 16][tc + 1] = fmaxf(K1.y * a1.y + K2.y * a2.y + CC.y, 0.f);
    T[tr + p * 16][tc + 2] = fmaxf(K1.z * a1.z + K2.z * a2.z + CC.z, 0.f);
    T[tr + p * 16][tc + 3] = fmaxf(K1.w * a1.w + K2.w * a2.w + CC.w, 0.f);
  }
  __syncthreads();
#pragma unroll
  for (int p = 0; p < 4; ++p) {
    int c = tr + p * 16;
    float4 o = {T[tc + 0][c], T[tc + 1][c], T[tc + 2][c], T[tc + 3][c]};
    *reinterpret_cast<float4*>(&O[((size_t)g * NCOUT + c0 + c) * LNODES + d0 + tc]) = o;
  }
}

// ---------------- launch ----------------

extern "C" void kernel_launch(void* const* d_in, const int* in_sizes, int n_in,
                              void* d_out, int out_size, void* d_ws, size_t ws_size,
                              hipStream_t stream) {
  const float* x_in = (const float*)d_in[0];
  const int* ei = (const int*)d_in[1];
  const float* W[3]   = {(const float*)d_in[2],  (const float*)d_in[4],  (const float*)d_in[6]};
  const float* Wsym[3]= {(const float*)d_in[8],  (const float*)d_in[10], (const float*)d_in[12]};
  const float* ga[3]  = {(const float*)d_in[14], (const float*)d_in[16], (const float*)d_in[18]};
  const float* be[3]  = {(const float*)d_in[15], (const float*)d_in[17], (const float*)d_in[19]};
  const float* gs[3]  = {(const float*)d_in[20], (const float*)d_in[22], (const float*)d_in[24]};
  const float* bes[3] = {(const float*)d_in[21], (const float*)d_in[23], (const float*)d_in[25]};

  const size_t SBIG = (size_t)GBIG * NCOUT * LNODES * sizeof(float);  // 64 MiB
  const size_t SP = (size_t)GSM * NCOUT * LNODES * sizeof(float);     // 8 MiB
  // bufA aliases d_out (exactly SBIG); rotation guarantees d_out's final writer
  // is the layer-2 fuse_tr.
  float* bufA = (float*)d_out;
  char* p = (char*)d_ws;
  float* bufB = (float*)p; p += SBIG;
  float* xp   = (float*)p; p += SP;
  float* hw2  = (float*)p; p += SP;
  float* agg2 = (float*)p; p += SP;
  int*   col  = (int*)p;   p += NEDGE * 4;
  float* wn   = (float*)p; p += NEDGE * 4;
  int*   rp   = (int*)p;   p += 2064 * 4;
  float* dis  = (float*)p; p += LNODES * 4;
  float* selfn= (float*)p; p += LNODES * 4;
  char* zbase = p;
  float* deg  = (float*)p; p += LNODES * 4;
  int*   cnt  = (int*)p;   p += LNODES * 4;
  int*   fillc= (int*)p;   p += LNODES * 4;
  size_t zsize = (size_t)(p - zbase);
  char* statbase = p;
  float* sum1 = (float*)p; p += 1024;
  float* sq1  = (float*)p; p += 1024;
  float* sum2 = (float*)p; p += 1024;
  float* sq2  = (float*)p; p += 1024;
  float* k1 = (float*)p; p += 1024;
  float* k2 = (float*)p; p += 1024;
  float* cc = (float*)p; p += 1024;

  // ---- graph setup (recomputed every call; ws is re-poisoned) ----
  hipMemsetAsync(zbase, 0, zsize, stream);
  count_deg_k<<<NEDGE / 256, 256, 0, stream>>>(ei, deg, cnt);
  dis_k<<<LNODES / 256, 256, 0, stream>>>(deg, dis, selfn);
  scan_k<<<1, 256, 0, stream>>>(cnt, rp);
  fill_k<<<NEDGE / 256, 256, 0, stream>>>(ei, rp, fillc, dis, col, wn);

  // ping-pong (all node-major internally):
  // layer0 x=d_in(ch-major), hw->A, agg->B, out->A
  // layer1 x=A, hw->B, agg->A, out->B
  // layer2 x=B, hw->A, agg->B, fuse_tr->d_out(=A)
  const float* xs[3]  = {x_in, bufA, bufB};
  float* hw1p[3] = {bufA, bufB, bufA};
  float* agg1p[3]= {bufB, bufA, bufB};
  float* outp[3] = {bufA, bufB, (float*)d_out};

  dim3 gemm_grid_big(LNODES / 64, NCOUT / 64, GBIG);
  dim3 gemm_grid_sm(LNODES / 64, NCOUT / 64, GSM);
  const int agg_blocks_big = (LNODES / ND) * GBIG;  // 2048, 1-D swizzled
  const int agg_blocks_sm = (LNODES / ND) * GSM;    // 256

  for (int l = 0; l < 3; ++l) {
    const int Cin = (l == 0) ? 128 : 256;
    // pooled branch: max over N (layout-agnostic), then GEMM
    int npool4 = GSM * Cin * LNODES / 4;
    pool_k<<<npool4 / 256, 256, 0, stream>>>(xs[l], xp, Cin * LNODES);
    if (l == 0) {
      gemm_nm_k<1><<<gemm_grid_sm, 256, 0, stream>>>(xp, Wsym[l], hw2, Cin);
      gemm_nm_k<1><<<gemm_grid_big, 256, 0, stream>>>(xs[l], W[l], hw1p[l], Cin);
    } else {
      gemm_nm_k<0><<<gemm_grid_sm, 256, 0, stream>>>(xp, Wsym[l], hw2, Cin);
      gemm_nm_k<0><<<gemm_grid_big, 256, 0, stream>>>(xs[l], W[l], hw1p[l], Cin);
    }
    // BN stats are fused into agg; zero them first
    hipMemsetAsync(statbase, 0, 4096, stream);
    agg_nm_k<GBIG><<<agg_blocks_big, 256, 0, stream>>>(hw1p[l], col, wn, rp, selfn,
                                                       agg1p[l], sum1, sq1);
    agg_nm_k<GSM><<<agg_blocks_sm, 256, 0, stream>>>(hw2, col, wn, rp, selfn,
                                                     agg2, sum2, sq2);
    bnfinal_k<<<1, 256, 0, stream>>>(sum1, sq1, sum2, sq2,
                                     ga[l], be[l], gs[l], bes[l], k1, k2, cc);
    if (l < 2) {
      int nf = (GBIG * NCOUT * LNODES / 4) / 256;
      fuse_nm_k<<<nf, 256, 0, stream>>>(agg1p[l], agg2, k1, k2, cc, outp[l]);
    } else {
      dim3 ft(LNODES / 64, NCOUT / 64, GBIG);
      fuse_tr_k<<<ft, 256, 0, stream>>>(agg1p[l], agg2, k1, k2, cc, (float*)d_out);
    }
  }
}

// Round 5
// 676.035 us; speedup vs baseline: 3.2788x; 1.4136x over previous
//
#include <hip/hip_runtime.h>
#include <math.h>

#define LNODES 2048
#define NEDGE 16384
#define GBIG 32
#define GSM 4
#define NCOUT 256
#define BN_EPS 1e-5f
#define ND 32  // dst nodes per agg block

typedef unsigned short u16;
typedef __attribute__((ext_vector_type(8))) short bf16x8;
typedef __attribute__((ext_vector_type(4))) float f32x4;

__device__ __forceinline__ u16 f2bf(float f) {
  unsigned u = __float_as_uint(f);
  u += 0x7fffu + ((u >> 16) & 1u);  // RNE
  return (u16)(u >> 16);
}
__device__ __forceinline__ unsigned pk2(float a, float b) {  // a->lo, b->hi
  unsigned ua = __float_as_uint(a); ua += 0x7fffu + ((ua >> 16) & 1u);
  unsigned ub = __float_as_uint(b); ub += 0x7fffu + ((ub >> 16) & 1u);
  return (ua >> 16) | (ub & 0xffff0000u);
}
__device__ __forceinline__ float blo(unsigned u) { return __uint_as_float(u << 16); }
__device__ __forceinline__ float bhi(unsigned u) { return __uint_as_float(u & 0xffff0000u); }

// ---------------- setup: degree, dis, CSR ----------------

__global__ __launch_bounds__(256) void count_deg_k(const int* __restrict__ ei,
                                                   float* __restrict__ deg,
                                                   int* __restrict__ cnt) {
  int e = blockIdx.x * 256 + threadIdx.x;
  if (e < NEDGE) {
    int d = ei[NEDGE + e];
    atomicAdd(&deg[d], 1.0f);
    atomicAdd(&cnt[d], 1);
  }
}

__global__ __launch_bounds__(256) void dis_k(const float* __restrict__ deg,
                                             float* __restrict__ dis,
                                             float* __restrict__ selfn) {
  int i = blockIdx.x * 256 + threadIdx.x;
  if (i < LNODES) {
    float di = rsqrtf(deg[i] + 2.0f);  // improved=True self loop weight 2
    dis[i] = di;
    selfn[i] = 2.0f * di * di;
  }
}

__global__ __launch_bounds__(256) void scan_k(const int* __restrict__ cnt,
                                              int* __restrict__ rp) {
  __shared__ int part[256];
  int t = threadIdx.x;
  int base = t * 8;
  int loc[8];
  int s = 0;
#pragma unroll
  for (int j = 0; j < 8; ++j) { loc[j] = s; s += cnt[base + j]; }
  part[t] = s;
  __syncthreads();
  for (int off = 1; off < 256; off <<= 1) {
    int v = (t >= off) ? part[t - off] : 0;
    __syncthreads();
    part[t] += v;
    __syncthreads();
  }
  int excl = (t == 0) ? 0 : part[t - 1];
#pragma unroll
  for (int j = 0; j < 8; ++j) rp[base + j] = excl + loc[j];
  if (t == 255) rp[LNODES] = part[255];
}

__global__ __launch_bounds__(256) void fill_k(const int* __restrict__ ei,
                                              const int* __restrict__ rp,
                                              int* __restrict__ fillc,
                                              const float* __restrict__ dis,
                                              int* __restrict__ col,
                                              float* __restrict__ wn) {
  int e = blockIdx.x * 256 + threadIdx.x;
  if (e < NEDGE) {
    int s = ei[e], d = ei[NEDGE + e];
    int pos = rp[d] + atomicAdd(&fillc[d], 1);
    col[pos] = s;
    wn[pos] = dis[s] * dis[d];
  }
}

// ---------------- x [G][Cin][L] f32 -> XT [G][L][Cin] bf16 ----------------
// grid (L/64, Cin/64, G)
__global__ __launch_bounds__(256) void trans_k(const float* __restrict__ X,
                                               u16* __restrict__ XT, int Cin) {
  __shared__ float T[64][65];  // [ci_local][node_local]
  const int g = blockIdx.z;
  const int n0 = blockIdx.x * 64;
  const int c0 = blockIdx.y * 64;
  const int tr = threadIdx.x >> 4;
  const int tc = (threadIdx.x & 15) * 4;
#pragma unroll
  for (int p = 0; p < 4; ++p) {
    int ci = c0 + tr + p * 16;
    float4 v = *reinterpret_cast<const float4*>(&X[((size_t)g * Cin + ci) * LNODES + n0 + tc]);
    T[tr + p * 16][tc + 0] = v.x; T[tr + p * 16][tc + 1] = v.y;
    T[tr + p * 16][tc + 2] = v.z; T[tr + p * 16][tc + 3] = v.w;
  }
  __syncthreads();
#pragma unroll
  for (int p = 0; p < 4; ++p) {
    int nd = tr + p * 16;
    uint2 o = {pk2(T[tc + 0][nd], T[tc + 1][nd]), pk2(T[tc + 2][nd], T[tc + 3][nd])};
    *reinterpret_cast<uint2*>(&XT[((size_t)g * LNODES + n0 + nd) * Cin + c0 + tc]) = o;
  }
}

// ---------------- W [Ci][256] f32 -> WbT [256][Ci] bf16 ----------------
// grid (256/64, Ci/64)
__global__ __launch_bounds__(256) void cvtw_k(const float* __restrict__ W,
                                              u16* __restrict__ WbT, int Ci) {
  __shared__ float T[64][65];  // [ci_local][co_local]
  const int co0 = blockIdx.x * 64;
  const int ci0 = blockIdx.y * 64;
  const int tr = threadIdx.x >> 4;
  const int tc = (threadIdx.x & 15) * 4;
#pragma unroll
  for (int p = 0; p < 4; ++p) {
    int ci = ci0 + tr + p * 16;
    float4 v = *reinterpret_cast<const float4*>(&W[(size_t)ci * NCOUT + co0 + tc]);
    T[tr + p * 16][tc + 0] = v.x; T[tr + p * 16][tc + 1] = v.y;
    T[tr + p * 16][tc + 2] = v.z; T[tr + p * 16][tc + 3] = v.w;
  }
  __syncthreads();
#pragma unroll
  for (int p = 0; p < 4; ++p) {
    int co = tr + p * 16;
    uint2 o = {pk2(T[tc + 0][co], T[tc + 1][co]), pk2(T[tc + 2][co], T[tc + 3][co])};
    *reinterpret_cast<uint2*>(&WbT[(size_t)(co0 + co) * Ci + ci0 + tc]) = o;
  }
}

// ---------------- max-pool over N=8, bf16, flat [4][8][per] ----------------
__global__ __launch_bounds__(256) void pool_bf_k(const u16* __restrict__ X,
                                                 u16* __restrict__ XP, int per) {
  int i = blockIdx.x * 256 + threadIdx.x;
  size_t f = (size_t)i * 8;
  int b = (int)(f / per);
  size_t rem = f - (size_t)b * per;
  const u16* base = X + (size_t)b * 8 * per + rem;
  uint4 u = *reinterpret_cast<const uint4*>(base);
  float m0 = blo(u.x), m1 = bhi(u.x), m2 = blo(u.y), m3 = bhi(u.y);
  float m4 = blo(u.z), m5 = bhi(u.z), m6 = blo(u.w), m7 = bhi(u.w);
#pragma unroll
  for (int j = 1; j < 8; ++j) {
    uint4 v = *reinterpret_cast<const uint4*>(base + (size_t)j * per);
    m0 = fmaxf(m0, blo(v.x)); m1 = fmaxf(m1, bhi(v.x));
    m2 = fmaxf(m2, blo(v.y)); m3 = fmaxf(m3, bhi(v.y));
    m4 = fmaxf(m4, blo(v.z)); m5 = fmaxf(m5, bhi(v.z));
    m6 = fmaxf(m6, blo(v.w)); m7 = fmaxf(m7, bhi(v.w));
  }
  uint4 o = {pk2(m0, m1), pk2(m2, m3), pk2(m4, m5), pk2(m6, m7)};
  *reinterpret_cast<uint4*>(XP + (size_t)b * per + rem) = o;
}

// ---------------- bf16 MFMA GEMM ----------------
// HW[g,node,co] bf16 = X[g,node,ci] bf16 @ WbT[co,ci] bf16  (fp32 acc)
// A-operand = W-tile (M=co), B-operand = X-tile (N=node).
// 128x128 block tile, 4 waves in 2x2, each wave 64x64 via 4x4 frags of 16x16x32.
// grid (L/128, 256/128, G), 256 threads.
__global__ __launch_bounds__(256) void gemm_bf_k(const u16* __restrict__ X,
                                                 const u16* __restrict__ WbT,
                                                 u16* __restrict__ HW, int Cin) {
  __shared__ u16 smem[17408];      // 34816 B: K-loop uses 2x[128][40]; epilogue [128][136]
  u16* Wsh = smem;                 // [128][40] (pad 8 bf16)
  u16* Xsh = smem + 128 * 40;
  const int g = blockIdx.z;
  const int n0 = blockIdx.x * 128;
  const int c0 = blockIdx.y * 128;
  const int t = threadIdx.x;
  const int wv = t >> 6;
  const int lane = t & 63;
  const int q = lane >> 4, l = lane & 15;
  const int wm = wv >> 1, wn = wv & 1;  // co-half, node-half
  f32x4 zero = {0.f, 0.f, 0.f, 0.f};
  f32x4 acc[4][4];
#pragma unroll
  for (int i = 0; i < 4; ++i)
#pragma unroll
    for (int j = 0; j < 4; ++j) acc[i][j] = zero;
  const int r0 = t >> 2;        // 0..63: tile row
  const int seg = (t & 3) * 8;  // k sub-offset (bf16)
  const u16* Wg = WbT + (size_t)(c0 + r0) * Cin + seg;
  const u16* Xg = X + ((size_t)g * LNODES + n0 + r0) * Cin + seg;
  for (int k0 = 0; k0 < Cin; k0 += 32) {
    uint4 w0 = *reinterpret_cast<const uint4*>(Wg + k0);
    uint4 w1 = *reinterpret_cast<const uint4*>(Wg + (size_t)64 * Cin + k0);
    uint4 x0 = *reinterpret_cast<const uint4*>(Xg + k0);
    uint4 x1 = *reinterpret_cast<const uint4*>(Xg + (size_t)64 * Cin + k0);
    __syncthreads();
    *reinterpret_cast<uint4*>(&Wsh[r0 * 40 + seg]) = w0;
    *reinterpret_cast<uint4*>(&Wsh[(r0 + 64) * 40 + seg]) = w1;
    *reinterpret_cast<uint4*>(&Xsh[r0 * 40 + seg]) = x0;
    *reinterpret_cast<uint4*>(&Xsh[(r0 + 64) * 40 + seg]) = x1;
    __syncthreads();
    bf16x8 af[4], bx[4];
#pragma unroll
    for (int fi = 0; fi < 4; ++fi)
      af[fi] = *reinterpret_cast<const bf16x8*>(&Wsh[(wm * 64 + fi * 16 + l) * 40 + q * 8]);
#pragma unroll
    for (int fj = 0; fj < 4; ++fj)
      bx[fj] = *reinterpret_cast<const bf16x8*>(&Xsh[(wn * 64 + fj * 16 + l) * 40 + q * 8]);
#pragma unroll
    for (int fi = 0; fi < 4; ++fi)
#pragma unroll
      for (int fj = 0; fj < 4; ++fj)
        acc[fi][fj] = __builtin_amdgcn_mfma_f32_16x16x32_bf16(af[fi], bx[fj], acc[fi][fj], 0, 0, 0);
  }
  __syncthreads();
  // epilogue: D row = co(q*4+reg), col = node(l). Repack via LDS -> coalesced stores.
  u16* Csh = smem;  // [128][136] ushort
#pragma unroll
  for (int fi = 0; fi < 4; ++fi) {
#pragma unroll
    for (int fj = 0; fj < 4; ++fj) {
      int co_l = wm * 64 + fi * 16 + q * 4;
      int nd_l = wn * 64 + fj * 16 + l;
      uint2 pkd = {pk2(acc[fi][fj][0], acc[fi][fj][1]),
                   pk2(acc[fi][fj][2], acc[fi][fj][3])};
      *reinterpret_cast<uint2*>(&Csh[nd_l * 136 + co_l]) = pkd;
    }
  }
  __syncthreads();
#pragma unroll
  for (int p = 0; p < 8; ++p) {
    int idx = p * 256 + t;
    int nd = idx >> 4;
    int c8 = (idx & 15) * 8;
    uint4 v = *reinterpret_cast<const uint4*>(&Csh[nd * 136 + c8]);
    *reinterpret_cast<uint4*>(&HW[((size_t)g * LNODES + n0 + nd) * NCOUT + c0 + c8]) = v;
  }
}

// ---------------- GCN aggregation, bf16 IO, fused fp32 BN stats ----------------
// lane = 4 channels (uint2); wave covers the 256-ch row (512B coalesced).
// XCD swizzle: all blocks of one g on one XCD.
template <int NG>
__global__ __launch_bounds__(256) void agg_bf_k(const u16* __restrict__ HW,
                                                const int* __restrict__ col,
                                                const float* __restrict__ wn,
                                                const int* __restrict__ rp,
                                                const float* __restrict__ selfn,
                                                u16* __restrict__ AGG,
                                                float* __restrict__ sum,
                                                float* __restrict__ sq) {
  int bid = blockIdx.x;
  int g, chunk;
  if (NG == GBIG) {
    int slot = bid >> 3;
    g = (bid & 7) + 8 * (slot >> 6);
    chunk = slot & 63;
  } else {
    g = bid & (NG - 1);
    chunk = bid >> 2;
  }
  const int d0 = chunk * ND;
  const int t = threadIdx.x;
  const int wv = t >> 6;
  const int lc = (t & 63) * 4;
  const u16* base = HW + (size_t)g * LNODES * NCOUT;
  float4 s = {0.f, 0.f, 0.f, 0.f}, qq = {0.f, 0.f, 0.f, 0.f};
  for (int i = wv; i < ND; i += 4) {
    int d = d0 + i;
    int e0 = rp[d], e1 = rp[d + 1];
    float sw = selfn[d];
    uint2 u = *reinterpret_cast<const uint2*>(&base[(size_t)d * NCOUT + lc]);
    float4 a = {sw * blo(u.x), sw * bhi(u.x), sw * blo(u.y), sw * bhi(u.y)};
    for (int e = e0; e < e1; ++e) {
      float w = wn[e];
      uint2 v = *reinterpret_cast<const uint2*>(&base[(size_t)col[e] * NCOUT + lc]);
      a.x += w * blo(v.x); a.y += w * bhi(v.x);
      a.z += w * blo(v.y); a.w += w * bhi(v.y);
    }
    uint2 o = {pk2(a.x, a.y), pk2(a.z, a.w)};
    *reinterpret_cast<uint2*>(&AGG[((size_t)g * LNODES + d) * NCOUT + lc]) = o;
    s.x += a.x; s.y += a.y; s.z += a.z; s.w += a.w;
    qq.x += a.x * a.x; qq.y += a.y * a.y; qq.z += a.z * a.z; qq.w += a.w * a.w;
  }
  __shared__ float lsum[4][NCOUT], lsq[4][NCOUT];
  *reinterpret_cast<float4*>(&lsum[wv][lc]) = s;
  *reinterpret_cast<float4*>(&lsq[wv][lc]) = qq;
  __syncthreads();
  float ts = lsum[0][t] + lsum[1][t] + lsum[2][t] + lsum[3][t];
  float tq = lsq[0][t] + lsq[1][t] + lsq[2][t] + lsq[3][t];
  atomicAdd(&sum[t], ts);
  atomicAdd(&sq[t], tq);
}

// ---------------- BN finalize ----------------
__global__ __launch_bounds__(256) void bnfinal_k(const float* __restrict__ sum1,
                                                 const float* __restrict__ sq1,
                                                 const float* __restrict__ sum2,
                                                 const float* __restrict__ sq2,
                                                 const float* __restrict__ ga,
                                                 const float* __restrict__ be,
                                                 const float* __restrict__ gs,
                                                 const float* __restrict__ bes,
                                                 float* __restrict__ k1,
                                                 float* __restrict__ k2,
                                                 float* __restrict__ cc) {
  int co = threadIdx.x;
  const float c1 = (float)(GBIG * LNODES), c2 = (float)(GSM * LNODES);
  float mA = sum1[co] / c1;
  float vA = sq1[co] / c1 - mA * mA;
  float kA = ga[co] * rsqrtf(vA + BN_EPS);
  float mB = sum2[co] / c2;
  float vB = sq2[co] / c2 - mB * mB;
  float kB = gs[co] * rsqrtf(vB + BN_EPS);
  k1[co] = kA;
  k2[co] = kB;
  cc[co] = be[co] - kA * mA + bes[co] - kB * mB;
}

// ---------------- fused BN+BN+add+ReLU, bf16 node-major (layers 0,1) ----------------
__global__ __launch_bounds__(256) void fuse_bf_k(const u16* __restrict__ A1,
                                                 const u16* __restrict__ A2,
                                                 const float* __restrict__ k1,
                                                 const float* __restrict__ k2,
                                                 const float* __restrict__ cc,
                                                 u16* __restrict__ O) {
  size_t i = (size_t)blockIdx.x * 256 + threadIdx.x;
  size_t f = i * 8;
  int co = (int)(f & (NCOUT - 1));
  int d = (int)((f >> 8) & (LNODES - 1));
  int g = (int)(f >> 19);
  int b = g >> 3;
  uint4 a1 = *reinterpret_cast<const uint4*>(&A1[f]);
  uint4 a2 = *reinterpret_cast<const uint4*>(&A2[((size_t)b * LNODES + d) * NCOUT + co]);
  float4 K1a = *reinterpret_cast<const float4*>(&k1[co]);
  float4 K1b = *reinterpret_cast<const float4*>(&k1[co + 4]);
  float4 K2a = *reinterpret_cast<const float4*>(&k2[co]);
  float4 K2b = *reinterpret_cast<const float4*>(&k2[co + 4]);
  float4 Ca = *reinterpret_cast<const float4*>(&cc[co]);
  float4 Cb = *reinterpret_cast<const float4*>(&cc[co + 4]);
  float o0 = fmaxf(K1a.x * blo(a1.x) + K2a.x * blo(a2.x) + Ca.x, 0.f);
  float o1 = fmaxf(K1a.y * bhi(a1.x) + K2a.y * bhi(a2.x) + Ca.y, 0.f);
  float o2 = fmaxf(K1a.z * blo(a1.y) + K2a.z * blo(a2.y) + Ca.z, 0.f);
  float o3 = fmaxf(K1a.w * bhi(a1.y) + K2a.w * bhi(a2.y) + Ca.w, 0.f);
  float o4 = fmaxf(K1b.x * blo(a1.z) + K2b.x * blo(a2.z) + Cb.x, 0.f);
  float o5 = fmaxf(K1b.y * bhi(a1.z) + K2b.y * bhi(a2.z) + Cb.y, 0.f);
  float o6 = fmaxf(K1b.z * blo(a1.w) + K2b.z * blo(a2.w) + Cb.z, 0.f);
  float o7 = fmaxf(K1b.w * bhi(a1.w) + K2b.w * bhi(a2.w) + Cb.w, 0.f);
  uint4 ou = {pk2(o0, o1), pk2(o2, o3), pk2(o4, o5), pk2(o6, o7)};
  *reinterpret_cast<uint4*>(&O[f]) = ou;
}

// ---------------- layer 2: fuse + transpose to channel-major fp32 d_out ----------------
// grid (L/64, 256/64, G)
__global__ __launch_bounds__(256) void fuse_tr_bf_k(const u16* __restrict__ A1,
                                                    const u16* __restrict__ A2,
                                                    const float* __restrict__ k1,
                                                    const float* __restrict__ k2,
                                                    const float* __restrict__ cc,
                                                    float* __restrict__ O) {
  __shared__ float T[64][65];  // [node_local][co_local]
  const int g = blockIdx.z;
  const int d0 = blockIdx.x * 64;
  const int c0 = blockIdx.y * 64;
  const int b = g >> 3;
  const int tr = threadIdx.x >> 4;
  const int tc = (threadIdx.x & 15) * 4;
  float4 K1 = *reinterpret_cast<const float4*>(&k1[c0 + tc]);
  float4 K2 = *reinterpret_cast<const float4*>(&k2[c0 + tc]);
  float4 CC = *reinterpret_cast<const float4*>(&cc[c0 + tc]);
#pragma unroll
  for (int p = 0; p < 4; ++p) {
    int d = d0 + tr + p * 16;
    uint2 a1 = *reinterpret_cast<const uint2*>(&A1[((size_t)g * LNODES + d) * NCOUT + c0 + tc]);
    uint2 a2 = *reinterpret_cast<const uint2*>(&A2[((size_t)b * LNODES + d) * NCOUT + c0 + tc]);
    T[tr + p * 16][tc + 0] = fmaxf(K1.x * blo(a1.x) + K2.x * blo(a2.x) + CC.x, 0.f);
    T[tr + p * 16][tc + 1] = fmaxf(K1.y * bhi(a1.x) + K2.y * bhi(a2.x) + CC.y, 0.f);
    T[tr + p * 16][tc + 2] = fmaxf(K1.z * blo(a1.y) + K2.z * blo(a2.y) + CC.z, 0.f);
    T[tr + p * 16][tc + 3] = fmaxf(K1.w * bhi(a1.y) + K2.w * bhi(a2.y) + CC.w, 0.f);
  }
  __syncthreads();
#pragma unroll
  for (int p = 0; p < 4; ++p) {
    int c = tr + p * 16;
    float4 o = {T[tc + 0][c], T[tc + 1][c], T[tc + 2][c], T[tc + 3][c]};
    *reinterpret_cast<float4*>(&O[((size_t)g * NCOUT + c0 + c) * LNODES + d0 + tc]) = o;
  }
}

// ---------------- launch ----------------

extern "C" void kernel_launch(void* const* d_in, const int* in_sizes, int n_in,
                              void* d_out, int out_size, void* d_ws, size_t ws_size,
                              hipStream_t stream) {
  const float* x_in = (const float*)d_in[0];
  const int* ei = (const int*)d_in[1];
  const float* W[3]   = {(const float*)d_in[2],  (const float*)d_in[4],  (const float*)d_in[6]};
  const float* Wsym[3]= {(const float*)d_in[8],  (const float*)d_in[10], (const float*)d_in[12]};
  const float* ga[3]  = {(const float*)d_in[14], (const float*)d_in[16], (const float*)d_in[18]};
  const float* be[3]  = {(const float*)d_in[15], (const float*)d_in[17], (const float*)d_in[19]};
  const float* gs[3]  = {(const float*)d_in[20], (const float*)d_in[22], (const float*)d_in[24]};
  const float* bes[3] = {(const float*)d_in[21], (const float*)d_in[23], (const float*)d_in[25]};

  const size_t EBIG = (size_t)GBIG * LNODES * NCOUT;  // 16.7M elems
  const size_t ESM = (size_t)GSM * LNODES * NCOUT;
  char* p = (char*)d_ws;
  u16* Xact = (u16*)p; p += EBIG * 2;   // 32 MiB: inter-layer activations (bf16)
  u16* AGG1 = (u16*)p; p += EBIG * 2;   // 32 MiB
  u16* agg2 = (u16*)p; p += ESM * 2;    // 4 MiB
  u16* WbT[3], *WsT[3];
  for (int i = 0; i < 3; ++i) { WbT[i] = (u16*)p; p += NCOUT * NCOUT * 2; }
  for (int i = 0; i < 3; ++i) { WsT[i] = (u16*)p; p += NCOUT * NCOUT * 2; }
  int*   col  = (int*)p;   p += NEDGE * 4;
  float* wn   = (float*)p; p += NEDGE * 4;
  int*   rp   = (int*)p;   p += 2064 * 4;
  float* dis  = (float*)p; p += LNODES * 4;
  float* selfn= (float*)p; p += LNODES * 4;
  char* zbase = p;
  float* deg  = (float*)p; p += LNODES * 4;
  int*   cnt  = (int*)p;   p += LNODES * 4;
  int*   fillc= (int*)p;   p += LNODES * 4;
  size_t zsize = (size_t)(p - zbase);
  char* statbase = p;
  float* sum1 = (float*)p; p += 1024;
  float* sq1  = (float*)p; p += 1024;
  float* sum2 = (float*)p; p += 1024;
  float* sq2  = (float*)p; p += 1024;
  float* k1 = (float*)p; p += 1024;
  float* k2 = (float*)p; p += 1024;
  float* cc = (float*)p; p += 1024;
  // aliases (lifetime-disjoint):
  u16* XT0 = Xact;                         // layer-0 node-major input (16 MiB)
  u16* xp  = AGG1;                         // pooled input (dead before agg_big writes)
  u16* hw2 = AGG1 + 2 * 1024 * 1024;       // sym GEMM out (read by agg_sm before agg_big)
  u16* HW1 = (u16*)d_out;                  // big GEMM out lives in d_out (dead by fuse time)

  // ---- CSR + weight conversion + input transpose ----
  hipMemsetAsync(zbase, 0, zsize, stream);
  count_deg_k<<<NEDGE / 256, 256, 0, stream>>>(ei, deg, cnt);
  dis_k<<<LNODES / 256, 256, 0, stream>>>(deg, dis, selfn);
  scan_k<<<1, 256, 0, stream>>>(cnt, rp);
  fill_k<<<NEDGE / 256, 256, 0, stream>>>(ei, rp, fillc, dis, col, wn);
  for (int i = 0; i < 3; ++i) {
    int Ci = (i == 0) ? 128 : 256;
    cvtw_k<<<dim3(NCOUT / 64, Ci / 64), 256, 0, stream>>>(W[i], WbT[i], Ci);
    cvtw_k<<<dim3(NCOUT / 64, Ci / 64), 256, 0, stream>>>(Wsym[i], WsT[i], Ci);
  }
  trans_k<<<dim3(LNODES / 64, 128 / 64, GBIG), 256, 0, stream>>>(x_in, XT0, 128);

  for (int l = 0; l < 3; ++l) {
    const int Cin = (l == 0) ? 128 : 256;
    const u16* Xin = (l == 0) ? XT0 : Xact;
    const int per = Cin * LNODES;
    pool_bf_k<<<GSM * per / 8 / 256, 256, 0, stream>>>(Xin, xp, per);
    gemm_bf_k<<<dim3(LNODES / 128, NCOUT / 128, GSM), 256, 0, stream>>>(xp, WsT[l], hw2, Cin);
    gemm_bf_k<<<dim3(LNODES / 128, NCOUT / 128, GBIG), 256, 0, stream>>>(Xin, WbT[l], HW1, Cin);
    hipMemsetAsync(statbase, 0, 4096, stream);
    // agg_sm first: it reads hw2 which aliases AGG1 (clobbered by agg_big)
    agg_bf_k<GSM><<<(LNODES / ND) * GSM, 256, 0, stream>>>(hw2, col, wn, rp, selfn,
                                                           agg2, sum2, sq2);
    agg_bf_k<GBIG><<<(LNODES / ND) * GBIG, 256, 0, stream>>>(HW1, col, wn, rp, selfn,
                                                             AGG1, sum1, sq1);
    bnfinal_k<<<1, 256, 0, stream>>>(sum1, sq1, sum2, sq2,
                                     ga[l], be[l], gs[l], bes[l], k1, k2, cc);
    if (l < 2) {
      fuse_bf_k<<<(int)(EBIG / 8 / 256), 256, 0, stream>>>(AGG1, agg2, k1, k2, cc, Xact);
    } else {
      fuse_tr_bf_k<<<dim3(LNODES / 64, NCOUT / 64, GBIG), 256, 0, stream>>>(
          AGG1, agg2, k1, k2, cc, (float*)d_out);
    }
  }
}

// Round 6
// 602.675 us; speedup vs baseline: 3.6779x; 1.1217x over previous
//
#include <hip/hip_runtime.h>
#include <math.h>

#define LNODES 2048
#define NEDGE 16384
#define GBIG 32
#define GSM 4
#define NCOUT 256
#define BN_EPS 1e-5f
#define ND 32  // dst nodes per agg block

typedef unsigned short u16;
typedef __attribute__((ext_vector_type(8))) short bf16x8;
typedef __attribute__((ext_vector_type(4))) float f32x4;

__device__ __forceinline__ u16 f2bf(float f) {
  unsigned u = __float_as_uint(f);
  u += 0x7fffu + ((u >> 16) & 1u);  // RNE
  return (u16)(u >> 16);
}
__device__ __forceinline__ unsigned pk2(float a, float b) {  // a->lo, b->hi
  unsigned ua = __float_as_uint(a); ua += 0x7fffu + ((ua >> 16) & 1u);
  unsigned ub = __float_as_uint(b); ub += 0x7fffu + ((ub >> 16) & 1u);
  return (ua >> 16) | (ub & 0xffff0000u);
}
__device__ __forceinline__ float blo(unsigned u) { return __uint_as_float(u << 16); }
__device__ __forceinline__ float bhi(unsigned u) { return __uint_as_float(u & 0xffff0000u); }

// ---------------- setup: degree, dis, CSR ----------------

__global__ __launch_bounds__(256) void count_deg_k(const int* __restrict__ ei,
                                                   float* __restrict__ deg,
                                                   int* __restrict__ cnt) {
  int e = blockIdx.x * 256 + threadIdx.x;
  if (e < NEDGE) {
    int d = ei[NEDGE + e];
    atomicAdd(&deg[d], 1.0f);
    atomicAdd(&cnt[d], 1);
  }
}

__global__ __launch_bounds__(256) void dis_k(const float* __restrict__ deg,
                                             float* __restrict__ dis,
                                             float* __restrict__ selfn) {
  int i = blockIdx.x * 256 + threadIdx.x;
  if (i < LNODES) {
    float di = rsqrtf(deg[i] + 2.0f);  // improved=True self loop weight 2
    dis[i] = di;
    selfn[i] = 2.0f * di * di;
  }
}

__global__ __launch_bounds__(256) void scan_k(const int* __restrict__ cnt,
                                              int* __restrict__ rp) {
  __shared__ int part[256];
  int t = threadIdx.x;
  int base = t * 8;
  int loc[8];
  int s = 0;
#pragma unroll
  for (int j = 0; j < 8; ++j) { loc[j] = s; s += cnt[base + j]; }
  part[t] = s;
  __syncthreads();
  for (int off = 1; off < 256; off <<= 1) {
    int v = (t >= off) ? part[t - off] : 0;
    __syncthreads();
    part[t] += v;
    __syncthreads();
  }
  int excl = (t == 0) ? 0 : part[t - 1];
#pragma unroll
  for (int j = 0; j < 8; ++j) rp[base + j] = excl + loc[j];
  if (t == 255) rp[LNODES] = part[255];
}

__global__ __launch_bounds__(256) void fill_k(const int* __restrict__ ei,
                                              const int* __restrict__ rp,
                                              int* __restrict__ fillc,
                                              const float* __restrict__ dis,
                                              int* __restrict__ col,
                                              float* __restrict__ wn) {
  int e = blockIdx.x * 256 + threadIdx.x;
  if (e < NEDGE) {
    int s = ei[e], d = ei[NEDGE + e];
    int pos = rp[d] + atomicAdd(&fillc[d], 1);
    col[pos] = s;
    wn[pos] = dis[s] * dis[d];
  }
}

// ---------------- x [G][Cin][L] f32 -> XT [G][L][Cin] bf16 ----------------
// grid (L/64, Cin/64, G)
__global__ __launch_bounds__(256) void trans_k(const float* __restrict__ X,
                                               u16* __restrict__ XT, int Cin) {
  __shared__ float T[64][65];  // [ci_local][node_local]
  const int g = blockIdx.z;
  const int n0 = blockIdx.x * 64;
  const int c0 = blockIdx.y * 64;
  const int tr = threadIdx.x >> 4;
  const int tc = (threadIdx.x & 15) * 4;
#pragma unroll
  for (int p = 0; p < 4; ++p) {
    int ci = c0 + tr + p * 16;
    float4 v = *reinterpret_cast<const float4*>(&X[((size_t)g * Cin + ci) * LNODES + n0 + tc]);
    T[tr + p * 16][tc + 0] = v.x; T[tr + p * 16][tc + 1] = v.y;
    T[tr + p * 16][tc + 2] = v.z; T[tr + p * 16][tc + 3] = v.w;
  }
  __syncthreads();
#pragma unroll
  for (int p = 0; p < 4; ++p) {
    int nd = tr + p * 16;
    uint2 o = {pk2(T[tc + 0][nd], T[tc + 1][nd]), pk2(T[tc + 2][nd], T[tc + 3][nd])};
    *reinterpret_cast<uint2*>(&XT[((size_t)g * LNODES + n0 + nd) * Cin + c0 + tc]) = o;
  }
}

// ---------------- W [Ci][256] f32 -> WbT [256][Ci] bf16 ----------------
// grid (256/64, Ci/64)
__global__ __launch_bounds__(256) void cvtw_k(const float* __restrict__ W,
                                              u16* __restrict__ WbT, int Ci) {
  __shared__ float T[64][65];  // [ci_local][co_local]
  const int co0 = blockIdx.x * 64;
  const int ci0 = blockIdx.y * 64;
  const int tr = threadIdx.x >> 4;
  const int tc = (threadIdx.x & 15) * 4;
#pragma unroll
  for (int p = 0; p < 4; ++p) {
    int ci = ci0 + tr + p * 16;
    float4 v = *reinterpret_cast<const float4*>(&W[(size_t)ci * NCOUT + co0 + tc]);
    T[tr + p * 16][tc + 0] = v.x; T[tr + p * 16][tc + 1] = v.y;
    T[tr + p * 16][tc + 2] = v.z; T[tr + p * 16][tc + 3] = v.w;
  }
  __syncthreads();
#pragma unroll
  for (int p = 0; p < 4; ++p) {
    int co = tr + p * 16;
    uint2 o = {pk2(T[tc + 0][co], T[tc + 1][co]), pk2(T[tc + 2][co], T[tc + 3][co])};
    *reinterpret_cast<uint2*>(&WbT[(size_t)(co0 + co) * Ci + ci0 + tc]) = o;
  }
}

// ---------------- max-pool over N=8, bf16, flat [4][8][per] ----------------
__global__ __launch_bounds__(256) void pool_bf_k(const u16* __restrict__ X,
                                                 u16* __restrict__ XP, int per) {
  int i = blockIdx.x * 256 + threadIdx.x;
  size_t f = (size_t)i * 8;
  int b = (int)(f / per);
  size_t rem = f - (size_t)b * per;
  const u16* base = X + (size_t)b * 8 * per + rem;
  uint4 u = *reinterpret_cast<const uint4*>(base);
  float m0 = blo(u.x), m1 = bhi(u.x), m2 = blo(u.y), m3 = bhi(u.y);
  float m4 = blo(u.z), m5 = bhi(u.z), m6 = blo(u.w), m7 = bhi(u.w);
#pragma unroll
  for (int j = 1; j < 8; ++j) {
    uint4 v = *reinterpret_cast<const uint4*>(base + (size_t)j * per);
    m0 = fmaxf(m0, blo(v.x)); m1 = fmaxf(m1, bhi(v.x));
    m2 = fmaxf(m2, blo(v.y)); m3 = fmaxf(m3, bhi(v.y));
    m4 = fmaxf(m4, blo(v.z)); m5 = fmaxf(m5, bhi(v.z));
    m6 = fmaxf(m6, blo(v.w)); m7 = fmaxf(m7, bhi(v.w));
  }
  uint4 o = {pk2(m0, m1), pk2(m2, m3), pk2(m4, m5), pk2(m6, m7)};
  *reinterpret_cast<uint4*>(XP + (size_t)b * per + rem) = o;
}

// ---------------- bf16 MFMA GEMM ----------------
// HW[g,node,co] bf16 = X[g,node,ci] bf16 @ WbT[co,ci] bf16  (fp32 acc)
// 128x128 block tile, 4 waves in 2x2, each wave 64x64 via 4x4 frags of 16x16x32.
__global__ __launch_bounds__(256) void gemm_bf_k(const u16* __restrict__ X,
                                                 const u16* __restrict__ WbT,
                                                 u16* __restrict__ HW, int Cin) {
  __shared__ u16 smem[17408];      // 34816 B: K-loop uses 2x[128][40]; epilogue [128][136]
  u16* Wsh = smem;                 // [128][40] (pad 8 bf16)
  u16* Xsh = smem + 128 * 40;
  const int g = blockIdx.z;
  const int n0 = blockIdx.x * 128;
  const int c0 = blockIdx.y * 128;
  const int t = threadIdx.x;
  const int wv = t >> 6;
  const int lane = t & 63;
  const int q = lane >> 4, l = lane & 15;
  const int wm = wv >> 1, wn = wv & 1;  // co-half, node-half
  f32x4 zero = {0.f, 0.f, 0.f, 0.f};
  f32x4 acc[4][4];
#pragma unroll
  for (int i = 0; i < 4; ++i)
#pragma unroll
    for (int j = 0; j < 4; ++j) acc[i][j] = zero;
  const int r0 = t >> 2;        // 0..63: tile row
  const int seg = (t & 3) * 8;  // k sub-offset (bf16)
  const u16* Wg = WbT + (size_t)(c0 + r0) * Cin + seg;
  const u16* Xg = X + ((size_t)g * LNODES + n0 + r0) * Cin + seg;
  for (int k0 = 0; k0 < Cin; k0 += 32) {
    uint4 w0 = *reinterpret_cast<const uint4*>(Wg + k0);
    uint4 w1 = *reinterpret_cast<const uint4*>(Wg + (size_t)64 * Cin + k0);
    uint4 x0 = *reinterpret_cast<const uint4*>(Xg + k0);
    uint4 x1 = *reinterpret_cast<const uint4*>(Xg + (size_t)64 * Cin + k0);
    __syncthreads();
    *reinterpret_cast<uint4*>(&Wsh[r0 * 40 + seg]) = w0;
    *reinterpret_cast<uint4*>(&Wsh[(r0 + 64) * 40 + seg]) = w1;
    *reinterpret_cast<uint4*>(&Xsh[r0 * 40 + seg]) = x0;
    *reinterpret_cast<uint4*>(&Xsh[(r0 + 64) * 40 + seg]) = x1;
    __syncthreads();
    bf16x8 af[4], bx[4];
#pragma unroll
    for (int fi = 0; fi < 4; ++fi)
      af[fi] = *reinterpret_cast<const bf16x8*>(&Wsh[(wm * 64 + fi * 16 + l) * 40 + q * 8]);
#pragma unroll
    for (int fj = 0; fj < 4; ++fj)
      bx[fj] = *reinterpret_cast<const bf16x8*>(&Xsh[(wn * 64 + fj * 16 + l) * 40 + q * 8]);
#pragma unroll
    for (int fi = 0; fi < 4; ++fi)
#pragma unroll
      for (int fj = 0; fj < 4; ++fj)
        acc[fi][fj] = __builtin_amdgcn_mfma_f32_16x16x32_bf16(af[fi], bx[fj], acc[fi][fj], 0, 0, 0);
  }
  __syncthreads();
  // epilogue: D row = co(q*4+reg), col = node(l). Repack via LDS -> coalesced stores.
  u16* Csh = smem;  // [128][136] ushort
#pragma unroll
  for (int fi = 0; fi < 4; ++fi) {
#pragma unroll
    for (int fj = 0; fj < 4; ++fj) {
      int co_l = wm * 64 + fi * 16 + q * 4;
      int nd_l = wn * 64 + fj * 16 + l;
      uint2 pkd = {pk2(acc[fi][fj][0], acc[fi][fj][1]),
                   pk2(acc[fi][fj][2], acc[fi][fj][3])};
      *reinterpret_cast<uint2*>(&Csh[nd_l * 136 + co_l]) = pkd;
    }
  }
  __syncthreads();
#pragma unroll
  for (int p = 0; p < 8; ++p) {
    int idx = p * 256 + t;
    int nd = idx >> 4;
    int c8 = (idx & 15) * 8;
    uint4 v = *reinterpret_cast<const uint4*>(&Csh[nd * 136 + c8]);
    *reinterpret_cast<uint4*>(&HW[((size_t)g * LNODES + n0 + nd) * NCOUT + c0 + c8]) = v;
  }
}

// ---------------- GCN aggregation, bf16 IO, edge loop unrolled x4 ----------------
// lane = 4 channels (uint2); wave covers the 256-ch row (512B coalesced).
// Edge loop unrolled by 4 with independent gathers -> 4 loads in flight/wave
// (was 1: serial col->gather->waitcnt chain made the kernel latency-bound).
template <int NG>
__global__ __launch_bounds__(256) void agg_bf_k(const u16* __restrict__ HW,
                                                const int* __restrict__ col,
                                                const float* __restrict__ wn,
                                                const int* __restrict__ rp,
                                                const float* __restrict__ selfn,
                                                u16* __restrict__ AGG,
                                                float* __restrict__ sum,
                                                float* __restrict__ sq) {
  int bid = blockIdx.x;
  int g, chunk;
  if (NG == GBIG) {
    int slot = bid >> 3;
    g = (bid & 7) + 8 * (slot >> 6);
    chunk = slot & 63;
  } else {
    g = bid & (NG - 1);
    chunk = bid >> 2;
  }
  const int d0 = chunk * ND;
  const int t = threadIdx.x;
  const int wv = t >> 6;
  const int lc = (t & 63) * 4;
  const u16* base = HW + (size_t)g * LNODES * NCOUT;
  float4 s = {0.f, 0.f, 0.f, 0.f}, qq = {0.f, 0.f, 0.f, 0.f};
  for (int i = wv; i < ND; i += 4) {
    int d = d0 + i;
    int e0 = rp[d], e1 = rp[d + 1];
    float sw = selfn[d];
    uint2 u = *reinterpret_cast<const uint2*>(&base[(size_t)d * NCOUT + lc]);
    float4 a = {sw * blo(u.x), sw * bhi(u.x), sw * blo(u.y), sw * bhi(u.y)};
    int e = e0;
    const int e4 = e0 + ((e1 - e0) & ~3);
    for (; e < e4; e += 4) {
      int c0i = col[e + 0], c1i = col[e + 1], c2i = col[e + 2], c3i = col[e + 3];
      float w0 = wn[e + 0], w1 = wn[e + 1], w2 = wn[e + 2], w3 = wn[e + 3];
      uint2 v0 = *reinterpret_cast<const uint2*>(&base[(size_t)c0i * NCOUT + lc]);
      uint2 v1 = *reinterpret_cast<const uint2*>(&base[(size_t)c1i * NCOUT + lc]);
      uint2 v2 = *reinterpret_cast<const uint2*>(&base[(size_t)c2i * NCOUT + lc]);
      uint2 v3 = *reinterpret_cast<const uint2*>(&base[(size_t)c3i * NCOUT + lc]);
      a.x += w0 * blo(v0.x); a.y += w0 * bhi(v0.x);
      a.z += w0 * blo(v0.y); a.w += w0 * bhi(v0.y);
      a.x += w1 * blo(v1.x); a.y += w1 * bhi(v1.x);
      a.z += w1 * blo(v1.y); a.w += w1 * bhi(v1.y);
      a.x += w2 * blo(v2.x); a.y += w2 * bhi(v2.x);
      a.z += w2 * blo(v2.y); a.w += w2 * bhi(v2.y);
      a.x += w3 * blo(v3.x); a.y += w3 * bhi(v3.x);
      a.z += w3 * blo(v3.y); a.w += w3 * bhi(v3.y);
    }
    for (; e < e1; ++e) {
      float w = wn[e];
      uint2 v = *reinterpret_cast<const uint2*>(&base[(size_t)col[e] * NCOUT + lc]);
      a.x += w * blo(v.x); a.y += w * bhi(v.x);
      a.z += w * blo(v.y); a.w += w * bhi(v.y);
    }
    uint2 o = {pk2(a.x, a.y), pk2(a.z, a.w)};
    *reinterpret_cast<uint2*>(&AGG[((size_t)g * LNODES + d) * NCOUT + lc]) = o;
    s.x += a.x; s.y += a.y; s.z += a.z; s.w += a.w;
    qq.x += a.x * a.x; qq.y += a.y * a.y; qq.z += a.z * a.z; qq.w += a.w * a.w;
  }
  __shared__ float lsum[4][NCOUT], lsq[4][NCOUT];
  *reinterpret_cast<float4*>(&lsum[wv][lc]) = s;
  *reinterpret_cast<float4*>(&lsq[wv][lc]) = qq;
  __syncthreads();
  float ts = lsum[0][t] + lsum[1][t] + lsum[2][t] + lsum[3][t];
  float tq = lsq[0][t] + lsq[1][t] + lsq[2][t] + lsq[3][t];
  atomicAdd(&sum[t], ts);
  atomicAdd(&sq[t], tq);
}

// ---------------- BN finalize ----------------
__global__ __launch_bounds__(256) void bnfinal_k(const float* __restrict__ sum1,
                                                 const float* __restrict__ sq1,
                                                 const float* __restrict__ sum2,
                                                 const float* __restrict__ sq2,
                                                 const float* __restrict__ ga,
                                                 const float* __restrict__ be,
                                                 const float* __restrict__ gs,
                                                 const float* __restrict__ bes,
                                                 float* __restrict__ k1,
                                                 float* __restrict__ k2,
                                                 float* __restrict__ cc) {
  int co = threadIdx.x;
  const float c1 = (float)(GBIG * LNODES), c2 = (float)(GSM * LNODES);
  float mA = sum1[co] / c1;
  float vA = sq1[co] / c1 - mA * mA;
  float kA = ga[co] * rsqrtf(vA + BN_EPS);
  float mB = sum2[co] / c2;
  float vB = sq2[co] / c2 - mB * mB;
  float kB = gs[co] * rsqrtf(vB + BN_EPS);
  k1[co] = kA;
  k2[co] = kB;
  cc[co] = be[co] - kA * mA + bes[co] - kB * mB;
}

// ---------------- fused BN+BN+add+ReLU, bf16 node-major (layers 0,1) ----------------
__global__ __launch_bounds__(256) void fuse_bf_k(const u16* __restrict__ A1,
                                                 const u16* __restrict__ A2,
                                                 const float* __restrict__ k1,
                                                 const float* __restrict__ k2,
                                                 const float* __restrict__ cc,
                                                 u16* __restrict__ O) {
  size_t i = (size_t)blockIdx.x * 256 + threadIdx.x;
  size_t f = i * 8;
  int co = (int)(f & (NCOUT - 1));
  int d = (int)((f >> 8) & (LNODES - 1));
  int g = (int)(f >> 19);
  int b = g >> 3;
  uint4 a1 = *reinterpret_cast<const uint4*>(&A1[f]);
  uint4 a2 = *reinterpret_cast<const uint4*>(&A2[((size_t)b * LNODES + d) * NCOUT + co]);
  float4 K1a = *reinterpret_cast<const float4*>(&k1[co]);
  float4 K1b = *reinterpret_cast<const float4*>(&k1[co + 4]);
  float4 K2a = *reinterpret_cast<const float4*>(&k2[co]);
  float4 K2b = *reinterpret_cast<const float4*>(&k2[co + 4]);
  float4 Ca = *reinterpret_cast<const float4*>(&cc[co]);
  float4 Cb = *reinterpret_cast<const float4*>(&cc[co + 4]);
  float o0 = fmaxf(K1a.x * blo(a1.x) + K2a.x * blo(a2.x) + Ca.x, 0.f);
  float o1 = fmaxf(K1a.y * bhi(a1.x) + K2a.y * bhi(a2.x) + Ca.y, 0.f);
  float o2 = fmaxf(K1a.z * blo(a1.y) + K2a.z * blo(a2.y) + Ca.z, 0.f);
  float o3 = fmaxf(K1a.w * bhi(a1.y) + K2a.w * bhi(a2.y) + Ca.w, 0.f);
  float o4 = fmaxf(K1b.x * blo(a1.z) + K2b.x * blo(a2.z) + Cb.x, 0.f);
  float o5 = fmaxf(K1b.y * bhi(a1.z) + K2b.y * bhi(a2.z) + Cb.y, 0.f);
  float o6 = fmaxf(K1b.z * blo(a1.w) + K2b.z * blo(a2.w) + Cb.z, 0.f);
  float o7 = fmaxf(K1b.w * bhi(a1.w) + K2b.w * bhi(a2.w) + Cb.w, 0.f);
  uint4 ou = {pk2(o0, o1), pk2(o2, o3), pk2(o4, o5), pk2(o6, o7)};
  *reinterpret_cast<uint4*>(&O[f]) = ou;
}

// ---------------- layer 2: fuse + transpose to channel-major fp32 d_out ----------------
// grid (L/64, 256/64, G)
__global__ __launch_bounds__(256) void fuse_tr_bf_k(const u16* __restrict__ A1,
                                                    const u16* __restrict__ A2,
                                                    const float* __restrict__ k1,
                                                    const float* __restrict__ k2,
                                                    const float* __restrict__ cc,
                                                    float* __restrict__ O) {
  __shared__ float T[64][65];  // [node_local][co_local]
  const int g = blockIdx.z;
  const int d0 = blockIdx.x * 64;
  const int c0 = blockIdx.y * 64;
  const int b = g >> 3;
  const int tr = threadIdx.x >> 4;
  const int tc = (threadIdx.x & 15) * 4;
  float4 K1 = *reinterpret_cast<const float4*>(&k1[c0 + tc]);
  float4 K2 = *reinterpret_cast<const float4*>(&k2[c0 + tc]);
  float4 CC = *reinterpret_cast<const float4*>(&cc[c0 + tc]);
#pragma unroll
  for (int p = 0; p < 4; ++p) {
    int d = d0 + tr + p * 16;
    uint2 a1 = *reinterpret_cast<const uint2*>(&A1[((size_t)g * LNODES + d) * NCOUT + c0 + tc]);
    uint2 a2 = *reinterpret_cast<const uint2*>(&A2[((size_t)b * LNODES + d) * NCOUT + c0 + tc]);
    T[tr + p * 16][tc + 0] = fmaxf(K1.x * blo(a1.x) + K2.x * blo(a2.x) + CC.x, 0.f);
    T[tr + p * 16][tc + 1] = fmaxf(K1.y * bhi(a1.x) + K2.y * bhi(a2.x) + CC.y, 0.f);
    T[tr + p * 16][tc + 2] = fmaxf(K1.z * blo(a1.y) + K2.z * blo(a2.y) + CC.z, 0.f);
    T[tr + p * 16][tc + 3] = fmaxf(K1.w * bhi(a1.y) + K2.w * bhi(a2.y) + CC.w, 0.f);
  }
  __syncthreads();
#pragma unroll
  for (int p = 0; p < 4; ++p) {
    int c = tr + p * 16;
    float4 o = {T[tc + 0][c], T[tc + 1][c], T[tc + 2][c], T[tc + 3][c]};
    *reinterpret_cast<float4*>(&O[((size_t)g * NCOUT + c0 + c) * LNODES + d0 + tc]) = o;
  }
}

// ---------------- launch ----------------

extern "C" void kernel_launch(void* const* d_in, const int* in_sizes, int n_in,
                              void* d_out, int out_size, void* d_ws, size_t ws_size,
                              hipStream_t stream) {
  const float* x_in = (const float*)d_in[0];
  const int* ei = (const int*)d_in[1];
  const float* W[3]   = {(const float*)d_in[2],  (const float*)d_in[4],  (const float*)d_in[6]};
  const float* Wsym[3]= {(const float*)d_in[8],  (const float*)d_in[10], (const float*)d_in[12]};
  const float* ga[3]  = {(const float*)d_in[14], (const float*)d_in[16], (const float*)d_in[18]};
  const float* be[3]  = {(const float*)d_in[15], (const float*)d_in[17], (const float*)d_in[19]};
  const float* gs[3]  = {(const float*)d_in[20], (const float*)d_in[22], (const float*)d_in[24]};
  const float* bes[3] = {(const float*)d_in[21], (const float*)d_in[23], (const float*)d_in[25]};

  const size_t EBIG = (size_t)GBIG * LNODES * NCOUT;  // 16.7M elems
  const size_t ESM = (size_t)GSM * LNODES * NCOUT;
  char* p = (char*)d_ws;
  u16* Xact = (u16*)p; p += EBIG * 2;   // 32 MiB: inter-layer activations (bf16)
  u16* AGG1 = (u16*)p; p += EBIG * 2;   // 32 MiB
  u16* agg2 = (u16*)p; p += ESM * 2;    // 4 MiB
  u16* WbT[3], *WsT[3];
  for (int i = 0; i < 3; ++i) { WbT[i] = (u16*)p; p += NCOUT * NCOUT * 2; }
  for (int i = 0; i < 3; ++i) { WsT[i] = (u16*)p; p += NCOUT * NCOUT * 2; }
  int*   col  = (int*)p;   p += NEDGE * 4;
  float* wn   = (float*)p; p += NEDGE * 4;
  int*   rp   = (int*)p;   p += 2064 * 4;
  float* dis  = (float*)p; p += LNODES * 4;
  float* selfn= (float*)p; p += LNODES * 4;
  char* zbase = p;
  float* deg  = (float*)p; p += LNODES * 4;
  int*   cnt  = (int*)p;   p += LNODES * 4;
  int*   fillc= (int*)p;   p += LNODES * 4;
  size_t zsize = (size_t)(p - zbase);
  char* statbase = p;
  float* sum1 = (float*)p; p += 1024;
  float* sq1  = (float*)p; p += 1024;
  float* sum2 = (float*)p; p += 1024;
  float* sq2  = (float*)p; p += 1024;
  float* k1 = (float*)p; p += 1024;
  float* k2 = (float*)p; p += 1024;
  float* cc = (float*)p; p += 1024;
  // aliases (lifetime-disjoint):
  u16* XT0 = Xact;                         // layer-0 node-major input (16 MiB)
  u16* xp  = AGG1;                         // pooled input (dead before agg_big writes)
  u16* hw2 = AGG1 + 2 * 1024 * 1024;       // sym GEMM out (read by agg_sm before agg_big)
  u16* HW1 = (u16*)d_out;                  // big GEMM out lives in d_out (dead by fuse time)

  // ---- CSR + weight conversion + input transpose ----
  hipMemsetAsync(zbase, 0, zsize, stream);
  count_deg_k<<<NEDGE / 256, 256, 0, stream>>>(ei, deg, cnt);
  dis_k<<<LNODES / 256, 256, 0, stream>>>(deg, dis, selfn);
  scan_k<<<1, 256, 0, stream>>>(cnt, rp);
  fill_k<<<NEDGE / 256, 256, 0, stream>>>(ei, rp, fillc, dis, col, wn);
  for (int i = 0; i < 3; ++i) {
    int Ci = (i == 0) ? 128 : 256;
    cvtw_k<<<dim3(NCOUT / 64, Ci / 64), 256, 0, stream>>>(W[i], WbT[i], Ci);
    cvtw_k<<<dim3(NCOUT / 64, Ci / 64), 256, 0, stream>>>(Wsym[i], WsT[i], Ci);
  }
  trans_k<<<dim3(LNODES / 64, 128 / 64, GBIG), 256, 0, stream>>>(x_in, XT0, 128);

  for (int l = 0; l < 3; ++l) {
    const int Cin = (l == 0) ? 128 : 256;
    const u16* Xin = (l == 0) ? XT0 : Xact;
    const int per = Cin * LNODES;
    pool_bf_k<<<GSM * per / 8 / 256, 256, 0, stream>>>(Xin, xp, per);
    gemm_bf_k<<<dim3(LNODES / 128, NCOUT / 128, GSM), 256, 0, stream>>>(xp, WsT[l], hw2, Cin);
    gemm_bf_k<<<dim3(LNODES / 128, NCOUT / 128, GBIG), 256, 0, stream>>>(Xin, WbT[l], HW1, Cin);
    hipMemsetAsync(statbase, 0, 4096, stream);
    // agg_sm first: it reads hw2 which aliases AGG1 (clobbered by agg_big)
    agg_bf_k<GSM><<<(LNODES / ND) * GSM, 256, 0, stream>>>(hw2, col, wn, rp, selfn,
                                                           agg2, sum2, sq2);
    agg_bf_k<GBIG><<<(LNODES / ND) * GBIG, 256, 0, stream>>>(HW1, col, wn, rp, selfn,
                                                             AGG1, sum1, sq1);
    bnfinal_k<<<1, 256, 0, stream>>>(sum1, sq1, sum2, sq2,
                                     ga[l], be[l], gs[l], bes[l], k1, k2, cc);
    if (l < 2) {
      fuse_bf_k<<<(int)(EBIG / 8 / 256), 256, 0, stream>>>(AGG1, agg2, k1, k2, cc, Xact);
    } else {
      fuse_tr_bf_k<<<dim3(LNODES / 64, NCOUT / 64, GBIG), 256, 0, stream>>>(
          AGG1, agg2, k1, k2, cc, (float*)d_out);
    }
  }
}

// Round 7
// 466.895 us; speedup vs baseline: 4.7475x; 1.2908x over previous
//
#include <hip/hip_runtime.h>
#include <math.h>

#define LNODES 2048
#define NEDGE 16384
#define GBIG 32
#define GSM 4
#define NCOUT 256
#define BN_EPS 1e-5f
#define ND 32  // dst nodes per agg block

typedef unsigned short u16;
typedef __attribute__((ext_vector_type(8))) short bf16x8;
typedef __attribute__((ext_vector_type(4))) float f32x4;

__device__ __forceinline__ u16 f2bf(float f) {
  unsigned u = __float_as_uint(f);
  u += 0x7fffu + ((u >> 16) & 1u);  // RNE
  return (u16)(u >> 16);
}
__device__ __forceinline__ unsigned pk2(float a, float b) {  // a->lo, b->hi
  unsigned ua = __float_as_uint(a); ua += 0x7fffu + ((ua >> 16) & 1u);
  unsigned ub = __float_as_uint(b); ub += 0x7fffu + ((ub >> 16) & 1u);
  return (ua >> 16) | (ub & 0xffff0000u);
}
__device__ __forceinline__ float blo(unsigned u) { return __uint_as_float(u << 16); }
__device__ __forceinline__ float bhi(unsigned u) { return __uint_as_float(u & 0xffff0000u); }

// ---------------- setup: degree, dis, CSR ----------------

__global__ __launch_bounds__(256) void count_deg_k(const int* __restrict__ ei,
                                                   float* __restrict__ deg,
                                                   int* __restrict__ cnt) {
  int e = blockIdx.x * 256 + threadIdx.x;
  if (e < NEDGE) {
    int d = ei[NEDGE + e];
    atomicAdd(&deg[d], 1.0f);
    atomicAdd(&cnt[d], 1);
  }
}

__global__ __launch_bounds__(256) void dis_k(const float* __restrict__ deg,
                                             float* __restrict__ dis,
                                             float* __restrict__ selfn) {
  int i = blockIdx.x * 256 + threadIdx.x;
  if (i < LNODES) {
    float di = rsqrtf(deg[i] + 2.0f);  // improved=True self loop weight 2
    dis[i] = di;
    selfn[i] = 2.0f * di * di;
  }
}

__global__ __launch_bounds__(256) void scan_k(const int* __restrict__ cnt,
                                              int* __restrict__ rp) {
  __shared__ int part[256];
  int t = threadIdx.x;
  int base = t * 8;
  int loc[8];
  int s = 0;
#pragma unroll
  for (int j = 0; j < 8; ++j) { loc[j] = s; s += cnt[base + j]; }
  part[t] = s;
  __syncthreads();
  for (int off = 1; off < 256; off <<= 1) {
    int v = (t >= off) ? part[t - off] : 0;
    __syncthreads();
    part[t] += v;
    __syncthreads();
  }
  int excl = (t == 0) ? 0 : part[t - 1];
#pragma unroll
  for (int j = 0; j < 8; ++j) rp[base + j] = excl + loc[j];
  if (t == 255) rp[LNODES] = part[255];
}

__global__ __launch_bounds__(256) void fill_k(const int* __restrict__ ei,
                                              const int* __restrict__ rp,
                                              int* __restrict__ fillc,
                                              const float* __restrict__ dis,
                                              int* __restrict__ col,
                                              float* __restrict__ wn) {
  int e = blockIdx.x * 256 + threadIdx.x;
  if (e < NEDGE) {
    int s = ei[e], d = ei[NEDGE + e];
    int pos = rp[d] + atomicAdd(&fillc[d], 1);
    col[pos] = s;
    wn[pos] = dis[s] * dis[d];
  }
}

// ---------------- x [G][Cin][L] f32 -> XT [G][L][Cin] bf16 ----------------
// grid (L/64, Cin/64, G)
__global__ __launch_bounds__(256) void trans_k(const float* __restrict__ X,
                                               u16* __restrict__ XT, int Cin) {
  __shared__ float T[64][65];  // [ci_local][node_local]
  const int g = blockIdx.z;
  const int n0 = blockIdx.x * 64;
  const int c0 = blockIdx.y * 64;
  const int tr = threadIdx.x >> 4;
  const int tc = (threadIdx.x & 15) * 4;
#pragma unroll
  for (int p = 0; p < 4; ++p) {
    int ci = c0 + tr + p * 16;
    float4 v = *reinterpret_cast<const float4*>(&X[((size_t)g * Cin + ci) * LNODES + n0 + tc]);
    T[tr + p * 16][tc + 0] = v.x; T[tr + p * 16][tc + 1] = v.y;
    T[tr + p * 16][tc + 2] = v.z; T[tr + p * 16][tc + 3] = v.w;
  }
  __syncthreads();
#pragma unroll
  for (int p = 0; p < 4; ++p) {
    int nd = tr + p * 16;
    uint2 o = {pk2(T[tc + 0][nd], T[tc + 1][nd]), pk2(T[tc + 2][nd], T[tc + 3][nd])};
    *reinterpret_cast<uint2*>(&XT[((size_t)g * LNODES + n0 + nd) * Cin + c0 + tc]) = o;
  }
}

// ---------------- W [Ci][256] f32 -> WbT [256][Ci] bf16 ----------------
// grid (256/64, Ci/64)
__global__ __launch_bounds__(256) void cvtw_k(const float* __restrict__ W,
                                              u16* __restrict__ WbT, int Ci) {
  __shared__ float T[64][65];  // [ci_local][co_local]
  const int co0 = blockIdx.x * 64;
  const int ci0 = blockIdx.y * 64;
  const int tr = threadIdx.x >> 4;
  const int tc = (threadIdx.x & 15) * 4;
#pragma unroll
  for (int p = 0; p < 4; ++p) {
    int ci = ci0 + tr + p * 16;
    float4 v = *reinterpret_cast<const float4*>(&W[(size_t)ci * NCOUT + co0 + tc]);
    T[tr + p * 16][tc + 0] = v.x; T[tr + p * 16][tc + 1] = v.y;
    T[tr + p * 16][tc + 2] = v.z; T[tr + p * 16][tc + 3] = v.w;
  }
  __syncthreads();
#pragma unroll
  for (int p = 0; p < 4; ++p) {
    int co = tr + p * 16;
    uint2 o = {pk2(T[tc + 0][co], T[tc + 1][co]), pk2(T[tc + 2][co], T[tc + 3][co])};
    *reinterpret_cast<uint2*>(&WbT[(size_t)(co0 + co) * Ci + ci0 + tc]) = o;
  }
}

// ---------------- max-pool over N=8, bf16, flat [4][8][per] ----------------
__global__ __launch_bounds__(256) void pool_bf_k(const u16* __restrict__ X,
                                                 u16* __restrict__ XP, int per) {
  int i = blockIdx.x * 256 + threadIdx.x;
  size_t f = (size_t)i * 8;
  int b = (int)(f / per);
  size_t rem = f - (size_t)b * per;
  const u16* base = X + (size_t)b * 8 * per + rem;
  uint4 u = *reinterpret_cast<const uint4*>(base);
  float m0 = blo(u.x), m1 = bhi(u.x), m2 = blo(u.y), m3 = bhi(u.y);
  float m4 = blo(u.z), m5 = bhi(u.z), m6 = blo(u.w), m7 = bhi(u.w);
#pragma unroll
  for (int j = 1; j < 8; ++j) {
    uint4 v = *reinterpret_cast<const uint4*>(base + (size_t)j * per);
    m0 = fmaxf(m0, blo(v.x)); m1 = fmaxf(m1, bhi(v.x));
    m2 = fmaxf(m2, blo(v.y)); m3 = fmaxf(m3, bhi(v.y));
    m4 = fmaxf(m4, blo(v.z)); m5 = fmaxf(m5, bhi(v.z));
    m6 = fmaxf(m6, blo(v.w)); m7 = fmaxf(m7, bhi(v.w));
  }
  uint4 o = {pk2(m0, m1), pk2(m2, m3), pk2(m4, m5), pk2(m6, m7)};
  *reinterpret_cast<uint4*>(XP + (size_t)b * per + rem) = o;
}

// ---------------- bf16 MFMA GEMM ----------------
// HW[g,node,co] bf16 = X[g,node,ci] bf16 @ WbT[co,ci] bf16  (fp32 acc)
// 128x128 block tile, 4 waves in 2x2, each wave 64x64 via 4x4 frags of 16x16x32.
__global__ __launch_bounds__(256) void gemm_bf_k(const u16* __restrict__ X,
                                                 const u16* __restrict__ WbT,
                                                 u16* __restrict__ HW, int Cin) {
  __shared__ u16 smem[17408];      // 34816 B: K-loop uses 2x[128][40]; epilogue [128][136]
  u16* Wsh = smem;                 // [128][40] (pad 8 bf16)
  u16* Xsh = smem + 128 * 40;
  const int g = blockIdx.z;
  const int n0 = blockIdx.x * 128;
  const int c0 = blockIdx.y * 128;
  const int t = threadIdx.x;
  const int wv = t >> 6;
  const int lane = t & 63;
  const int q = lane >> 4, l = lane & 15;
  const int wm = wv >> 1, wn = wv & 1;  // co-half, node-half
  f32x4 zero = {0.f, 0.f, 0.f, 0.f};
  f32x4 acc[4][4];
#pragma unroll
  for (int i = 0; i < 4; ++i)
#pragma unroll
    for (int j = 0; j < 4; ++j) acc[i][j] = zero;
  const int r0 = t >> 2;        // 0..63: tile row
  const int seg = (t & 3) * 8;  // k sub-offset (bf16)
  const u16* Wg = WbT + (size_t)(c0 + r0) * Cin + seg;
  const u16* Xg = X + ((size_t)g * LNODES + n0 + r0) * Cin + seg;
  for (int k0 = 0; k0 < Cin; k0 += 32) {
    uint4 w0 = *reinterpret_cast<const uint4*>(Wg + k0);
    uint4 w1 = *reinterpret_cast<const uint4*>(Wg + (size_t)64 * Cin + k0);
    uint4 x0 = *reinterpret_cast<const uint4*>(Xg + k0);
    uint4 x1 = *reinterpret_cast<const uint4*>(Xg + (size_t)64 * Cin + k0);
    __syncthreads();
    *reinterpret_cast<uint4*>(&Wsh[r0 * 40 + seg]) = w0;
    *reinterpret_cast<uint4*>(&Wsh[(r0 + 64) * 40 + seg]) = w1;
    *reinterpret_cast<uint4*>(&Xsh[r0 * 40 + seg]) = x0;
    *reinterpret_cast<uint4*>(&Xsh[(r0 + 64) * 40 + seg]) = x1;
    __syncthreads();
    bf16x8 af[4], bx[4];
#pragma unroll
    for (int fi = 0; fi < 4; ++fi)
      af[fi] = *reinterpret_cast<const bf16x8*>(&Wsh[(wm * 64 + fi * 16 + l) * 40 + q * 8]);
#pragma unroll
    for (int fj = 0; fj < 4; ++fj)
      bx[fj] = *reinterpret_cast<const bf16x8*>(&Xsh[(wn * 64 + fj * 16 + l) * 40 + q * 8]);
#pragma unroll
    for (int fi = 0; fi < 4; ++fi)
#pragma unroll
      for (int fj = 0; fj < 4; ++fj)
        acc[fi][fj] = __builtin_amdgcn_mfma_f32_16x16x32_bf16(af[fi], bx[fj], acc[fi][fj], 0, 0, 0);
  }
  __syncthreads();
  // epilogue: D row = co(q*4+reg), col = node(l). Repack via LDS -> coalesced stores.
  u16* Csh = smem;  // [128][136] ushort
#pragma unroll
  for (int fi = 0; fi < 4; ++fi) {
#pragma unroll
    for (int fj = 0; fj < 4; ++fj) {
      int co_l = wm * 64 + fi * 16 + q * 4;
      int nd_l = wn * 64 + fj * 16 + l;
      uint2 pkd = {pk2(acc[fi][fj][0], acc[fi][fj][1]),
                   pk2(acc[fi][fj][2], acc[fi][fj][3])};
      *reinterpret_cast<uint2*>(&Csh[nd_l * 136 + co_l]) = pkd;
    }
  }
  __syncthreads();
#pragma unroll
  for (int p = 0; p < 8; ++p) {
    int idx = p * 256 + t;
    int nd = idx >> 4;
    int c8 = (idx & 15) * 8;
    uint4 v = *reinterpret_cast<const uint4*>(&Csh[nd * 136 + c8]);
    *reinterpret_cast<uint4*>(&HW[((size_t)g * LNODES + n0 + nd) * NCOUT + c0 + c8]) = v;
  }
}

// ---------------- GCN aggregation, bf16 IO, unroll x4, XCD-sharded BN atomics ----------------
// lane = 4 channels (uint2); wave covers the 256-ch row (512B coalesced).
// BN-stat atomics sharded 8x by (bid&7): sum/sq are [8][256] — cuts per-line
// atomic chains 8x (2048 blocks all hammering 32 lines was the ~80us wall).
template <int NG>
__global__ __launch_bounds__(256) void agg_bf_k(const u16* __restrict__ HW,
                                                const int* __restrict__ col,
                                                const float* __restrict__ wn,
                                                const int* __restrict__ rp,
                                                const float* __restrict__ selfn,
                                                u16* __restrict__ AGG,
                                                float* __restrict__ sum,
                                                float* __restrict__ sq) {
  int bid = blockIdx.x;
  int g, chunk;
  if (NG == GBIG) {
    int slot = bid >> 3;
    g = (bid & 7) + 8 * (slot >> 6);
    chunk = slot & 63;
  } else {
    g = bid & (NG - 1);
    chunk = bid >> 2;
  }
  const int d0 = chunk * ND;
  const int t = threadIdx.x;
  const int wv = t >> 6;
  const int lc = (t & 63) * 4;
  const u16* base = HW + (size_t)g * LNODES * NCOUT;
  float4 s = {0.f, 0.f, 0.f, 0.f}, qq = {0.f, 0.f, 0.f, 0.f};
  for (int i = wv; i < ND; i += 4) {
    int d = d0 + i;
    int e0 = rp[d], e1 = rp[d + 1];
    float sw = selfn[d];
    uint2 u = *reinterpret_cast<const uint2*>(&base[(size_t)d * NCOUT + lc]);
    float4 a = {sw * blo(u.x), sw * bhi(u.x), sw * blo(u.y), sw * bhi(u.y)};
    int e = e0;
    const int e4 = e0 + ((e1 - e0) & ~3);
    for (; e < e4; e += 4) {
      int c0i = col[e + 0], c1i = col[e + 1], c2i = col[e + 2], c3i = col[e + 3];
      float w0 = wn[e + 0], w1 = wn[e + 1], w2 = wn[e + 2], w3 = wn[e + 3];
      uint2 v0 = *reinterpret_cast<const uint2*>(&base[(size_t)c0i * NCOUT + lc]);
      uint2 v1 = *reinterpret_cast<const uint2*>(&base[(size_t)c1i * NCOUT + lc]);
      uint2 v2 = *reinterpret_cast<const uint2*>(&base[(size_t)c2i * NCOUT + lc]);
      uint2 v3 = *reinterpret_cast<const uint2*>(&base[(size_t)c3i * NCOUT + lc]);
      a.x += w0 * blo(v0.x); a.y += w0 * bhi(v0.x);
      a.z += w0 * blo(v0.y); a.w += w0 * bhi(v0.y);
      a.x += w1 * blo(v1.x); a.y += w1 * bhi(v1.x);
      a.z += w1 * blo(v1.y); a.w += w1 * bhi(v1.y);
      a.x += w2 * blo(v2.x); a.y += w2 * bhi(v2.x);
      a.z += w2 * blo(v2.y); a.w += w2 * bhi(v2.y);
      a.x += w3 * blo(v3.x); a.y += w3 * bhi(v3.x);
      a.z += w3 * blo(v3.y); a.w += w3 * bhi(v3.y);
    }
    for (; e < e1; ++e) {
      float w = wn[e];
      uint2 v = *reinterpret_cast<const uint2*>(&base[(size_t)col[e] * NCOUT + lc]);
      a.x += w * blo(v.x); a.y += w * bhi(v.x);
      a.z += w * blo(v.y); a.w += w * bhi(v.y);
    }
    uint2 o = {pk2(a.x, a.y), pk2(a.z, a.w)};
    *reinterpret_cast<uint2*>(&AGG[((size_t)g * LNODES + d) * NCOUT + lc]) = o;
    s.x += a.x; s.y += a.y; s.z += a.z; s.w += a.w;
    qq.x += a.x * a.x; qq.y += a.y * a.y; qq.z += a.z * a.z; qq.w += a.w * a.w;
  }
  __shared__ float lsum[4][NCOUT], lsq[4][NCOUT];
  *reinterpret_cast<float4*>(&lsum[wv][lc]) = s;
  *reinterpret_cast<float4*>(&lsq[wv][lc]) = qq;
  __syncthreads();
  float ts = lsum[0][t] + lsum[1][t] + lsum[2][t] + lsum[3][t];
  float tq = lsq[0][t] + lsq[1][t] + lsq[2][t] + lsq[3][t];
  const int shard = (bid & 7) * NCOUT;
  atomicAdd(&sum[shard + t], ts);
  atomicAdd(&sq[shard + t], tq);
}

// ---------------- BN finalize (reads 8 shards per stat) ----------------
__global__ __launch_bounds__(256) void bnfinal_k(const float* __restrict__ sum1,
                                                 const float* __restrict__ sq1,
                                                 const float* __restrict__ sum2,
                                                 const float* __restrict__ sq2,
                                                 const float* __restrict__ ga,
                                                 const float* __restrict__ be,
                                                 const float* __restrict__ gs,
                                                 const float* __restrict__ bes,
                                                 float* __restrict__ k1,
                                                 float* __restrict__ k2,
                                                 float* __restrict__ cc) {
  int co = threadIdx.x;
  float sA = 0.f, qA = 0.f, sB = 0.f, qB = 0.f;
#pragma unroll
  for (int x = 0; x < 8; ++x) {
    sA += sum1[x * NCOUT + co];
    qA += sq1[x * NCOUT + co];
    sB += sum2[x * NCOUT + co];
    qB += sq2[x * NCOUT + co];
  }
  const float c1 = (float)(GBIG * LNODES), c2 = (float)(GSM * LNODES);
  float mA = sA / c1;
  float vA = qA / c1 - mA * mA;
  float kA = ga[co] * rsqrtf(vA + BN_EPS);
  float mB = sB / c2;
  float vB = qB / c2 - mB * mB;
  float kB = gs[co] * rsqrtf(vB + BN_EPS);
  k1[co] = kA;
  k2[co] = kB;
  cc[co] = be[co] - kA * mA + bes[co] - kB * mB;
}

// ---------------- fused BN+BN+add+ReLU, bf16 node-major (layers 0,1) ----------------
__global__ __launch_bounds__(256) void fuse_bf_k(const u16* __restrict__ A1,
                                                 const u16* __restrict__ A2,
                                                 const float* __restrict__ k1,
                                                 const float* __restrict__ k2,
                                                 const float* __restrict__ cc,
                                                 u16* __restrict__ O) {
  size_t i = (size_t)blockIdx.x * 256 + threadIdx.x;
  size_t f = i * 8;
  int co = (int)(f & (NCOUT - 1));
  int d = (int)((f >> 8) & (LNODES - 1));
  int g = (int)(f >> 19);
  int b = g >> 3;
  uint4 a1 = *reinterpret_cast<const uint4*>(&A1[f]);
  uint4 a2 = *reinterpret_cast<const uint4*>(&A2[((size_t)b * LNODES + d) * NCOUT + co]);
  float4 K1a = *reinterpret_cast<const float4*>(&k1[co]);
  float4 K1b = *reinterpret_cast<const float4*>(&k1[co + 4]);
  float4 K2a = *reinterpret_cast<const float4*>(&k2[co]);
  float4 K2b = *reinterpret_cast<const float4*>(&k2[co + 4]);
  float4 Ca = *reinterpret_cast<const float4*>(&cc[co]);
  float4 Cb = *reinterpret_cast<const float4*>(&cc[co + 4]);
  float o0 = fmaxf(K1a.x * blo(a1.x) + K2a.x * blo(a2.x) + Ca.x, 0.f);
  float o1 = fmaxf(K1a.y * bhi(a1.x) + K2a.y * bhi(a2.x) + Ca.y, 0.f);
  float o2 = fmaxf(K1a.z * blo(a1.y) + K2a.z * blo(a2.y) + Ca.z, 0.f);
  float o3 = fmaxf(K1a.w * bhi(a1.y) + K2a.w * bhi(a2.y) + Ca.w, 0.f);
  float o4 = fmaxf(K1b.x * blo(a1.z) + K2b.x * blo(a2.z) + Cb.x, 0.f);
  float o5 = fmaxf(K1b.y * bhi(a1.z) + K2b.y * bhi(a2.z) + Cb.y, 0.f);
  float o6 = fmaxf(K1b.z * blo(a1.w) + K2b.z * blo(a2.w) + Cb.z, 0.f);
  float o7 = fmaxf(K1b.w * bhi(a1.w) + K2b.w * bhi(a2.w) + Cb.w, 0.f);
  uint4 ou = {pk2(o0, o1), pk2(o2, o3), pk2(o4, o5), pk2(o6, o7)};
  *reinterpret_cast<uint4*>(&O[f]) = ou;
}

// ---------------- layer 2: fuse + transpose to channel-major fp32 d_out ----------------
// grid (L/64, 256/64, G)
__global__ __launch_bounds__(256) void fuse_tr_bf_k(const u16* __restrict__ A1,
                                                    const u16* __restrict__ A2,
                                                    const float* __restrict__ k1,
                                                    const float* __restrict__ k2,
                                                    const float* __restrict__ cc,
                                                    float* __restrict__ O) {
  __shared__ float T[64][65];  // [node_local][co_local]
  const int g = blockIdx.z;
  const int d0 = blockIdx.x * 64;
  const int c0 = blockIdx.y * 64;
  const int b = g >> 3;
  const int tr = threadIdx.x >> 4;
  const int tc = (threadIdx.x & 15) * 4;
  float4 K1 = *reinterpret_cast<const float4*>(&k1[c0 + tc]);
  float4 K2 = *reinterpret_cast<const float4*>(&k2[c0 + tc]);
  float4 CC = *reinterpret_cast<const float4*>(&cc[c0 + tc]);
#pragma unroll
  for (int p = 0; p < 4; ++p) {
    int d = d0 + tr + p * 16;
    uint2 a1 = *reinterpret_cast<const uint2*>(&A1[((size_t)g * LNODES + d) * NCOUT + c0 + tc]);
    uint2 a2 = *reinterpret_cast<const uint2*>(&A2[((size_t)b * LNODES + d) * NCOUT + c0 + tc]);
    T[tr + p * 16][tc + 0] = fmaxf(K1.x * blo(a1.x) + K2.x * blo(a2.x) + CC.x, 0.f);
    T[tr + p * 16][tc + 1] = fmaxf(K1.y * bhi(a1.x) + K2.y * bhi(a2.x) + CC.y, 0.f);
    T[tr + p * 16][tc + 2] = fmaxf(K1.z * blo(a1.y) + K2.z * blo(a2.y) + CC.z, 0.f);
    T[tr + p * 16][tc + 3] = fmaxf(K1.w * bhi(a1.y) + K2.w * bhi(a2.y) + CC.w, 0.f);
  }
  __syncthreads();
#pragma unroll
  for (int p = 0; p < 4; ++p) {
    int c = tr + p * 16;
    float4 o = {T[tc + 0][c], T[tc + 1][c], T[tc + 2][c], T[tc + 3][c]};
    *reinterpret_cast<float4*>(&O[((size_t)g * NCOUT + c0 + c) * LNODES + d0 + tc]) = o;
  }
}

// ---------------- launch ----------------

extern "C" void kernel_launch(void* const* d_in, const int* in_sizes, int n_in,
                              void* d_out, int out_size, void* d_ws, size_t ws_size,
                              hipStream_t stream) {
  const float* x_in = (const float*)d_in[0];
  const int* ei = (const int*)d_in[1];
  const float* W[3]   = {(const float*)d_in[2],  (const float*)d_in[4],  (const float*)d_in[6]};
  const float* Wsym[3]= {(const float*)d_in[8],  (const float*)d_in[10], (const float*)d_in[12]};
  const float* ga[3]  = {(const float*)d_in[14], (const float*)d_in[16], (const float*)d_in[18]};
  const float* be[3]  = {(const float*)d_in[15], (const float*)d_in[17], (const float*)d_in[19]};
  const float* gs[3]  = {(const float*)d_in[20], (const float*)d_in[22], (const float*)d_in[24]};
  const float* bes[3] = {(const float*)d_in[21], (const float*)d_in[23], (const float*)d_in[25]};

  const size_t EBIG = (size_t)GBIG * LNODES * NCOUT;  // 16.7M elems
  const size_t ESM = (size_t)GSM * LNODES * NCOUT;
  char* p = (char*)d_ws;
  u16* Xact = (u16*)p; p += EBIG * 2;   // 32 MiB: inter-layer activations (bf16)
  u16* AGG1 = (u16*)p; p += EBIG * 2;   // 32 MiB
  u16* agg2 = (u16*)p; p += ESM * 2;    // 4 MiB
  u16* WbT[3], *WsT[3];
  for (int i = 0; i < 3; ++i) { WbT[i] = (u16*)p; p += NCOUT * NCOUT * 2; }
  for (int i = 0; i < 3; ++i) { WsT[i] = (u16*)p; p += NCOUT * NCOUT * 2; }
  int*   col  = (int*)p;   p += NEDGE * 4;
  float* wn   = (float*)p; p += NEDGE * 4;
  int*   rp   = (int*)p;   p += 2064 * 4;
  float* dis  = (float*)p; p += LNODES * 4;
  float* selfn= (float*)p; p += LNODES * 4;
  char* zbase = p;
  float* deg  = (float*)p; p += LNODES * 4;
  int*   cnt  = (int*)p;   p += LNODES * 4;
  int*   fillc= (int*)p;   p += LNODES * 4;
  size_t zsize = (size_t)(p - zbase);
  char* statbase = p;                    // 8-way sharded stats: [8][256] each
  float* sum1 = (float*)p; p += 8 * 1024;
  float* sq1  = (float*)p; p += 8 * 1024;
  float* sum2 = (float*)p; p += 8 * 1024;
  float* sq2  = (float*)p; p += 8 * 1024;
  size_t statsize = (size_t)(p - statbase);  // 32 KiB
  float* k1 = (float*)p; p += 1024;
  float* k2 = (float*)p; p += 1024;
  float* cc = (float*)p; p += 1024;
  // aliases (lifetime-disjoint):
  u16* XT0 = Xact;                         // layer-0 node-major input (16 MiB)
  u16* xp  = AGG1;                         // pooled input (dead before agg_big writes)
  u16* hw2 = AGG1 + 2 * 1024 * 1024;       // sym GEMM out (read by agg_sm before agg_big)
  u16* HW1 = (u16*)d_out;                  // big GEMM out lives in d_out (dead by fuse time)

  // ---- CSR + weight conversion + input transpose ----
  hipMemsetAsync(zbase, 0, zsize, stream);
  count_deg_k<<<NEDGE / 256, 256, 0, stream>>>(ei, deg, cnt);
  dis_k<<<LNODES / 256, 256, 0, stream>>>(deg, dis, selfn);
  scan_k<<<1, 256, 0, stream>>>(cnt, rp);
  fill_k<<<NEDGE / 256, 256, 0, stream>>>(ei, rp, fillc, dis, col, wn);
  for (int i = 0; i < 3; ++i) {
    int Ci = (i == 0) ? 128 : 256;
    cvtw_k<<<dim3(NCOUT / 64, Ci / 64), 256, 0, stream>>>(W[i], WbT[i], Ci);
    cvtw_k<<<dim3(NCOUT / 64, Ci / 64), 256, 0, stream>>>(Wsym[i], WsT[i], Ci);
  }
  trans_k<<<dim3(LNODES / 64, 128 / 64, GBIG), 256, 0, stream>>>(x_in, XT0, 128);

  for (int l = 0; l < 3; ++l) {
    const int Cin = (l == 0) ? 128 : 256;
    const u16* Xin = (l == 0) ? XT0 : Xact;
    const int per = Cin * LNODES;
    pool_bf_k<<<GSM * per / 8 / 256, 256, 0, stream>>>(Xin, xp, per);
    gemm_bf_k<<<dim3(LNODES / 128, NCOUT / 128, GSM), 256, 0, stream>>>(xp, WsT[l], hw2, Cin);
    gemm_bf_k<<<dim3(LNODES / 128, NCOUT / 128, GBIG), 256, 0, stream>>>(Xin, WbT[l], HW1, Cin);
    hipMemsetAsync(statbase, 0, statsize, stream);
    // agg_sm first: it reads hw2 which aliases AGG1 (clobbered by agg_big)
    agg_bf_k<GSM><<<(LNODES / ND) * GSM, 256, 0, stream>>>(hw2, col, wn, rp, selfn,
                                                           agg2, sum2, sq2);
    agg_bf_k<GBIG><<<(LNODES / ND) * GBIG, 256, 0, stream>>>(HW1, col, wn, rp, selfn,
                                                             AGG1, sum1, sq1);
    bnfinal_k<<<1, 256, 0, stream>>>(sum1, sq1, sum2, sq2,
                                     ga[l], be[l], gs[l], bes[l], k1, k2, cc);
    if (l < 2) {
      fuse_bf_k<<<(int)(EBIG / 8 / 256), 256, 0, stream>>>(AGG1, agg2, k1, k2, cc, Xact);
    } else {
      fuse_tr_bf_k<<<dim3(LNODES / 64, NCOUT / 64, GBIG), 256, 0, stream>>>(
          AGG1, agg2, k1, k2, cc, (float*)d_out);
    }
  }
}

// Round 8
// 443.613 us; speedup vs baseline: 4.9966x; 1.0525x over previous
//
#include <hip/hip_runtime.h>
#include <math.h>

#define LNODES 2048
#define NEDGE 16384
#define GBIG 32
#define GSM 4
#define NCOUT 256
#define BN_EPS 1e-5f
#define ND 32  // dst nodes per agg block

typedef unsigned short u16;
typedef __attribute__((ext_vector_type(8))) short bf16x8;
typedef __attribute__((ext_vector_type(4))) float f32x4;

__device__ __forceinline__ unsigned pk2(float a, float b) {  // a->lo, b->hi
  unsigned ua = __float_as_uint(a); ua += 0x7fffu + ((ua >> 16) & 1u);
  unsigned ub = __float_as_uint(b); ub += 0x7fffu + ((ub >> 16) & 1u);
  return (ua >> 16) | (ub & 0xffff0000u);
}
__device__ __forceinline__ float blo(unsigned u) { return __uint_as_float(u << 16); }
__device__ __forceinline__ float bhi(unsigned u) { return __uint_as_float(u & 0xffff0000u); }

// ---------------- setup: degree, dis, CSR ----------------

__global__ __launch_bounds__(256) void count_deg_k(const int* __restrict__ ei,
                                                   float* __restrict__ deg,
                                                   int* __restrict__ cnt) {
  int e = blockIdx.x * 256 + threadIdx.x;
  if (e < NEDGE) {
    int d = ei[NEDGE + e];
    atomicAdd(&deg[d], 1.0f);
    atomicAdd(&cnt[d], 1);
  }
}

__global__ __launch_bounds__(256) void dis_k(const float* __restrict__ deg,
                                             float* __restrict__ dis,
                                             float* __restrict__ selfn) {
  int i = blockIdx.x * 256 + threadIdx.x;
  if (i < LNODES) {
    float di = rsqrtf(deg[i] + 2.0f);  // improved=True self loop weight 2
    dis[i] = di;
    selfn[i] = 2.0f * di * di;
  }
}

__global__ __launch_bounds__(256) void scan_k(const int* __restrict__ cnt,
                                              int* __restrict__ rp) {
  __shared__ int part[256];
  int t = threadIdx.x;
  int base = t * 8;
  int loc[8];
  int s = 0;
#pragma unroll
  for (int j = 0; j < 8; ++j) { loc[j] = s; s += cnt[base + j]; }
  part[t] = s;
  __syncthreads();
  for (int off = 1; off < 256; off <<= 1) {
    int v = (t >= off) ? part[t - off] : 0;
    __syncthreads();
    part[t] += v;
    __syncthreads();
  }
  int excl = (t == 0) ? 0 : part[t - 1];
#pragma unroll
  for (int j = 0; j < 8; ++j) rp[base + j] = excl + loc[j];
  if (t == 255) rp[LNODES] = part[255];
}

__global__ __launch_bounds__(256) void fill_k(const int* __restrict__ ei,
                                              const int* __restrict__ rp,
                                              int* __restrict__ fillc,
                                              const float* __restrict__ dis,
                                              int* __restrict__ col,
                                              float* __restrict__ wn) {
  int e = blockIdx.x * 256 + threadIdx.x;
  if (e < NEDGE) {
    int s = ei[e], d = ei[NEDGE + e];
    int pos = rp[d] + atomicAdd(&fillc[d], 1);
    col[pos] = s;
    wn[pos] = dis[s] * dis[d];
  }
}

// ---------------- x [G][Cin][L] f32 -> XT [G][L][Cin] bf16 ----------------
__global__ __launch_bounds__(256) void trans_k(const float* __restrict__ X,
                                               u16* __restrict__ XT, int Cin) {
  __shared__ float T[64][65];  // [ci_local][node_local]
  const int g = blockIdx.z;
  const int n0 = blockIdx.x * 64;
  const int c0 = blockIdx.y * 64;
  const int tr = threadIdx.x >> 4;
  const int tc = (threadIdx.x & 15) * 4;
#pragma unroll
  for (int p = 0; p < 4; ++p) {
    int ci = c0 + tr + p * 16;
    float4 v = *reinterpret_cast<const float4*>(&X[((size_t)g * Cin + ci) * LNODES + n0 + tc]);
    T[tr + p * 16][tc + 0] = v.x; T[tr + p * 16][tc + 1] = v.y;
    T[tr + p * 16][tc + 2] = v.z; T[tr + p * 16][tc + 3] = v.w;
  }
  __syncthreads();
#pragma unroll
  for (int p = 0; p < 4; ++p) {
    int nd = tr + p * 16;
    uint2 o = {pk2(T[tc + 0][nd], T[tc + 1][nd]), pk2(T[tc + 2][nd], T[tc + 3][nd])};
    *reinterpret_cast<uint2*>(&XT[((size_t)g * LNODES + n0 + nd) * Cin + c0 + tc]) = o;
  }
}

// ---------------- W [Ci][256] f32 -> WbT [256][Ci] bf16 ----------------
__global__ __launch_bounds__(256) void cvtw_k(const float* __restrict__ W,
                                              u16* __restrict__ WbT, int Ci) {
  __shared__ float T[64][65];  // [ci_local][co_local]
  const int co0 = blockIdx.x * 64;
  const int ci0 = blockIdx.y * 64;
  const int tr = threadIdx.x >> 4;
  const int tc = (threadIdx.x & 15) * 4;
#pragma unroll
  for (int p = 0; p < 4; ++p) {
    int ci = ci0 + tr + p * 16;
    float4 v = *reinterpret_cast<const float4*>(&W[(size_t)ci * NCOUT + co0 + tc]);
    T[tr + p * 16][tc + 0] = v.x; T[tr + p * 16][tc + 1] = v.y;
    T[tr + p * 16][tc + 2] = v.z; T[tr + p * 16][tc + 3] = v.w;
  }
  __syncthreads();
#pragma unroll
  for (int p = 0; p < 4; ++p) {
    int co = tr + p * 16;
    uint2 o = {pk2(T[tc + 0][co], T[tc + 1][co]), pk2(T[tc + 2][co], T[tc + 3][co])};
    *reinterpret_cast<uint2*>(&WbT[(size_t)(co0 + co) * Ci + ci0 + tc]) = o;
  }
}

// ---------------- max-pool over N=8, bf16 (layer 0 only) ----------------
__global__ __launch_bounds__(256) void pool_bf_k(const u16* __restrict__ X,
                                                 u16* __restrict__ XP, int per) {
  int i = blockIdx.x * 256 + threadIdx.x;
  size_t f = (size_t)i * 8;
  int b = (int)(f / per);
  size_t rem = f - (size_t)b * per;
  const u16* base = X + (size_t)b * 8 * per + rem;
  uint4 u = *reinterpret_cast<const uint4*>(base);
  float m0 = blo(u.x), m1 = bhi(u.x), m2 = blo(u.y), m3 = bhi(u.y);
  float m4 = blo(u.z), m5 = bhi(u.z), m6 = blo(u.w), m7 = bhi(u.w);
#pragma unroll
  for (int j = 1; j < 8; ++j) {
    uint4 v = *reinterpret_cast<const uint4*>(base + (size_t)j * per);
    m0 = fmaxf(m0, blo(v.x)); m1 = fmaxf(m1, bhi(v.x));
    m2 = fmaxf(m2, blo(v.y)); m3 = fmaxf(m3, bhi(v.y));
    m4 = fmaxf(m4, blo(v.z)); m5 = fmaxf(m5, bhi(v.z));
    m6 = fmaxf(m6, blo(v.w)); m7 = fmaxf(m7, bhi(v.w));
  }
  uint4 o = {pk2(m0, m1), pk2(m2, m3), pk2(m4, m5), pk2(m6, m7)};
  *reinterpret_cast<uint4*>(XP + (size_t)b * per + rem) = o;
}

// ---------------- bf16 MFMA GEMM ----------------
__global__ __launch_bounds__(256) void gemm_bf_k(const u16* __restrict__ X,
                                                 const u16* __restrict__ WbT,
                                                 u16* __restrict__ HW, int Cin) {
  __shared__ u16 smem[17408];      // K-loop: 2x[128][40]; epilogue [128][136]
  u16* Wsh = smem;
  u16* Xsh = smem + 128 * 40;
  const int g = blockIdx.z;
  const int n0 = blockIdx.x * 128;
  const int c0 = blockIdx.y * 128;
  const int t = threadIdx.x;
  const int wv = t >> 6;
  const int lane = t & 63;
  const int q = lane >> 4, l = lane & 15;
  const int wm = wv >> 1, wn = wv & 1;
  f32x4 zero = {0.f, 0.f, 0.f, 0.f};
  f32x4 acc[4][4];
#pragma unroll
  for (int i = 0; i < 4; ++i)
#pragma unroll
    for (int j = 0; j < 4; ++j) acc[i][j] = zero;
  const int r0 = t >> 2;
  const int seg = (t & 3) * 8;
  const u16* Wg = WbT + (size_t)(c0 + r0) * Cin + seg;
  const u16* Xg = X + ((size_t)g * LNODES + n0 + r0) * Cin + seg;
  for (int k0 = 0; k0 < Cin; k0 += 32) {
    uint4 w0 = *reinterpret_cast<const uint4*>(Wg + k0);
    uint4 w1 = *reinterpret_cast<const uint4*>(Wg + (size_t)64 * Cin + k0);
    uint4 x0 = *reinterpret_cast<const uint4*>(Xg + k0);
    uint4 x1 = *reinterpret_cast<const uint4*>(Xg + (size_t)64 * Cin + k0);
    __syncthreads();
    *reinterpret_cast<uint4*>(&Wsh[r0 * 40 + seg]) = w0;
    *reinterpret_cast<uint4*>(&Wsh[(r0 + 64) * 40 + seg]) = w1;
    *reinterpret_cast<uint4*>(&Xsh[r0 * 40 + seg]) = x0;
    *reinterpret_cast<uint4*>(&Xsh[(r0 + 64) * 40 + seg]) = x1;
    __syncthreads();
    bf16x8 af[4], bx[4];
#pragma unroll
    for (int fi = 0; fi < 4; ++fi)
      af[fi] = *reinterpret_cast<const bf16x8*>(&Wsh[(wm * 64 + fi * 16 + l) * 40 + q * 8]);
#pragma unroll
    for (int fj = 0; fj < 4; ++fj)
      bx[fj] = *reinterpret_cast<const bf16x8*>(&Xsh[(wn * 64 + fj * 16 + l) * 40 + q * 8]);
#pragma unroll
    for (int fi = 0; fi < 4; ++fi)
#pragma unroll
      for (int fj = 0; fj < 4; ++fj)
        acc[fi][fj] = __builtin_amdgcn_mfma_f32_16x16x32_bf16(af[fi], bx[fj], acc[fi][fj], 0, 0, 0);
  }
  __syncthreads();
  u16* Csh = smem;  // [128][136]
#pragma unroll
  for (int fi = 0; fi < 4; ++fi) {
#pragma unroll
    for (int fj = 0; fj < 4; ++fj) {
      int co_l = wm * 64 + fi * 16 + q * 4;
      int nd_l = wn * 64 + fj * 16 + l;
      uint2 pkd = {pk2(acc[fi][fj][0], acc[fi][fj][1]),
                   pk2(acc[fi][fj][2], acc[fi][fj][3])};
      *reinterpret_cast<uint2*>(&Csh[nd_l * 136 + co_l]) = pkd;
    }
  }
  __syncthreads();
#pragma unroll
  for (int p = 0; p < 8; ++p) {
    int idx = p * 256 + t;
    int nd = idx >> 4;
    int c8 = (idx & 15) * 8;
    uint4 v = *reinterpret_cast<const uint4*>(&Csh[nd * 136 + c8]);
    *reinterpret_cast<uint4*>(&HW[((size_t)g * LNODES + n0 + nd) * NCOUT + c0 + c8]) = v;
  }
}

// ---------------- GCN aggregation, bf16, g-paired (big), unroll x4 ----------------
// PAIR (NG==GBIG): block handles g0 and g1=g0+16 (same XCD under swizzle) —
// one col/wn load feeds 2 independent gathers; with x4 unroll -> 8 in flight.
// BN-stat atomics 8-way sharded by (bid&7).
template <int NG>
__global__ __launch_bounds__(256) void agg_bf_k(const u16* __restrict__ HW,
                                                const int* __restrict__ col,
                                                const float* __restrict__ wn,
                                                const int* __restrict__ rp,
                                                const float* __restrict__ selfn,
                                                u16* __restrict__ AGG,
                                                float* __restrict__ sum,
                                                float* __restrict__ sq) {
  constexpr bool PAIR = (NG == GBIG);
  int bid = blockIdx.x;
  int g0, chunk;
  if (PAIR) {
    int slot = bid >> 3;
    chunk = slot & 63;
    g0 = (bid & 7) + 8 * (slot >> 6);  // 0..15; g1 = g0+16 (same XCD)
  } else {
    g0 = bid & (NG - 1);
    chunk = bid >> 2;
  }
  const int d0 = chunk * ND;
  const int t = threadIdx.x;
  const int wv = t >> 6;
  const int lc = (t & 63) * 4;
  const u16* base0 = HW + (size_t)g0 * LNODES * NCOUT;
  const u16* base1 = base0 + (size_t)16 * LNODES * NCOUT;  // used only if PAIR
  float4 s = {0.f, 0.f, 0.f, 0.f}, qq = {0.f, 0.f, 0.f, 0.f};
  for (int i = wv; i < ND; i += 4) {
    int d = d0 + i;
    int e0 = rp[d], e1 = rp[d + 1];
    float sw = selfn[d];
    uint2 u0 = *reinterpret_cast<const uint2*>(&base0[(size_t)d * NCOUT + lc]);
    float4 a = {sw * blo(u0.x), sw * bhi(u0.x), sw * blo(u0.y), sw * bhi(u0.y)};
    float4 c = {0.f, 0.f, 0.f, 0.f};
    if (PAIR) {
      uint2 u1 = *reinterpret_cast<const uint2*>(&base1[(size_t)d * NCOUT + lc]);
      c = {sw * blo(u1.x), sw * bhi(u1.x), sw * blo(u1.y), sw * bhi(u1.y)};
    }
    int e = e0;
    const int e4 = e0 + ((e1 - e0) & ~3);
    for (; e < e4; e += 4) {
      int i0 = col[e + 0], i1 = col[e + 1], i2 = col[e + 2], i3 = col[e + 3];
      float w0 = wn[e + 0], w1 = wn[e + 1], w2 = wn[e + 2], w3 = wn[e + 3];
      uint2 v0 = *reinterpret_cast<const uint2*>(&base0[(size_t)i0 * NCOUT + lc]);
      uint2 v1 = *reinterpret_cast<const uint2*>(&base0[(size_t)i1 * NCOUT + lc]);
      uint2 v2 = *reinterpret_cast<const uint2*>(&base0[(size_t)i2 * NCOUT + lc]);
      uint2 v3 = *reinterpret_cast<const uint2*>(&base0[(size_t)i3 * NCOUT + lc]);
      uint2 p0, p1, p2, p3;
      if (PAIR) {
        p0 = *reinterpret_cast<const uint2*>(&base1[(size_t)i0 * NCOUT + lc]);
        p1 = *reinterpret_cast<const uint2*>(&base1[(size_t)i1 * NCOUT + lc]);
        p2 = *reinterpret_cast<const uint2*>(&base1[(size_t)i2 * NCOUT + lc]);
        p3 = *reinterpret_cast<const uint2*>(&base1[(size_t)i3 * NCOUT + lc]);
      }
      a.x += w0 * blo(v0.x); a.y += w0 * bhi(v0.x); a.z += w0 * blo(v0.y); a.w += w0 * bhi(v0.y);
      a.x += w1 * blo(v1.x); a.y += w1 * bhi(v1.x); a.z += w1 * blo(v1.y); a.w += w1 * bhi(v1.y);
      a.x += w2 * blo(v2.x); a.y += w2 * bhi(v2.x); a.z += w2 * blo(v2.y); a.w += w2 * bhi(v2.y);
      a.x += w3 * blo(v3.x); a.y += w3 * bhi(v3.x); a.z += w3 * blo(v3.y); a.w += w3 * bhi(v3.y);
      if (PAIR) {
        c.x += w0 * blo(p0.x); c.y += w0 * bhi(p0.x); c.z += w0 * blo(p0.y); c.w += w0 * bhi(p0.y);
        c.x += w1 * blo(p1.x); c.y += w1 * bhi(p1.x); c.z += w1 * blo(p1.y); c.w += w1 * bhi(p1.y);
        c.x += w2 * blo(p2.x); c.y += w2 * bhi(p2.x); c.z += w2 * blo(p2.y); c.w += w2 * bhi(p2.y);
        c.x += w3 * blo(p3.x); c.y += w3 * bhi(p3.x); c.z += w3 * blo(p3.y); c.w += w3 * bhi(p3.y);
      }
    }
    for (; e < e1; ++e) {
      int ci = col[e];
      float w = wn[e];
      uint2 v = *reinterpret_cast<const uint2*>(&base0[(size_t)ci * NCOUT + lc]);
      a.x += w * blo(v.x); a.y += w * bhi(v.x); a.z += w * blo(v.y); a.w += w * bhi(v.y);
      if (PAIR) {
        uint2 pv = *reinterpret_cast<const uint2*>(&base1[(size_t)ci * NCOUT + lc]);
        c.x += w * blo(pv.x); c.y += w * bhi(pv.x); c.z += w * blo(pv.y); c.w += w * bhi(pv.y);
      }
    }
    uint2 o0 = {pk2(a.x, a.y), pk2(a.z, a.w)};
    *reinterpret_cast<uint2*>(&AGG[((size_t)g0 * LNODES + d) * NCOUT + lc]) = o0;
    s.x += a.x; s.y += a.y; s.z += a.z; s.w += a.w;
    qq.x += a.x * a.x; qq.y += a.y * a.y; qq.z += a.z * a.z; qq.w += a.w * a.w;
    if (PAIR) {
      uint2 o1 = {pk2(c.x, c.y), pk2(c.z, c.w)};
      *reinterpret_cast<uint2*>(&AGG[((size_t)(g0 + 16) * LNODES + d) * NCOUT + lc]) = o1;
      s.x += c.x; s.y += c.y; s.z += c.z; s.w += c.w;
      qq.x += c.x * c.x; qq.y += c.y * c.y; qq.z += c.z * c.z; qq.w += c.w * c.w;
    }
  }
  __shared__ float lsum[4][NCOUT], lsq[4][NCOUT];
  *reinterpret_cast<float4*>(&lsum[wv][lc]) = s;
  *reinterpret_cast<float4*>(&lsq[wv][lc]) = qq;
  __syncthreads();
  float ts = lsum[0][t] + lsum[1][t] + lsum[2][t] + lsum[3][t];
  float tq = lsq[0][t] + lsq[1][t] + lsq[2][t] + lsq[3][t];
  const int shard = (bid & 7) * NCOUT;
  atomicAdd(&sum[shard + t], ts);
  atomicAdd(&sq[shard + t], tq);
}

// ---------------- BN finalize (reads 8 shards per stat) ----------------
__global__ __launch_bounds__(256) void bnfinal_k(const float* __restrict__ sum1,
                                                 const float* __restrict__ sq1,
                                                 const float* __restrict__ sum2,
                                                 const float* __restrict__ sq2,
                                                 const float* __restrict__ ga,
                                                 const float* __restrict__ be,
                                                 const float* __restrict__ gs,
                                                 const float* __restrict__ bes,
                                                 float* __restrict__ k1,
                                                 float* __restrict__ k2,
                                                 float* __restrict__ cc) {
  int co = threadIdx.x;
  float sA = 0.f, qA = 0.f, sB = 0.f, qB = 0.f;
#pragma unroll
  for (int x = 0; x < 8; ++x) {
    sA += sum1[x * NCOUT + co];
    qA += sq1[x * NCOUT + co];
    sB += sum2[x * NCOUT + co];
    qB += sq2[x * NCOUT + co];
  }
  const float c1 = (float)(GBIG * LNODES), c2 = (float)(GSM * LNODES);
  float mA = sA / c1;
  float vA = qA / c1 - mA * mA;
  float kA = ga[co] * rsqrtf(vA + BN_EPS);
  float mB = sB / c2;
  float vB = qB / c2 - mB * mB;
  float kB = gs[co] * rsqrtf(vB + BN_EPS);
  k1[co] = kA;
  k2[co] = kB;
  cc[co] = be[co] - kA * mA + bes[co] - kB * mB;
}

// ---------------- fused BN+BN+add+ReLU + next-layer max-pool (layers 0,1) ----------------
// One thread owns 8 channels of one (b, d); loops the 8 n of b: reads A1[g],
// writes O[g], tracks running max, writes pooled XP[b]. A2 read ONCE.
// grid (256, GSM)
__global__ __launch_bounds__(256) void fuse_pool_bf_k(const u16* __restrict__ A1,
                                                      const u16* __restrict__ A2,
                                                      const float* __restrict__ k1,
                                                      const float* __restrict__ k2,
                                                      const float* __restrict__ cc,
                                                      u16* __restrict__ O,
                                                      u16* __restrict__ XP) {
  const int b = blockIdx.y;
  size_t f = ((size_t)blockIdx.x * 256 + threadIdx.x) * 8;  // within-b [d][co] flat
  int co = (int)(f & (NCOUT - 1));
  float4 K1a = *reinterpret_cast<const float4*>(&k1[co]);
  float4 K1b = *reinterpret_cast<const float4*>(&k1[co + 4]);
  float4 K2a = *reinterpret_cast<const float4*>(&k2[co]);
  float4 K2b = *reinterpret_cast<const float4*>(&k2[co + 4]);
  float4 Ca = *reinterpret_cast<const float4*>(&cc[co]);
  float4 Cb = *reinterpret_cast<const float4*>(&cc[co + 4]);
  uint4 a2 = *reinterpret_cast<const uint4*>(&A2[(size_t)b * LNODES * NCOUT + f]);
  float t0 = K2a.x * blo(a2.x) + Ca.x, t1 = K2a.y * bhi(a2.x) + Ca.y;
  float t2 = K2a.z * blo(a2.y) + Ca.z, t3 = K2a.w * bhi(a2.y) + Ca.w;
  float t4 = K2b.x * blo(a2.z) + Cb.x, t5 = K2b.y * bhi(a2.z) + Cb.y;
  float t6 = K2b.z * blo(a2.w) + Cb.z, t7 = K2b.w * bhi(a2.w) + Cb.w;
  float m0 = 0.f, m1 = 0.f, m2 = 0.f, m3 = 0.f, m4 = 0.f, m5 = 0.f, m6 = 0.f, m7 = 0.f;
#pragma unroll
  for (int n = 0; n < 8; ++n) {
    size_t gi = ((size_t)(b * 8 + n) * LNODES * NCOUT) + f;
    uint4 a1 = *reinterpret_cast<const uint4*>(&A1[gi]);
    float o0 = fmaxf(K1a.x * blo(a1.x) + t0, 0.f);
    float o1 = fmaxf(K1a.y * bhi(a1.x) + t1, 0.f);
    float o2 = fmaxf(K1a.z * blo(a1.y) + t2, 0.f);
    float o3 = fmaxf(K1a.w * bhi(a1.y) + t3, 0.f);
    float o4 = fmaxf(K1b.x * blo(a1.z) + t4, 0.f);
    float o5 = fmaxf(K1b.y * bhi(a1.z) + t5, 0.f);
    float o6 = fmaxf(K1b.z * blo(a1.w) + t6, 0.f);
    float o7 = fmaxf(K1b.w * bhi(a1.w) + t7, 0.f);
    uint4 ou = {pk2(o0, o1), pk2(o2, o3), pk2(o4, o5), pk2(o6, o7)};
    *reinterpret_cast<uint4*>(&O[gi]) = ou;
    m0 = fmaxf(m0, o0); m1 = fmaxf(m1, o1); m2 = fmaxf(m2, o2); m3 = fmaxf(m3, o3);
    m4 = fmaxf(m4, o4); m5 = fmaxf(m5, o5); m6 = fmaxf(m6, o6); m7 = fmaxf(m7, o7);
  }
  uint4 mu = {pk2(m0, m1), pk2(m2, m3), pk2(m4, m5), pk2(m6, m7)};
  *reinterpret_cast<uint4*>(&XP[(size_t)b * LNODES * NCOUT + f]) = mu;
}

// ---------------- layer 2: fuse + transpose to channel-major fp32 d_out ----------------
__global__ __launch_bounds__(256) void fuse_tr_bf_k(const u16* __restrict__ A1,
                                                    const u16* __restrict__ A2,
                                                    const float* __restrict__ k1,
                                                    const float* __restrict__ k2,
                                                    const float* __restrict__ cc,
                                                    float* __restrict__ O) {
  __shared__ float T[64][65];  // [node_local][co_local]
  const int g = blockIdx.z;
  const int d0 = blockIdx.x * 64;
  const int c0 = blockIdx.y * 64;
  const int b = g >> 3;
  const int tr = threadIdx.x >> 4;
  const int tc = (threadIdx.x & 15) * 4;
  float4 K1 = *reinterpret_cast<const float4*>(&k1[c0 + tc]);
  float4 K2 = *reinterpret_cast<const float4*>(&k2[c0 + tc]);
  float4 CC = *reinterpret_cast<const float4*>(&cc[c0 + tc]);
#pragma unroll
  for (int p = 0; p < 4; ++p) {
    int d = d0 + tr + p * 16;
    uint2 a1 = *reinterpret_cast<const uint2*>(&A1[((size_t)g * LNODES + d) * NCOUT + c0 + tc]);
    uint2 a2 = *reinterpret_cast<const uint2*>(&A2[((size_t)b * LNODES + d) * NCOUT + c0 + tc]);
    T[tr + p * 16][tc + 0] = fmaxf(K1.x * blo(a1.x) + K2.x * blo(a2.x) + CC.x, 0.f);
    T[tr + p * 16][tc + 1] = fmaxf(K1.y * bhi(a1.x) + K2.y * bhi(a2.x) + CC.y, 0.f);
    T[tr + p * 16][tc + 2] = fmaxf(K1.z * blo(a1.y) + K2.z * blo(a2.y) + CC.z, 0.f);
    T[tr + p * 16][tc + 3] = fmaxf(K1.w * bhi(a1.y) + K2.w * bhi(a2.y) + CC.w, 0.f);
  }
  __syncthreads();
#pragma unroll
  for (int p = 0; p < 4; ++p) {
    int c = tr + p * 16;
    float4 o = {T[tc + 0][c], T[tc + 1][c], T[tc + 2][c], T[tc + 3][c]};
    *reinterpret_cast<float4*>(&O[((size_t)g * NCOUT + c0 + c) * LNODES + d0 + tc]) = o;
  }
}

// ---------------- launch ----------------

extern "C" void kernel_launch(void* const* d_in, const int* in_sizes, int n_in,
                              void* d_out, int out_size, void* d_ws, size_t ws_size,
                              hipStream_t stream) {
  const float* x_in = (const float*)d_in[0];
  const int* ei = (const int*)d_in[1];
  const float* W[3]   = {(const float*)d_in[2],  (const float*)d_in[4],  (const float*)d_in[6]};
  const float* Wsym[3]= {(const float*)d_in[8],  (const float*)d_in[10], (const float*)d_in[12]};
  const float* ga[3]  = {(const float*)d_in[14], (const float*)d_in[16], (const float*)d_in[18]};
  const float* be[3]  = {(const float*)d_in[15], (const float*)d_in[17], (const float*)d_in[19]};
  const float* gs[3]  = {(const float*)d_in[20], (const float*)d_in[22], (const float*)d_in[24]};
  const float* bes[3] = {(const float*)d_in[21], (const float*)d_in[23], (const float*)d_in[25]};

  const size_t EBIG = (size_t)GBIG * LNODES * NCOUT;  // 16.7M elems
  const size_t ESM = (size_t)GSM * LNODES * NCOUT;
  char* p = (char*)d_ws;
  u16* Xact = (u16*)p; p += EBIG * 2;   // 32 MiB inter-layer activations
  u16* AGG1 = (u16*)p; p += EBIG * 2;   // 32 MiB
  u16* agg2 = (u16*)p; p += ESM * 2;    // 4 MiB
  u16* xp   = (u16*)p; p += ESM * 2;    // 4 MiB dedicated (written by fuse_pool)
  u16* hw2  = (u16*)p; p += ESM * 2;    // 4 MiB dedicated
  u16* WbT[3], *WsT[3];
  for (int i = 0; i < 3; ++i) { WbT[i] = (u16*)p; p += NCOUT * NCOUT * 2; }
  for (int i = 0; i < 3; ++i) { WsT[i] = (u16*)p; p += NCOUT * NCOUT * 2; }
  int*   col  = (int*)p;   p += NEDGE * 4;
  float* wn   = (float*)p; p += NEDGE * 4;
  int*   rp   = (int*)p;   p += 2064 * 4;
  float* dis  = (float*)p; p += LNODES * 4;
  float* selfn= (float*)p; p += LNODES * 4;
  char* zbase = p;
  float* deg  = (float*)p; p += LNODES * 4;
  int*   cnt  = (int*)p;   p += LNODES * 4;
  int*   fillc= (int*)p;   p += LNODES * 4;
  size_t zsize = (size_t)(p - zbase);
  char* statbase = p;                    // 8-way sharded stats: [8][256] each
  float* sum1 = (float*)p; p += 8 * 1024;
  float* sq1  = (float*)p; p += 8 * 1024;
  float* sum2 = (float*)p; p += 8 * 1024;
  float* sq2  = (float*)p; p += 8 * 1024;
  size_t statsize = (size_t)(p - statbase);  // 32 KiB
  float* k1 = (float*)p; p += 1024;
  float* k2 = (float*)p; p += 1024;
  float* cc = (float*)p; p += 1024;
  u16* XT0 = Xact;            // layer-0 node-major input (Xact dead until fuse l0)
  u16* HW1 = (u16*)d_out;     // big GEMM out lives in d_out (dead by fuse_tr time)

  // ---- CSR + weight conversion + input transpose ----
  hipMemsetAsync(zbase, 0, zsize, stream);
  count_deg_k<<<NEDGE / 256, 256, 0, stream>>>(ei, deg, cnt);
  dis_k<<<LNODES / 256, 256, 0, stream>>>(deg, dis, selfn);
  scan_k<<<1, 256, 0, stream>>>(cnt, rp);
  fill_k<<<NEDGE / 256, 256, 0, stream>>>(ei, rp, fillc, dis, col, wn);
  for (int i = 0; i < 3; ++i) {
    int Ci = (i == 0) ? 128 : 256;
    cvtw_k<<<dim3(NCOUT / 64, Ci / 64), 256, 0, stream>>>(W[i], WbT[i], Ci);
    cvtw_k<<<dim3(NCOUT / 64, Ci / 64), 256, 0, stream>>>(Wsym[i], WsT[i], Ci);
  }
  trans_k<<<dim3(LNODES / 64, 128 / 64, GBIG), 256, 0, stream>>>(x_in, XT0, 128);
  // layer-0 pooled input (layers 1,2 get xp from fuse_pool)
  pool_bf_k<<<GSM * 128 * LNODES / 8 / 256, 256, 0, stream>>>(XT0, xp, 128 * LNODES);

  for (int l = 0; l < 3; ++l) {
    const int Cin = (l == 0) ? 128 : 256;
    const u16* Xin = (l == 0) ? XT0 : Xact;
    gemm_bf_k<<<dim3(LNODES / 128, NCOUT / 128, GSM), 256, 0, stream>>>(xp, WsT[l], hw2, Cin);
    gemm_bf_k<<<dim3(LNODES / 128, NCOUT / 128, GBIG), 256, 0, stream>>>(Xin, WbT[l], HW1, Cin);
    hipMemsetAsync(statbase, 0, statsize, stream);
    agg_bf_k<GSM><<<(LNODES / ND) * GSM, 256, 0, stream>>>(hw2, col, wn, rp, selfn,
                                                           agg2, sum2, sq2);
    agg_bf_k<GBIG><<<(LNODES / ND) * GBIG / 2, 256, 0, stream>>>(HW1, col, wn, rp, selfn,
                                                                 AGG1, sum1, sq1);
    bnfinal_k<<<1, 256, 0, stream>>>(sum1, sq1, sum2, sq2,
                                     ga[l], be[l], gs[l], bes[l], k1, k2, cc);
    if (l < 2) {
      fuse_pool_bf_k<<<dim3(256, GSM), 256, 0, stream>>>(AGG1, agg2, k1, k2, cc, Xact, xp);
    } else {
      fuse_tr_bf_k<<<dim3(LNODES / 64, NCOUT / 64, GBIG), 256, 0, stream>>>(
          AGG1, agg2, k1, k2, cc, (float*)d_out);
    }
  }
}

// Round 9
// 376.289 us; speedup vs baseline: 5.8906x; 1.1789x over previous
//
#include <hip/hip_runtime.h>
#include <math.h>

#define LNODES 2048
#define NEDGE 16384
#define GBIG 32
#define GSM 4
#define NCOUT 256
#define BN_EPS 1e-5f
#define ND 32  // dst nodes per agg block

typedef unsigned short u16;
typedef __attribute__((ext_vector_type(8))) short bf16x8;
typedef __attribute__((ext_vector_type(4))) float f32x4;

__device__ __forceinline__ unsigned pk2(float a, float b) {  // a->lo, b->hi
  unsigned ua = __float_as_uint(a); ua += 0x7fffu + ((ua >> 16) & 1u);
  unsigned ub = __float_as_uint(b); ub += 0x7fffu + ((ub >> 16) & 1u);
  return (ua >> 16) | (ub & 0xffff0000u);
}
__device__ __forceinline__ float blo(unsigned u) { return __uint_as_float(u << 16); }
__device__ __forceinline__ float bhi(unsigned u) { return __uint_as_float(u & 0xffff0000u); }

// ---------------- setup: degree, dis, CSR ----------------

__global__ __launch_bounds__(256) void count_deg_k(const int* __restrict__ ei,
                                                   float* __restrict__ deg,
                                                   int* __restrict__ cnt) {
  int e = blockIdx.x * 256 + threadIdx.x;
  if (e < NEDGE) {
    int d = ei[NEDGE + e];
    atomicAdd(&deg[d], 1.0f);
    atomicAdd(&cnt[d], 1);
  }
}

__global__ __launch_bounds__(256) void dis_k(const float* __restrict__ deg,
                                             float* __restrict__ dis,
                                             float* __restrict__ selfn) {
  int i = blockIdx.x * 256 + threadIdx.x;
  if (i < LNODES) {
    float di = rsqrtf(deg[i] + 2.0f);  // improved=True self loop weight 2
    dis[i] = di;
    selfn[i] = 2.0f * di * di;
  }
}

__global__ __launch_bounds__(256) void scan_k(const int* __restrict__ cnt,
                                              int* __restrict__ rp) {
  __shared__ int part[256];
  int t = threadIdx.x;
  int base = t * 8;
  int loc[8];
  int s = 0;
#pragma unroll
  for (int j = 0; j < 8; ++j) { loc[j] = s; s += cnt[base + j]; }
  part[t] = s;
  __syncthreads();
  for (int off = 1; off < 256; off <<= 1) {
    int v = (t >= off) ? part[t - off] : 0;
    __syncthreads();
    part[t] += v;
    __syncthreads();
  }
  int excl = (t == 0) ? 0 : part[t - 1];
#pragma unroll
  for (int j = 0; j < 8; ++j) rp[base + j] = excl + loc[j];
  if (t == 255) rp[LNODES] = part[255];
}

__global__ __launch_bounds__(256) void fill_k(const int* __restrict__ ei,
                                              const int* __restrict__ rp,
                                              int* __restrict__ fillc,
                                              const float* __restrict__ dis,
                                              int* __restrict__ col,
                                              float* __restrict__ wn) {
  int e = blockIdx.x * 256 + threadIdx.x;
  if (e < NEDGE) {
    int s = ei[e], d = ei[NEDGE + e];
    int pos = rp[d] + atomicAdd(&fillc[d], 1);
    col[pos] = s;
    wn[pos] = dis[s] * dis[d];
  }
}

// ---------------- x [G][Cin][L] f32 -> XT [G][L][Cin] bf16 ----------------
__global__ __launch_bounds__(256) void trans_k(const float* __restrict__ X,
                                               u16* __restrict__ XT, int Cin) {
  __shared__ float T[64][65];  // [ci_local][node_local]
  const int g = blockIdx.z;
  const int n0 = blockIdx.x * 64;
  const int c0 = blockIdx.y * 64;
  const int tr = threadIdx.x >> 4;
  const int tc = (threadIdx.x & 15) * 4;
#pragma unroll
  for (int p = 0; p < 4; ++p) {
    int ci = c0 + tr + p * 16;
    float4 v = *reinterpret_cast<const float4*>(&X[((size_t)g * Cin + ci) * LNODES + n0 + tc]);
    T[tr + p * 16][tc + 0] = v.x; T[tr + p * 16][tc + 1] = v.y;
    T[tr + p * 16][tc + 2] = v.z; T[tr + p * 16][tc + 3] = v.w;
  }
  __syncthreads();
#pragma unroll
  for (int p = 0; p < 4; ++p) {
    int nd = tr + p * 16;
    uint2 o = {pk2(T[tc + 0][nd], T[tc + 1][nd]), pk2(T[tc + 2][nd], T[tc + 3][nd])};
    *reinterpret_cast<uint2*>(&XT[((size_t)g * LNODES + n0 + nd) * Cin + c0 + tc]) = o;
  }
}

// ---------------- all 6 weights: W [Ci][256] f32 -> WT [256][Ci] bf16, one launch ----------------
struct WCvt {
  const float* src[6];
  u16* dst[6];
  int ci[6];
};
__global__ __launch_bounds__(256) void cvtw_all_k(WCvt wp) {
  __shared__ float T[64][65];
  const int w = blockIdx.z;
  const int Ci = wp.ci[w];
  const int ci0 = blockIdx.y * 64;
  if (ci0 >= Ci) return;
  const float* W = wp.src[w];
  u16* WT = wp.dst[w];
  const int co0 = blockIdx.x * 64;
  const int tr = threadIdx.x >> 4;
  const int tc = (threadIdx.x & 15) * 4;
#pragma unroll
  for (int p = 0; p < 4; ++p) {
    int ci = ci0 + tr + p * 16;
    float4 v = *reinterpret_cast<const float4*>(&W[(size_t)ci * NCOUT + co0 + tc]);
    T[tr + p * 16][tc + 0] = v.x; T[tr + p * 16][tc + 1] = v.y;
    T[tr + p * 16][tc + 2] = v.z; T[tr + p * 16][tc + 3] = v.w;
  }
  __syncthreads();
#pragma unroll
  for (int p = 0; p < 4; ++p) {
    int co = tr + p * 16;
    uint2 o = {pk2(T[tc + 0][co], T[tc + 1][co]), pk2(T[tc + 2][co], T[tc + 3][co])};
    *reinterpret_cast<uint2*>(&WT[(size_t)(co0 + co) * Ci + ci0 + tc]) = o;
  }
}

// ---------------- layer-0 max-pool over N=8 (raw bf16 input) ----------------
__global__ __launch_bounds__(256) void pool_bf_k(const u16* __restrict__ X,
                                                 u16* __restrict__ XP, int per) {
  int i = blockIdx.x * 256 + threadIdx.x;
  size_t f = (size_t)i * 8;
  int b = (int)(f / per);
  size_t rem = f - (size_t)b * per;
  const u16* base = X + (size_t)b * 8 * per + rem;
  uint4 u = *reinterpret_cast<const uint4*>(base);
  float m0 = blo(u.x), m1 = bhi(u.x), m2 = blo(u.y), m3 = bhi(u.y);
  float m4 = blo(u.z), m5 = bhi(u.z), m6 = blo(u.w), m7 = bhi(u.w);
#pragma unroll
  for (int j = 1; j < 8; ++j) {
    uint4 v = *reinterpret_cast<const uint4*>(base + (size_t)j * per);
    m0 = fmaxf(m0, blo(v.x)); m1 = fmaxf(m1, bhi(v.x));
    m2 = fmaxf(m2, blo(v.y)); m3 = fmaxf(m3, bhi(v.y));
    m4 = fmaxf(m4, blo(v.z)); m5 = fmaxf(m5, bhi(v.z));
    m6 = fmaxf(m6, blo(v.w)); m7 = fmaxf(m7, bhi(v.w));
  }
  uint4 o = {pk2(m0, m1), pk2(m2, m3), pk2(m4, m5), pk2(m6, m7)};
  *reinterpret_cast<uint4*>(XP + (size_t)b * per + rem) = o;
}

// ---------------- layers 1,2: BN+BN+add+ReLU -> pooled xp only ----------------
// grid (256, GSM); thread = 8 channels of one (b, d).
__global__ __launch_bounds__(256) void poolonly_k(const u16* __restrict__ A1,
                                                  const u16* __restrict__ A2,
                                                  const float* __restrict__ k1,
                                                  const float* __restrict__ k2,
                                                  const float* __restrict__ cc,
                                                  u16* __restrict__ XP) {
  const int b = blockIdx.y;
  size_t f = ((size_t)blockIdx.x * 256 + threadIdx.x) * 8;
  int co = (int)(f & (NCOUT - 1));
  float4 K1a = *reinterpret_cast<const float4*>(&k1[co]);
  float4 K1b = *reinterpret_cast<const float4*>(&k1[co + 4]);
  float4 K2a = *reinterpret_cast<const float4*>(&k2[co]);
  float4 K2b = *reinterpret_cast<const float4*>(&k2[co + 4]);
  float4 Ca = *reinterpret_cast<const float4*>(&cc[co]);
  float4 Cb = *reinterpret_cast<const float4*>(&cc[co + 4]);
  uint4 a2 = *reinterpret_cast<const uint4*>(&A2[(size_t)b * LNODES * NCOUT + f]);
  float t0 = K2a.x * blo(a2.x) + Ca.x, t1 = K2a.y * bhi(a2.x) + Ca.y;
  float t2 = K2a.z * blo(a2.y) + Ca.z, t3 = K2a.w * bhi(a2.y) + Ca.w;
  float t4 = K2b.x * blo(a2.z) + Cb.x, t5 = K2b.y * bhi(a2.z) + Cb.y;
  float t6 = K2b.z * blo(a2.w) + Cb.z, t7 = K2b.w * bhi(a2.w) + Cb.w;
  float m0 = 0.f, m1 = 0.f, m2 = 0.f, m3 = 0.f, m4 = 0.f, m5 = 0.f, m6 = 0.f, m7 = 0.f;
#pragma unroll
  for (int n = 0; n < 8; ++n) {
    size_t gi = ((size_t)(b * 8 + n) * LNODES * NCOUT) + f;
    uint4 a1 = *reinterpret_cast<const uint4*>(&A1[gi]);
    m0 = fmaxf(m0, K1a.x * blo(a1.x) + t0);
    m1 = fmaxf(m1, K1a.y * bhi(a1.x) + t1);
    m2 = fmaxf(m2, K1a.z * blo(a1.y) + t2);
    m3 = fmaxf(m3, K1a.w * bhi(a1.y) + t3);
    m4 = fmaxf(m4, K1b.x * blo(a1.z) + t4);
    m5 = fmaxf(m5, K1b.y * bhi(a1.z) + t5);
    m6 = fmaxf(m6, K1b.z * blo(a1.w) + t6);
    m7 = fmaxf(m7, K1b.w * bhi(a1.w) + t7);
  }
  // relu == clamp at 0 (max over n then 0)
  m0 = fmaxf(m0, 0.f); m1 = fmaxf(m1, 0.f); m2 = fmaxf(m2, 0.f); m3 = fmaxf(m3, 0.f);
  m4 = fmaxf(m4, 0.f); m5 = fmaxf(m5, 0.f); m6 = fmaxf(m6, 0.f); m7 = fmaxf(m7, 0.f);
  uint4 mu = {pk2(m0, m1), pk2(m2, m3), pk2(m4, m5), pk2(m6, m7)};
  *reinterpret_cast<uint4*>(&XP[(size_t)b * LNODES * NCOUT + f]) = mu;
}

// ---------------- bf16 MFMA GEMM, combined big+sym, optional fused BN-load ----------------
// z<32: big path, g=z. MODE 0: A from Xbig[g][node][ci]. MODE 1: A computed
//   on the fly = relu(k1*AGG1[g] + k2*agg2[g/8] + cc) — identical bf16 rounding
//   to the old materialized Xact (pk2 RNE both places).
// z>=32: sym path, g=z-32, A from xp (plain), W=WsT, out=hw2.
template <int MODE>
__global__ __launch_bounds__(256) void gemm_all_k(const u16* __restrict__ Xbig,
                                                  const u16* __restrict__ AGG1,
                                                  const u16* __restrict__ agg2,
                                                  const float* __restrict__ k1,
                                                  const float* __restrict__ k2,
                                                  const float* __restrict__ cc,
                                                  const u16* __restrict__ xp,
                                                  const u16* __restrict__ WbT,
                                                  const u16* __restrict__ WsT,
                                                  u16* __restrict__ HW1,
                                                  u16* __restrict__ hw2,
                                                  int CinBig) {
  __shared__ u16 smem[17408];      // K-loop: 2x[128][40]; epilogue [128][136]
  __shared__ float lk1[NCOUT], lk2[NCOUT], lcc[NCOUT];
  u16* Wsh = smem;
  u16* Xsh = smem + 128 * 40;
  const int z = blockIdx.z;
  const bool big = z < GBIG;
  const int g = big ? z : z - GBIG;
  const int Cin = big ? CinBig : ((MODE == 0) ? CinBig : NCOUT);
  const u16* Wmat = big ? WbT : WsT;
  u16* out = big ? HW1 : hw2;
  const int n0 = blockIdx.x * 128;
  const int c0 = blockIdx.y * 128;
  const int t = threadIdx.x;
  // coef preload (used only by fused big path; harmless otherwise)
  lk1[t] = k1[t]; lk2[t] = k2[t]; lcc[t] = cc[t];
  __syncthreads();
  const int wv = t >> 6;
  const int lane = t & 63;
  const int q = lane >> 4, l = lane & 15;
  const int wm = wv >> 1, wn = wv & 1;
  f32x4 zero = {0.f, 0.f, 0.f, 0.f};
  f32x4 acc[4][4];
#pragma unroll
  for (int i = 0; i < 4; ++i)
#pragma unroll
    for (int j = 0; j < 4; ++j) acc[i][j] = zero;
  const int r0 = t >> 2;
  const int seg = (t & 3) * 8;
  const u16* Wg = Wmat + (size_t)(c0 + r0) * Cin + seg;
  const u16* Xplain = (big ? Xbig : xp);
  const u16* Xg = Xplain + ((size_t)g * LNODES + n0 + r0) * Cin + seg;
  const size_t a1base = ((size_t)g * LNODES + n0 + r0) * NCOUT + seg;
  const size_t a2base = ((size_t)(g >> 3) * LNODES + n0 + r0) * NCOUT + seg;
  const bool fuse = (MODE == 1) && big;
  for (int k0 = 0; k0 < Cin; k0 += 32) {
    uint4 w0 = *reinterpret_cast<const uint4*>(Wg + k0);
    uint4 w1 = *reinterpret_cast<const uint4*>(Wg + (size_t)64 * Cin + k0);
    uint4 x0, x1;
    if (fuse) {
      uint4 a1a = *reinterpret_cast<const uint4*>(&AGG1[a1base + k0]);
      uint4 a1b = *reinterpret_cast<const uint4*>(&AGG1[a1base + (size_t)64 * NCOUT + k0]);
      uint4 a2a = *reinterpret_cast<const uint4*>(&agg2[a2base + k0]);
      uint4 a2b = *reinterpret_cast<const uint4*>(&agg2[a2base + (size_t)64 * NCOUT + k0]);
      int kk = k0 + seg;
      float o0 = fmaxf(lk1[kk+0]*blo(a1a.x) + lk2[kk+0]*blo(a2a.x) + lcc[kk+0], 0.f);
      float o1 = fmaxf(lk1[kk+1]*bhi(a1a.x) + lk2[kk+1]*bhi(a2a.x) + lcc[kk+1], 0.f);
      float o2 = fmaxf(lk1[kk+2]*blo(a1a.y) + lk2[kk+2]*blo(a2a.y) + lcc[kk+2], 0.f);
      float o3 = fmaxf(lk1[kk+3]*bhi(a1a.y) + lk2[kk+3]*bhi(a2a.y) + lcc[kk+3], 0.f);
      float o4 = fmaxf(lk1[kk+4]*blo(a1a.z) + lk2[kk+4]*blo(a2a.z) + lcc[kk+4], 0.f);
      float o5 = fmaxf(lk1[kk+5]*bhi(a1a.z) + lk2[kk+5]*bhi(a2a.z) + lcc[kk+5], 0.f);
      float o6 = fmaxf(lk1[kk+6]*blo(a1a.w) + lk2[kk+6]*blo(a2a.w) + lcc[kk+6], 0.f);
      float o7 = fmaxf(lk1[kk+7]*bhi(a1a.w) + lk2[kk+7]*bhi(a2a.w) + lcc[kk+7], 0.f);
      x0 = {pk2(o0, o1), pk2(o2, o3), pk2(o4, o5), pk2(o6, o7)};
      float p0 = fmaxf(lk1[kk+0]*blo(a1b.x) + lk2[kk+0]*blo(a2b.x) + lcc[kk+0], 0.f);
      float p1 = fmaxf(lk1[kk+1]*bhi(a1b.x) + lk2[kk+1]*bhi(a2b.x) + lcc[kk+1], 0.f);
      float p2 = fmaxf(lk1[kk+2]*blo(a1b.y) + lk2[kk+2]*blo(a2b.y) + lcc[kk+2], 0.f);
      float p3 = fmaxf(lk1[kk+3]*bhi(a1b.y) + lk2[kk+3]*bhi(a2b.y) + lcc[kk+3], 0.f);
      float p4 = fmaxf(lk1[kk+4]*blo(a1b.z) + lk2[kk+4]*blo(a2b.z) + lcc[kk+4], 0.f);
      float p5 = fmaxf(lk1[kk+5]*bhi(a1b.z) + lk2[kk+5]*bhi(a2b.z) + lcc[kk+5], 0.f);
      float p6 = fmaxf(lk1[kk+6]*blo(a1b.w) + lk2[kk+6]*blo(a2b.w) + lcc[kk+6], 0.f);
      float p7 = fmaxf(lk1[kk+7]*bhi(a1b.w) + lk2[kk+7]*bhi(a2b.w) + lcc[kk+7], 0.f);
      x1 = {pk2(p0, p1), pk2(p2, p3), pk2(p4, p5), pk2(p6, p7)};
    } else {
      x0 = *reinterpret_cast<const uint4*>(Xg + k0);
      x1 = *reinterpret_cast<const uint4*>(Xg + (size_t)64 * Cin + k0);
    }
    __syncthreads();
    *reinterpret_cast<uint4*>(&Wsh[r0 * 40 + seg]) = w0;
    *reinterpret_cast<uint4*>(&Wsh[(r0 + 64) * 40 + seg]) = w1;
    *reinterpret_cast<uint4*>(&Xsh[r0 * 40 + seg]) = x0;
    *reinterpret_cast<uint4*>(&Xsh[(r0 + 64) * 40 + seg]) = x1;
    __syncthreads();
    bf16x8 af[4], bx[4];
#pragma unroll
    for (int fi = 0; fi < 4; ++fi)
      af[fi] = *reinterpret_cast<const bf16x8*>(&Wsh[(wm * 64 + fi * 16 + l) * 40 + q * 8]);
#pragma unroll
    for (int fj = 0; fj < 4; ++fj)
      bx[fj] = *reinterpret_cast<const bf16x8*>(&Xsh[(wn * 64 + fj * 16 + l) * 40 + q * 8]);
#pragma unroll
    for (int fi = 0; fi < 4; ++fi)
#pragma unroll
      for (int fj = 0; fj < 4; ++fj)
        acc[fi][fj] = __builtin_amdgcn_mfma_f32_16x16x32_bf16(af[fi], bx[fj], acc[fi][fj], 0, 0, 0);
  }
  __syncthreads();
  u16* Csh = smem;  // [128][136]
#pragma unroll
  for (int fi = 0; fi < 4; ++fi) {
#pragma unroll
    for (int fj = 0; fj < 4; ++fj) {
      int co_l = wm * 64 + fi * 16 + q * 4;
      int nd_l = wn * 64 + fj * 16 + l;
      uint2 pkd = {pk2(acc[fi][fj][0], acc[fi][fj][1]),
                   pk2(acc[fi][fj][2], acc[fi][fj][3])};
      *reinterpret_cast<uint2*>(&Csh[nd_l * 136 + co_l]) = pkd;
    }
  }
  __syncthreads();
#pragma unroll
  for (int p = 0; p < 8; ++p) {
    int idx = p * 256 + t;
    int nd = idx >> 4;
    int c8 = (idx & 15) * 8;
    uint4 v = *reinterpret_cast<const uint4*>(&Csh[nd * 136 + c8]);
    *reinterpret_cast<uint4*>(&out[((size_t)g * LNODES + n0 + nd) * NCOUT + c0 + c8]) = v;
  }
}

// ---------------- combined aggregation: big paired (1024 blocks) + sym (256) ----------------
__global__ __launch_bounds__(256) void agg_comb_k(const u16* __restrict__ HW1,
                                                  const u16* __restrict__ hw2,
                                                  const int* __restrict__ col,
                                                  const float* __restrict__ wn,
                                                  const int* __restrict__ rp,
                                                  const float* __restrict__ selfn,
                                                  u16* __restrict__ AGG1,
                                                  u16* __restrict__ agg2,
                                                  float* __restrict__ sum1,
                                                  float* __restrict__ sq1,
                                                  float* __restrict__ sum2,
                                                  float* __restrict__ sq2) {
  __shared__ float lsum[4][NCOUT], lsq[4][NCOUT];
  const int bid = blockIdx.x;
  const int t = threadIdx.x;
  const int wv = t >> 6;
  const int lc = (t & 63) * 4;
  float4 s = {0.f, 0.f, 0.f, 0.f}, qq = {0.f, 0.f, 0.f, 0.f};
  float* sumO;
  float* sqO;
  int shard;
  if (bid < 1024) {
    // big paired: g0 in [0,16), g1 = g0+16
    int slot = bid >> 3;
    int chunk = slot & 63;
    int g0 = (bid & 7) + 8 * (slot >> 6);
    const int d0 = chunk * ND;
    const u16* base0 = HW1 + (size_t)g0 * LNODES * NCOUT;
    const u16* base1 = base0 + (size_t)16 * LNODES * NCOUT;
    for (int i = wv; i < ND; i += 4) {
      int d = d0 + i;
      int e0 = rp[d], e1 = rp[d + 1];
      float sw = selfn[d];
      uint2 u0 = *reinterpret_cast<const uint2*>(&base0[(size_t)d * NCOUT + lc]);
      uint2 u1 = *reinterpret_cast<const uint2*>(&base1[(size_t)d * NCOUT + lc]);
      float4 a = {sw * blo(u0.x), sw * bhi(u0.x), sw * blo(u0.y), sw * bhi(u0.y)};
      float4 c = {sw * blo(u1.x), sw * bhi(u1.x), sw * blo(u1.y), sw * bhi(u1.y)};
      int e = e0;
      const int e4 = e0 + ((e1 - e0) & ~3);
      for (; e < e4; e += 4) {
        int i0 = col[e + 0], i1 = col[e + 1], i2 = col[e + 2], i3 = col[e + 3];
        float w0 = wn[e + 0], w1 = wn[e + 1], w2 = wn[e + 2], w3 = wn[e + 3];
        uint2 v0 = *reinterpret_cast<const uint2*>(&base0[(size_t)i0 * NCOUT + lc]);
        uint2 v1 = *reinterpret_cast<const uint2*>(&base0[(size_t)i1 * NCOUT + lc]);
        uint2 v2 = *reinterpret_cast<const uint2*>(&base0[(size_t)i2 * NCOUT + lc]);
        uint2 v3 = *reinterpret_cast<const uint2*>(&base0[(size_t)i3 * NCOUT + lc]);
        uint2 p0 = *reinterpret_cast<const uint2*>(&base1[(size_t)i0 * NCOUT + lc]);
        uint2 p1 = *reinterpret_cast<const uint2*>(&base1[(size_t)i1 * NCOUT + lc]);
        uint2 p2 = *reinterpret_cast<const uint2*>(&base1[(size_t)i2 * NCOUT + lc]);
        uint2 p3 = *reinterpret_cast<const uint2*>(&base1[(size_t)i3 * NCOUT + lc]);
        a.x += w0 * blo(v0.x); a.y += w0 * bhi(v0.x); a.z += w0 * blo(v0.y); a.w += w0 * bhi(v0.y);
        a.x += w1 * blo(v1.x); a.y += w1 * bhi(v1.x); a.z += w1 * blo(v1.y); a.w += w1 * bhi(v1.y);
        a.x += w2 * blo(v2.x); a.y += w2 * bhi(v2.x); a.z += w2 * blo(v2.y); a.w += w2 * bhi(v2.y);
        a.x += w3 * blo(v3.x); a.y += w3 * bhi(v3.x); a.z += w3 * blo(v3.y); a.w += w3 * bhi(v3.y);
        c.x += w0 * blo(p0.x); c.y += w0 * bhi(p0.x); c.z += w0 * blo(p0.y); c.w += w0 * bhi(p0.y);
        c.x += w1 * blo(p1.x); c.y += w1 * bhi(p1.x); c.z += w1 * blo(p1.y); c.w += w1 * bhi(p1.y);
        c.x += w2 * blo(p2.x); c.y += w2 * bhi(p2.x); c.z += w2 * blo(p2.y); c.w += w2 * bhi(p2.y);
        c.x += w3 * blo(p3.x); c.y += w3 * bhi(p3.x); c.z += w3 * blo(p3.y); c.w += w3 * bhi(p3.y);
      }
      for (; e < e1; ++e) {
        int ci = col[e];
        float w = wn[e];
        uint2 v = *reinterpret_cast<const uint2*>(&base0[(size_t)ci * NCOUT + lc]);
        uint2 pv = *reinterpret_cast<const uint2*>(&base1[(size_t)ci * NCOUT + lc]);
        a.x += w * blo(v.x); a.y += w * bhi(v.x); a.z += w * blo(v.y); a.w += w * bhi(v.y);
        c.x += w * blo(pv.x); c.y += w * bhi(pv.x); c.z += w * blo(pv.y); c.w += w * bhi(pv.y);
      }
      uint2 o0 = {pk2(a.x, a.y), pk2(a.z, a.w)};
      *reinterpret_cast<uint2*>(&AGG1[((size_t)g0 * LNODES + d) * NCOUT + lc]) = o0;
      uint2 o1 = {pk2(c.x, c.y), pk2(c.z, c.w)};
      *reinterpret_cast<uint2*>(&AGG1[((size_t)(g0 + 16) * LNODES + d) * NCOUT + lc]) = o1;
      s.x += a.x + c.x; s.y += a.y + c.y; s.z += a.z + c.z; s.w += a.w + c.w;
      qq.x += a.x * a.x + c.x * c.x; qq.y += a.y * a.y + c.y * c.y;
      qq.z += a.z * a.z + c.z * c.z; qq.w += a.w * a.w + c.w * c.w;
    }
    sumO = sum1; sqO = sq1; shard = (bid & 7) * NCOUT;
  } else {
    int b2 = bid - 1024;
    int g = b2 & (GSM - 1);
    int chunk = b2 >> 2;
    const int d0 = chunk * ND;
    const u16* base = hw2 + (size_t)g * LNODES * NCOUT;
    for (int i = wv; i < ND; i += 4) {
      int d = d0 + i;
      int e0 = rp[d], e1 = rp[d + 1];
      float sw = selfn[d];
      uint2 u = *reinterpret_cast<const uint2*>(&base[(size_t)d * NCOUT + lc]);
      float4 a = {sw * blo(u.x), sw * bhi(u.x), sw * blo(u.y), sw * bhi(u.y)};
      int e = e0;
      const int e4 = e0 + ((e1 - e0) & ~3);
      for (; e < e4; e += 4) {
        int i0 = col[e + 0], i1 = col[e + 1], i2 = col[e + 2], i3 = col[e + 3];
        float w0 = wn[e + 0], w1 = wn[e + 1], w2 = wn[e + 2], w3 = wn[e + 3];
        uint2 v0 = *reinterpret_cast<const uint2*>(&base[(size_t)i0 * NCOUT + lc]);
        uint2 v1 = *reinterpret_cast<const uint2*>(&base[(size_t)i1 * NCOUT + lc]);
        uint2 v2 = *reinterpret_cast<const uint2*>(&base[(size_t)i2 * NCOUT + lc]);
        uint2 v3 = *reinterpret_cast<const uint2*>(&base[(size_t)i3 * NCOUT + lc]);
        a.x += w0 * blo(v0.x); a.y += w0 * bhi(v0.x); a.z += w0 * blo(v0.y); a.w += w0 * bhi(v0.y);
        a.x += w1 * blo(v1.x); a.y += w1 * bhi(v1.x); a.z += w1 * blo(v1.y); a.w += w1 * bhi(v1.y);
        a.x += w2 * blo(v2.x); a.y += w2 * bhi(v2.x); a.z += w2 * blo(v2.y); a.w += w2 * bhi(v2.y);
        a.x += w3 * blo(v3.x); a.y += w3 * bhi(v3.x); a.z += w3 * blo(v3.y); a.w += w3 * bhi(v3.y);
      }
      for (; e < e1; ++e) {
        float w = wn[e];
        uint2 v = *reinterpret_cast<const uint2*>(&base[(size_t)col[e] * NCOUT + lc]);
        a.x += w * blo(v.x); a.y += w * bhi(v.x); a.z += w * blo(v.y); a.w += w * bhi(v.y);
      }
      uint2 o = {pk2(a.x, a.y), pk2(a.z, a.w)};
      *reinterpret_cast<uint2*>(&agg2[((size_t)g * LNODES + d) * NCOUT + lc]) = o;
      s.x += a.x; s.y += a.y; s.z += a.z; s.w += a.w;
      qq.x += a.x * a.x; qq.y += a.y * a.y; qq.z += a.z * a.z; qq.w += a.w * a.w;
    }
    sumO = sum2; sqO = sq2; shard = (b2 & 7) * NCOUT;
  }
  *reinterpret_cast<float4*>(&lsum[wv][lc]) = s;
  *reinterpret_cast<float4*>(&lsq[wv][lc]) = qq;
  __syncthreads();
  float ts = lsum[0][t] + lsum[1][t] + lsum[2][t] + lsum[3][t];
  float tq = lsq[0][t] + lsq[1][t] + lsq[2][t] + lsq[3][t];
  atomicAdd(&sumO[shard + t], ts);
  atomicAdd(&sqO[shard + t], tq);
}

// ---------------- BN finalize: read 8 shards, compute coefs, self-zero shards ----------------
__global__ __launch_bounds__(256) void bnfinal_k(float* __restrict__ sum1,
                                                 float* __restrict__ sq1,
                                                 float* __restrict__ sum2,
                                                 float* __restrict__ sq2,
                                                 const float* __restrict__ ga,
                                                 const float* __restrict__ be,
                                                 const float* __restrict__ gs,
                                                 const float* __restrict__ bes,
                                                 float* __restrict__ k1,
                                                 float* __restrict__ k2,
                                                 float* __restrict__ cc) {
  int co = threadIdx.x;
  float sA = 0.f, qA = 0.f, sB = 0.f, qB = 0.f;
#pragma unroll
  for (int x = 0; x < 8; ++x) {
    sA += sum1[x * NCOUT + co];
    qA += sq1[x * NCOUT + co];
    sB += sum2[x * NCOUT + co];
    qB += sq2[x * NCOUT + co];
    sum1[x * NCOUT + co] = 0.f;
    sq1[x * NCOUT + co] = 0.f;
    sum2[x * NCOUT + co] = 0.f;
    sq2[x * NCOUT + co] = 0.f;
  }
  const float c1 = (float)(GBIG * LNODES), c2 = (float)(GSM * LNODES);
  float mA = sA / c1;
  float vA = qA / c1 - mA * mA;
  float kA = ga[co] * rsqrtf(vA + BN_EPS);
  float mB = sB / c2;
  float vB = qB / c2 - mB * mB;
  float kB = gs[co] * rsqrtf(vB + BN_EPS);
  k1[co] = kA;
  k2[co] = kB;
  cc[co] = be[co] - kA * mA + bes[co] - kB * mB;
}

// ---------------- layer 2: fuse + transpose to channel-major fp32 d_out ----------------
__global__ __launch_bounds__(256) void fuse_tr_bf_k(const u16* __restrict__ A1,
                                                    const u16* __restrict__ A2,
                                                    const float* __restrict__ k1,
                                                    const float* __restrict__ k2,
                                                    const float* __restrict__ cc,
                                                    float* __restrict__ O) {
  __shared__ float T[64][65];  // [node_local][co_local]
  const int g = blockIdx.z;
  const int d0 = blockIdx.x * 64;
  const int c0 = blockIdx.y * 64;
  const int b = g >> 3;
  const int tr = threadIdx.x >> 4;
  const int tc = (threadIdx.x & 15) * 4;
  float4 K1 = *reinterpret_cast<const float4*>(&k1[c0 + tc]);
  float4 K2 = *reinterpret_cast<const float4*>(&k2[c0 + tc]);
  float4 CC = *reinterpret_cast<const float4*>(&cc[c0 + tc]);
#pragma unroll
  for (int p = 0; p < 4; ++p) {
    int d = d0 + tr + p * 16;
    uint2 a1 = *reinterpret_cast<const uint2*>(&A1[((size_t)g * LNODES + d) * NCOUT + c0 + tc]);
    uint2 a2 = *reinterpret_cast<const uint2*>(&A2[((size_t)b * LNODES + d) * NCOUT + c0 + tc]);
    T[tr + p * 16][tc + 0] = fmaxf(K1.x * blo(a1.x) + K2.x * blo(a2.x) + CC.x, 0.f);
    T[tr + p * 16][tc + 1] = fmaxf(K1.y * bhi(a1.x) + K2.y * bhi(a2.x) + CC.y, 0.f);
    T[tr + p * 16][tc + 2] = fmaxf(K1.z * blo(a1.y) + K2.z * blo(a2.y) + CC.z, 0.f);
    T[tr + p * 16][tc + 3] = fmaxf(K1.w * bhi(a1.y) + K2.w * bhi(a2.y) + CC.w, 0.f);
  }
  __syncthreads();
#pragma unroll
  for (int p = 0; p < 4; ++p) {
    int c = tr + p * 16;
    float4 o = {T[tc + 0][c], T[tc + 1][c], T[tc + 2][c], T[tc + 3][c]};
    *reinterpret_cast<float4*>(&O[((size_t)g * NCOUT + c0 + c) * LNODES + d0 + tc]) = o;
  }
}

// ---------------- launch ----------------

extern "C" void kernel_launch(void* const* d_in, const int* in_sizes, int n_in,
                              void* d_out, int out_size, void* d_ws, size_t ws_size,
                              hipStream_t stream) {
  const float* x_in = (const float*)d_in[0];
  const int* ei = (const int*)d_in[1];
  const float* W[3]   = {(const float*)d_in[2],  (const float*)d_in[4],  (const float*)d_in[6]};
  const float* Wsym[3]= {(const float*)d_in[8],  (const float*)d_in[10], (const float*)d_in[12]};
  const float* ga[3]  = {(const float*)d_in[14], (const float*)d_in[16], (const float*)d_in[18]};
  const float* be[3]  = {(const float*)d_in[15], (const float*)d_in[17], (const float*)d_in[19]};
  const float* gs[3]  = {(const float*)d_in[20], (const float*)d_in[22], (const float*)d_in[24]};
  const float* bes[3] = {(const float*)d_in[21], (const float*)d_in[23], (const float*)d_in[25]};

  const size_t EBIG = (size_t)GBIG * LNODES * NCOUT;  // 16.7M elems
  const size_t ESM = (size_t)GSM * LNODES * NCOUT;
  char* p = (char*)d_ws;
  u16* XT0  = (u16*)p; p += (size_t)GBIG * LNODES * 128 * 2;  // 16 MiB layer-0 input
  u16* AGG1 = (u16*)p; p += EBIG * 2;   // 32 MiB
  u16* agg2 = (u16*)p; p += ESM * 2;    // 4 MiB
  u16* xp   = (u16*)p; p += ESM * 2;    // 4 MiB
  u16* hw2  = (u16*)p; p += ESM * 2;    // 4 MiB
  u16* WbT[3], *WsT[3];
  for (int i = 0; i < 3; ++i) { WbT[i] = (u16*)p; p += NCOUT * NCOUT * 2; }
  for (int i = 0; i < 3; ++i) { WsT[i] = (u16*)p; p += NCOUT * NCOUT * 2; }
  int*   col  = (int*)p;   p += NEDGE * 4;
  float* wn   = (float*)p; p += NEDGE * 4;
  int*   rp   = (int*)p;   p += 2064 * 4;
  float* dis  = (float*)p; p += LNODES * 4;
  float* selfn= (float*)p; p += LNODES * 4;
  char* zbase = p;
  float* deg  = (float*)p; p += LNODES * 4;
  int*   cnt  = (int*)p;   p += LNODES * 4;
  int*   fillc= (int*)p;   p += LNODES * 4;
  float* sum1 = (float*)p; p += 8 * 1024;  // stats zeroed with zbase memset
  float* sq1  = (float*)p; p += 8 * 1024;
  float* sum2 = (float*)p; p += 8 * 1024;
  float* sq2  = (float*)p; p += 8 * 1024;
  size_t zsize = (size_t)(p - zbase);
  float* k1 = (float*)p; p += 1024;
  float* k2 = (float*)p; p += 1024;
  float* cc = (float*)p; p += 1024;
  u16* HW1 = (u16*)d_out;  // big GEMM out in d_out (dead by fuse_tr time)

  // ---- setup: CSR + weights + input transpose + layer-0 pool ----
  hipMemsetAsync(zbase, 0, zsize, stream);
  count_deg_k<<<NEDGE / 256, 256, 0, stream>>>(ei, deg, cnt);
  dis_k<<<LNODES / 256, 256, 0, stream>>>(deg, dis, selfn);
  scan_k<<<1, 256, 0, stream>>>(cnt, rp);
  fill_k<<<NEDGE / 256, 256, 0, stream>>>(ei, rp, fillc, dis, col, wn);
  WCvt wc;
  for (int i = 0; i < 3; ++i) {
    wc.src[i] = W[i];     wc.dst[i] = WbT[i];     wc.ci[i] = (i == 0) ? 128 : 256;
    wc.src[3 + i] = Wsym[i]; wc.dst[3 + i] = WsT[i]; wc.ci[3 + i] = (i == 0) ? 128 : 256;
  }
  cvtw_all_k<<<dim3(4, 4, 6), 256, 0, stream>>>(wc);
  trans_k<<<dim3(LNODES / 64, 128 / 64, GBIG), 256, 0, stream>>>(x_in, XT0, 128);
  pool_bf_k<<<GSM * 128 * LNODES / 8 / 256, 256, 0, stream>>>(XT0, xp, 128 * LNODES);

  for (int l = 0; l < 3; ++l) {
    if (l > 0) {
      // produce xp for this layer from previous layer's AGG1/agg2 + coefs
      poolonly_k<<<dim3(256, GSM), 256, 0, stream>>>(AGG1, agg2, k1, k2, cc, xp);
      gemm_all_k<1><<<dim3(LNODES / 128, NCOUT / 128, GBIG + GSM), 256, 0, stream>>>(
          XT0, AGG1, agg2, k1, k2, cc, xp, WbT[l], WsT[l], HW1, hw2, NCOUT);
    } else {
      gemm_all_k<0><<<dim3(LNODES / 128, NCOUT / 128, GBIG + GSM), 256, 0, stream>>>(
          XT0, AGG1, agg2, k1, k2, cc, xp, WbT[l], WsT[l], HW1, hw2, 128);
    }
    agg_comb_k<<<1280, 256, 0, stream>>>(HW1, hw2, col, wn, rp, selfn,
                                         AGG1, agg2, sum1, sq1, sum2, sq2);
    bnfinal_k<<<1, 256, 0, stream>>>(sum1, sq1, sum2, sq2,
                                     ga[l], be[l], gs[l], bes[l], k1, k2, cc);
  }
  fuse_tr_bf_k<<<dim3(LNODES / 64, NCOUT / 64, GBIG), 256, 0, stream>>>(
      AGG1, agg2, k1, k2, cc, (float*)d_out);
}

// Round 10
// 367.326 us; speedup vs baseline: 6.0344x; 1.0244x over previous
//
#include <hip/hip_runtime.h>
#include <math.h>

#define LNODES 2048
#define NEDGE 16384
#define GBIG 32
#define GSM 4
#define NCOUT 256
#define BN_EPS 1e-5f
#define ND 32  // dst nodes per agg block

typedef unsigned short u16;
typedef __attribute__((ext_vector_type(8))) short bf16x8;
typedef __attribute__((ext_vector_type(4))) float f32x4;

__device__ __forceinline__ unsigned pk2(float a, float b) {  // a->lo, b->hi
  unsigned ua = __float_as_uint(a); ua += 0x7fffu + ((ua >> 16) & 1u);
  unsigned ub = __float_as_uint(b); ub += 0x7fffu + ((ub >> 16) & 1u);
  return (ua >> 16) | (ub & 0xffff0000u);
}
__device__ __forceinline__ float blo(unsigned u) { return __uint_as_float(u << 16); }
__device__ __forceinline__ float bhi(unsigned u) { return __uint_as_float(u & 0xffff0000u); }

// ---------------- setup: degree, dis, CSR ----------------

__global__ __launch_bounds__(256) void count_deg_k(const int* __restrict__ ei,
                                                   float* __restrict__ deg,
                                                   int* __restrict__ cnt) {
  int e = blockIdx.x * 256 + threadIdx.x;
  if (e < NEDGE) {
    int d = ei[NEDGE + e];
    atomicAdd(&deg[d], 1.0f);
    atomicAdd(&cnt[d], 1);
  }
}

__global__ __launch_bounds__(256) void dis_k(const float* __restrict__ deg,
                                             float* __restrict__ dis,
                                             float* __restrict__ selfn) {
  int i = blockIdx.x * 256 + threadIdx.x;
  if (i < LNODES) {
    float di = rsqrtf(deg[i] + 2.0f);  // improved=True self loop weight 2
    dis[i] = di;
    selfn[i] = 2.0f * di * di;
  }
}

__global__ __launch_bounds__(256) void scan_k(const int* __restrict__ cnt,
                                              int* __restrict__ rp) {
  __shared__ int part[256];
  int t = threadIdx.x;
  int base = t * 8;
  int loc[8];
  int s = 0;
#pragma unroll
  for (int j = 0; j < 8; ++j) { loc[j] = s; s += cnt[base + j]; }
  part[t] = s;
  __syncthreads();
  for (int off = 1; off < 256; off <<= 1) {
    int v = (t >= off) ? part[t - off] : 0;
    __syncthreads();
    part[t] += v;
    __syncthreads();
  }
  int excl = (t == 0) ? 0 : part[t - 1];
#pragma unroll
  for (int j = 0; j < 8; ++j) rp[base + j] = excl + loc[j];
  if (t == 255) rp[LNODES] = part[255];
}

__global__ __launch_bounds__(256) void fill_k(const int* __restrict__ ei,
                                              const int* __restrict__ rp,
                                              int* __restrict__ fillc,
                                              const float* __restrict__ dis,
                                              int* __restrict__ col,
                                              float* __restrict__ wn) {
  int e = blockIdx.x * 256 + threadIdx.x;
  if (e < NEDGE) {
    int s = ei[e], d = ei[NEDGE + e];
    int pos = rp[d] + atomicAdd(&fillc[d], 1);
    col[pos] = s;
    wn[pos] = dis[s] * dis[d];
  }
}

// ---------------- x [G][Cin][L] f32 -> XT [G][L][Cin] bf16 ----------------
__global__ __launch_bounds__(256) void trans_k(const float* __restrict__ X,
                                               u16* __restrict__ XT, int Cin) {
  __shared__ float T[64][65];  // [ci_local][node_local]
  const int g = blockIdx.z;
  const int n0 = blockIdx.x * 64;
  const int c0 = blockIdx.y * 64;
  const int tr = threadIdx.x >> 4;
  const int tc = (threadIdx.x & 15) * 4;
#pragma unroll
  for (int p = 0; p < 4; ++p) {
    int ci = c0 + tr + p * 16;
    float4 v = *reinterpret_cast<const float4*>(&X[((size_t)g * Cin + ci) * LNODES + n0 + tc]);
    T[tr + p * 16][tc + 0] = v.x; T[tr + p * 16][tc + 1] = v.y;
    T[tr + p * 16][tc + 2] = v.z; T[tr + p * 16][tc + 3] = v.w;
  }
  __syncthreads();
#pragma unroll
  for (int p = 0; p < 4; ++p) {
    int nd = tr + p * 16;
    uint2 o = {pk2(T[tc + 0][nd], T[tc + 1][nd]), pk2(T[tc + 2][nd], T[tc + 3][nd])};
    *reinterpret_cast<uint2*>(&XT[((size_t)g * LNODES + n0 + nd) * Cin + c0 + tc]) = o;
  }
}

// ---------------- all 6 weights: W [Ci][256] f32 -> WT [256][Ci] bf16, one launch ----------------
struct WCvt {
  const float* src[6];
  u16* dst[6];
  int ci[6];
};
__global__ __launch_bounds__(256) void cvtw_all_k(WCvt wp) {
  __shared__ float T[64][65];
  const int w = blockIdx.z;
  const int Ci = wp.ci[w];
  const int ci0 = blockIdx.y * 64;
  if (ci0 >= Ci) return;
  const float* W = wp.src[w];
  u16* WT = wp.dst[w];
  const int co0 = blockIdx.x * 64;
  const int tr = threadIdx.x >> 4;
  const int tc = (threadIdx.x & 15) * 4;
#pragma unroll
  for (int p = 0; p < 4; ++p) {
    int ci = ci0 + tr + p * 16;
    float4 v = *reinterpret_cast<const float4*>(&W[(size_t)ci * NCOUT + co0 + tc]);
    T[tr + p * 16][tc + 0] = v.x; T[tr + p * 16][tc + 1] = v.y;
    T[tr + p * 16][tc + 2] = v.z; T[tr + p * 16][tc + 3] = v.w;
  }
  __syncthreads();
#pragma unroll
  for (int p = 0; p < 4; ++p) {
    int co = tr + p * 16;
    uint2 o = {pk2(T[tc + 0][co], T[tc + 1][co]), pk2(T[tc + 2][co], T[tc + 3][co])};
    *reinterpret_cast<uint2*>(&WT[(size_t)(co0 + co) * Ci + ci0 + tc]) = o;
  }
}

// ---------------- layer-0 max-pool over N=8 (raw bf16 input) ----------------
__global__ __launch_bounds__(256) void pool_bf_k(const u16* __restrict__ X,
                                                 u16* __restrict__ XP, int per) {
  int i = blockIdx.x * 256 + threadIdx.x;
  size_t f = (size_t)i * 8;
  int b = (int)(f / per);
  size_t rem = f - (size_t)b * per;
  const u16* base = X + (size_t)b * 8 * per + rem;
  uint4 u = *reinterpret_cast<const uint4*>(base);
  float m0 = blo(u.x), m1 = bhi(u.x), m2 = blo(u.y), m3 = bhi(u.y);
  float m4 = blo(u.z), m5 = bhi(u.z), m6 = blo(u.w), m7 = bhi(u.w);
#pragma unroll
  for (int j = 1; j < 8; ++j) {
    uint4 v = *reinterpret_cast<const uint4*>(base + (size_t)j * per);
    m0 = fmaxf(m0, blo(v.x)); m1 = fmaxf(m1, bhi(v.x));
    m2 = fmaxf(m2, blo(v.y)); m3 = fmaxf(m3, bhi(v.y));
    m4 = fmaxf(m4, blo(v.z)); m5 = fmaxf(m5, bhi(v.z));
    m6 = fmaxf(m6, blo(v.w)); m7 = fmaxf(m7, bhi(v.w));
  }
  uint4 o = {pk2(m0, m1), pk2(m2, m3), pk2(m4, m5), pk2(m6, m7)};
  *reinterpret_cast<uint4*>(XP + (size_t)b * per + rem) = o;
}

// ---------------- coef reduction helper: shards -> LDS k1/k2/cc ----------------
// st layout per layer: sum1[8][256] | sq1 | sum2 | sq2 (floats, 8192 total)
__device__ __forceinline__ void coef_ld(const float* __restrict__ st,
                                        const float* __restrict__ ga,
                                        const float* __restrict__ be,
                                        const float* __restrict__ gs,
                                        const float* __restrict__ bes,
                                        float* lk1, float* lk2, float* lcc, int t) {
  float sA = 0.f, qA = 0.f, sB = 0.f, qB = 0.f;
#pragma unroll
  for (int x = 0; x < 8; ++x) {
    sA += st[x * NCOUT + t];
    qA += st[2048 + x * NCOUT + t];
    sB += st[4096 + x * NCOUT + t];
    qB += st[6144 + x * NCOUT + t];
  }
  const float c1 = (float)(GBIG * LNODES), c2 = (float)(GSM * LNODES);
  float mA = sA / c1;
  float vA = qA / c1 - mA * mA;
  float kA = ga[t] * rsqrtf(vA + BN_EPS);
  float mB = sB / c2;
  float vB = qB / c2 - mB * mB;
  float kB = gs[t] * rsqrtf(vB + BN_EPS);
  lk1[t] = kA;
  lk2[t] = kB;
  lcc[t] = be[t] - kA * mA + bes[t] - kB * mB;
}

// ---------------- bf16 MFMA GEMM, combined sym+big, fused BN(+pool) staging ----------------
// z<4: sym path, g=z=b. MODE 1: A staged on the fly = max_n relu(k1*AGG1[b*8+n]
//   + k2*agg2[b] + cc)  (rounding is monotonic -> identical to pool-then-GEMM).
// z>=4: big path, g=z-4. MODE 1: A = relu(k1*AGG1[g] + k2*agg2[g/8] + cc).
// MODE 0 (layer 0): plain A from Xbig / xp, no coefs needed.
template <int MODE>
__global__ __launch_bounds__(256) void gemm_all_k(const u16* __restrict__ Xbig,
                                                  const u16* __restrict__ xp,
                                                  const u16* __restrict__ AGG1,
                                                  const u16* __restrict__ agg2,
                                                  const float* __restrict__ st,
                                                  const float* __restrict__ ga,
                                                  const float* __restrict__ be,
                                                  const float* __restrict__ gs,
                                                  const float* __restrict__ bes,
                                                  const u16* __restrict__ WbT,
                                                  const u16* __restrict__ WsT,
                                                  u16* __restrict__ HW1,
                                                  u16* __restrict__ hw2,
                                                  int Cin) {
  __shared__ u16 smem[17408];      // K-loop: 2x[128][40]; epilogue [128][136]
  __shared__ float lk1[NCOUT], lk2[NCOUT], lcc[NCOUT];
  u16* Wsh = smem;
  u16* Xsh = smem + 128 * 40;
  const int z = blockIdx.z;
  const bool sym = z < GSM;
  const int g = sym ? z : z - GSM;
  const u16* Wmat = sym ? WsT : WbT;
  u16* out = sym ? hw2 : HW1;
  const int n0 = blockIdx.x * 128;
  const int c0 = blockIdx.y * 128;
  const int t = threadIdx.x;
  if (MODE == 1) {
    coef_ld(st, ga, be, gs, bes, lk1, lk2, lcc, t);
    __syncthreads();
  }
  const int wv = t >> 6;
  const int lane = t & 63;
  const int q = lane >> 4, l = lane & 15;
  const int wm = wv >> 1, wn = wv & 1;
  f32x4 zero = {0.f, 0.f, 0.f, 0.f};
  f32x4 acc[4][4];
#pragma unroll
  for (int i = 0; i < 4; ++i)
#pragma unroll
    for (int j = 0; j < 4; ++j) acc[i][j] = zero;
  const int r0 = t >> 2;
  const int seg = (t & 3) * 8;
  const u16* Wg = Wmat + (size_t)(c0 + r0) * Cin + seg;
  const u16* Xplain = sym ? xp : Xbig;
  const u16* Xg = Xplain + ((size_t)g * LNODES + n0 + r0) * Cin + seg;
  const size_t rowd = (size_t)(n0 + r0);
  const size_t nstep = (size_t)LNODES * NCOUT;
  const size_t a1base = sym ? (((size_t)(g * 8) * LNODES + rowd) * NCOUT + seg)
                            : (((size_t)g * LNODES + rowd) * NCOUT + seg);
  const size_t a2base = sym ? (((size_t)g * LNODES + rowd) * NCOUT + seg)
                            : (((size_t)(g >> 3) * LNODES + rowd) * NCOUT + seg);
  for (int k0 = 0; k0 < Cin; k0 += 32) {
    uint4 w0 = *reinterpret_cast<const uint4*>(Wg + k0);
    uint4 w1 = *reinterpret_cast<const uint4*>(Wg + (size_t)64 * Cin + k0);
    uint4 x0, x1;
    if (MODE == 0) {
      x0 = *reinterpret_cast<const uint4*>(Xg + k0);
      x1 = *reinterpret_cast<const uint4*>(Xg + (size_t)64 * Cin + k0);
    } else {
      int kk = k0 + seg;
      float K10 = lk1[kk+0], K11 = lk1[kk+1], K12 = lk1[kk+2], K13 = lk1[kk+3];
      float K14 = lk1[kk+4], K15 = lk1[kk+5], K16 = lk1[kk+6], K17 = lk1[kk+7];
      if (!sym) {
        uint4 a1a = *reinterpret_cast<const uint4*>(&AGG1[a1base + k0]);
        uint4 a1b = *reinterpret_cast<const uint4*>(&AGG1[a1base + 64 * (size_t)NCOUT + k0]);
        uint4 a2a = *reinterpret_cast<const uint4*>(&agg2[a2base + k0]);
        uint4 a2b = *reinterpret_cast<const uint4*>(&agg2[a2base + 64 * (size_t)NCOUT + k0]);
        float o0 = fmaxf(K10*blo(a1a.x) + lk2[kk+0]*blo(a2a.x) + lcc[kk+0], 0.f);
        float o1 = fmaxf(K11*bhi(a1a.x) + lk2[kk+1]*bhi(a2a.x) + lcc[kk+1], 0.f);
        float o2 = fmaxf(K12*blo(a1a.y) + lk2[kk+2]*blo(a2a.y) + lcc[kk+2], 0.f);
        float o3 = fmaxf(K13*bhi(a1a.y) + lk2[kk+3]*bhi(a2a.y) + lcc[kk+3], 0.f);
        float o4 = fmaxf(K14*blo(a1a.z) + lk2[kk+4]*blo(a2a.z) + lcc[kk+4], 0.f);
        float o5 = fmaxf(K15*bhi(a1a.z) + lk2[kk+5]*bhi(a2a.z) + lcc[kk+5], 0.f);
        float o6 = fmaxf(K16*blo(a1a.w) + lk2[kk+6]*blo(a2a.w) + lcc[kk+6], 0.f);
        float o7 = fmaxf(K17*bhi(a1a.w) + lk2[kk+7]*bhi(a2a.w) + lcc[kk+7], 0.f);
        x0 = {pk2(o0, o1), pk2(o2, o3), pk2(o4, o5), pk2(o6, o7)};
        float p0 = fmaxf(K10*blo(a1b.x) + lk2[kk+0]*blo(a2b.x) + lcc[kk+0], 0.f);
        float p1 = fmaxf(K11*bhi(a1b.x) + lk2[kk+1]*bhi(a2b.x) + lcc[kk+1], 0.f);
        float p2 = fmaxf(K12*blo(a1b.y) + lk2[kk+2]*blo(a2b.y) + lcc[kk+2], 0.f);
        float p3 = fmaxf(K13*bhi(a1b.y) + lk2[kk+3]*bhi(a2b.y) + lcc[kk+3], 0.f);
        float p4 = fmaxf(K14*blo(a1b.z) + lk2[kk+4]*blo(a2b.z) + lcc[kk+4], 0.f);
        float p5 = fmaxf(K15*bhi(a1b.z) + lk2[kk+5]*bhi(a2b.z) + lcc[kk+5], 0.f);
        float p6 = fmaxf(K16*blo(a1b.w) + lk2[kk+6]*blo(a2b.w) + lcc[kk+6], 0.f);
        float p7 = fmaxf(K17*bhi(a1b.w) + lk2[kk+7]*bhi(a2b.w) + lcc[kk+7], 0.f);
        x1 = {pk2(p0, p1), pk2(p2, p3), pk2(p4, p5), pk2(p6, p7)};
      } else {
        // sym: pooled A = max(0, max_n(k1*a1_n + (k2*a2 + cc)))
        uint4 a2a = *reinterpret_cast<const uint4*>(&agg2[a2base + k0]);
        uint4 a2b = *reinterpret_cast<const uint4*>(&agg2[a2base + 64 * (size_t)NCOUT + k0]);
        float t0 = lk2[kk+0]*blo(a2a.x) + lcc[kk+0], t1 = lk2[kk+1]*bhi(a2a.x) + lcc[kk+1];
        float t2 = lk2[kk+2]*blo(a2a.y) + lcc[kk+2], t3 = lk2[kk+3]*bhi(a2a.y) + lcc[kk+3];
        float t4 = lk2[kk+4]*blo(a2a.z) + lcc[kk+4], t5 = lk2[kk+5]*bhi(a2a.z) + lcc[kk+5];
        float t6 = lk2[kk+6]*blo(a2a.w) + lcc[kk+6], t7 = lk2[kk+7]*bhi(a2a.w) + lcc[kk+7];
        float u0 = lk2[kk+0]*blo(a2b.x) + lcc[kk+0], u1 = lk2[kk+1]*bhi(a2b.x) + lcc[kk+1];
        float u2 = lk2[kk+2]*blo(a2b.y) + lcc[kk+2], u3 = lk2[kk+3]*bhi(a2b.y) + lcc[kk+3];
        float u4 = lk2[kk+4]*blo(a2b.z) + lcc[kk+4], u5 = lk2[kk+5]*bhi(a2b.z) + lcc[kk+5];
        float u6 = lk2[kk+6]*blo(a2b.w) + lcc[kk+6], u7 = lk2[kk+7]*bhi(a2b.w) + lcc[kk+7];
        float m0 = 0.f, m1 = 0.f, m2 = 0.f, m3 = 0.f, m4 = 0.f, m5 = 0.f, m6 = 0.f, m7 = 0.f;
        float e0 = 0.f, e1 = 0.f, e2 = 0.f, e3 = 0.f, e4 = 0.f, e5 = 0.f, e6 = 0.f, e7 = 0.f;
#pragma unroll
        for (int n = 0; n < 8; ++n) {
          uint4 a1a = *reinterpret_cast<const uint4*>(&AGG1[a1base + n * nstep + k0]);
          uint4 a1b = *reinterpret_cast<const uint4*>(&AGG1[a1base + n * nstep + 64 * (size_t)NCOUT + k0]);
          m0 = fmaxf(m0, K10*blo(a1a.x) + t0); m1 = fmaxf(m1, K11*bhi(a1a.x) + t1);
          m2 = fmaxf(m2, K12*blo(a1a.y) + t2); m3 = fmaxf(m3, K13*bhi(a1a.y) + t3);
          m4 = fmaxf(m4, K14*blo(a1a.z) + t4); m5 = fmaxf(m5, K15*bhi(a1a.z) + t5);
          m6 = fmaxf(m6, K16*blo(a1a.w) + t6); m7 = fmaxf(m7, K17*bhi(a1a.w) + t7);
          e0 = fmaxf(e0, K10*blo(a1b.x) + u0); e1 = fmaxf(e1, K11*bhi(a1b.x) + u1);
          e2 = fmaxf(e2, K12*blo(a1b.y) + u2); e3 = fmaxf(e3, K13*bhi(a1b.y) + u3);
          e4 = fmaxf(e4, K14*blo(a1b.z) + u4); e5 = fmaxf(e5, K15*bhi(a1b.z) + u5);
          e6 = fmaxf(e6, K16*blo(a1b.w) + u6); e7 = fmaxf(e7, K17*bhi(a1b.w) + u7);
        }
        x0 = {pk2(m0, m1), pk2(m2, m3), pk2(m4, m5), pk2(m6, m7)};
        x1 = {pk2(e0, e1), pk2(e2, e3), pk2(e4, e5), pk2(e6, e7)};
      }
    }
    __syncthreads();
    *reinterpret_cast<uint4*>(&Wsh[r0 * 40 + seg]) = w0;
    *reinterpret_cast<uint4*>(&Wsh[(r0 + 64) * 40 + seg]) = w1;
    *reinterpret_cast<uint4*>(&Xsh[r0 * 40 + seg]) = x0;
    *reinterpret_cast<uint4*>(&Xsh[(r0 + 64) * 40 + seg]) = x1;
    __syncthreads();
    bf16x8 af[4], bx[4];
#pragma unroll
    for (int fi = 0; fi < 4; ++fi)
      af[fi] = *reinterpret_cast<const bf16x8*>(&Wsh[(wm * 64 + fi * 16 + l) * 40 + q * 8]);
#pragma unroll
    for (int fj = 0; fj < 4; ++fj)
      bx[fj] = *reinterpret_cast<const bf16x8*>(&Xsh[(wn * 64 + fj * 16 + l) * 40 + q * 8]);
#pragma unroll
    for (int fi = 0; fi < 4; ++fi)
#pragma unroll
      for (int fj = 0; fj < 4; ++fj)
        acc[fi][fj] = __builtin_amdgcn_mfma_f32_16x16x32_bf16(af[fi], bx[fj], acc[fi][fj], 0, 0, 0);
  }
  __syncthreads();
  u16* Csh = smem;  // [128][136]
#pragma unroll
  for (int fi = 0; fi < 4; ++fi) {
#pragma unroll
    for (int fj = 0; fj < 4; ++fj) {
      int co_l = wm * 64 + fi * 16 + q * 4;
      int nd_l = wn * 64 + fj * 16 + l;
      uint2 pkd = {pk2(acc[fi][fj][0], acc[fi][fj][1]),
                   pk2(acc[fi][fj][2], acc[fi][fj][3])};
      *reinterpret_cast<uint2*>(&Csh[nd_l * 136 + co_l]) = pkd;
    }
  }
  __syncthreads();
#pragma unroll
  for (int p = 0; p < 8; ++p) {
    int idx = p * 256 + t;
    int nd = idx >> 4;
    int c8 = (idx & 15) * 8;
    uint4 v = *reinterpret_cast<const uint4*>(&Csh[nd * 136 + c8]);
    *reinterpret_cast<uint4*>(&out[((size_t)g * LNODES + n0 + nd) * NCOUT + c0 + c8]) = v;
  }
}

// ---------------- combined aggregation: big paired (1024 blocks) + sym (256) ----------------
// Branchless edge loop: col/wn padded with 8 zeroed entries; weights predicated.
__global__ __launch_bounds__(256) void agg_comb_k(const u16* __restrict__ HW1,
                                                  const u16* __restrict__ hw2,
                                                  const int* __restrict__ col,
                                                  const float* __restrict__ wn,
                                                  const int* __restrict__ rp,
                                                  const float* __restrict__ selfn,
                                                  u16* __restrict__ AGG1,
                                                  u16* __restrict__ agg2,
                                                  float* __restrict__ st) {
  __shared__ float lsum[4][NCOUT], lsq[4][NCOUT];
  const int bid = blockIdx.x;
  const int t = threadIdx.x;
  const int wv = t >> 6;
  const int lc = (t & 63) * 4;
  float4 s = {0.f, 0.f, 0.f, 0.f}, qq = {0.f, 0.f, 0.f, 0.f};
  float* sumO;
  float* sqO;
  int shard;
  if (bid < 1024) {
    int slot = bid >> 3;
    int chunk = slot & 63;
    int g0 = (bid & 7) + 8 * (slot >> 6);
    const int d0 = chunk * ND;
    const u16* base0 = HW1 + (size_t)g0 * LNODES * NCOUT;
    const u16* base1 = base0 + (size_t)16 * LNODES * NCOUT;
    for (int i = wv; i < ND; i += 4) {
      int d = d0 + i;
      int e0 = rp[d], e1 = rp[d + 1];
      float sw = selfn[d];
      uint2 u0 = *reinterpret_cast<const uint2*>(&base0[(size_t)d * NCOUT + lc]);
      uint2 u1 = *reinterpret_cast<const uint2*>(&base1[(size_t)d * NCOUT + lc]);
      float4 a = {sw * blo(u0.x), sw * bhi(u0.x), sw * blo(u0.y), sw * bhi(u0.y)};
      float4 c = {sw * blo(u1.x), sw * bhi(u1.x), sw * blo(u1.y), sw * bhi(u1.y)};
      for (int e = e0; e < e1; e += 4) {
        int i0 = col[e + 0], i1 = col[e + 1], i2 = col[e + 2], i3 = col[e + 3];
        float w0 = wn[e + 0];
        float w1 = (e + 1 < e1) ? wn[e + 1] : 0.f;
        float w2 = (e + 2 < e1) ? wn[e + 2] : 0.f;
        float w3 = (e + 3 < e1) ? wn[e + 3] : 0.f;
        uint2 v0 = *reinterpret_cast<const uint2*>(&base0[(size_t)i0 * NCOUT + lc]);
        uint2 v1 = *reinterpret_cast<const uint2*>(&base0[(size_t)i1 * NCOUT + lc]);
        uint2 v2 = *reinterpret_cast<const uint2*>(&base0[(size_t)i2 * NCOUT + lc]);
        uint2 v3 = *reinterpret_cast<const uint2*>(&base0[(size_t)i3 * NCOUT + lc]);
        uint2 p0 = *reinterpret_cast<const uint2*>(&base1[(size_t)i0 * NCOUT + lc]);
        uint2 p1 = *reinterpret_cast<const uint2*>(&base1[(size_t)i1 * NCOUT + lc]);
        uint2 p2 = *reinterpret_cast<const uint2*>(&base1[(size_t)i2 * NCOUT + lc]);
        uint2 p3 = *reinterpret_cast<const uint2*>(&base1[(size_t)i3 * NCOUT + lc]);
        a.x += w0 * blo(v0.x); a.y += w0 * bhi(v0.x); a.z += w0 * blo(v0.y); a.w += w0 * bhi(v0.y);
        a.x += w1 * blo(v1.x); a.y += w1 * bhi(v1.x); a.z += w1 * blo(v1.y); a.w += w1 * bhi(v1.y);
        a.x += w2 * blo(v2.x); a.y += w2 * bhi(v2.x); a.z += w2 * blo(v2.y); a.w += w2 * bhi(v2.y);
        a.x += w3 * blo(v3.x); a.y += w3 * bhi(v3.x); a.z += w3 * blo(v3.y); a.w += w3 * bhi(v3.y);
        c.x += w0 * blo(p0.x); c.y += w0 * bhi(p0.x); c.z += w0 * blo(p0.y); c.w += w0 * bhi(p0.y);
        c.x += w1 * blo(p1.x); c.y += w1 * bhi(p1.x); c.z += w1 * blo(p1.y); c.w += w1 * bhi(p1.y);
        c.x += w2 * blo(p2.x); c.y += w2 * bhi(p2.x); c.z += w2 * blo(p2.y); c.w += w2 * bhi(p2.y);
        c.x += w3 * blo(p3.x); c.y += w3 * bhi(p3.x); c.z += w3 * blo(p3.y); c.w += w3 * bhi(p3.y);
      }
      uint2 o0 = {pk2(a.x, a.y), pk2(a.z, a.w)};
      *reinterpret_cast<uint2*>(&AGG1[((size_t)g0 * LNODES + d) * NCOUT + lc]) = o0;
      uint2 o1 = {pk2(c.x, c.y), pk2(c.z, c.w)};
      *reinterpret_cast<uint2*>(&AGG1[((size_t)(g0 + 16) * LNODES + d) * NCOUT + lc]) = o1;
      s.x += a.x + c.x; s.y += a.y + c.y; s.z += a.z + c.z; s.w += a.w + c.w;
      qq.x += a.x * a.x + c.x * c.x; qq.y += a.y * a.y + c.y * c.y;
      qq.z += a.z * a.z + c.z * c.z; qq.w += a.w * a.w + c.w * c.w;
    }
    sumO = st; sqO = st + 2048; shard = (bid & 7) * NCOUT;
  } else {
    int b2 = bid - 1024;
    int g = b2 & (GSM - 1);
    int chunk = b2 >> 2;
    const int d0 = chunk * ND;
    const u16* base = hw2 + (size_t)g * LNODES * NCOUT;
    for (int i = wv; i < ND; i += 4) {
      int d = d0 + i;
      int e0 = rp[d], e1 = rp[d + 1];
      float sw = selfn[d];
      uint2 u = *reinterpret_cast<const uint2*>(&base[(size_t)d * NCOUT + lc]);
      float4 a = {sw * blo(u.x), sw * bhi(u.x), sw * blo(u.y), sw * bhi(u.y)};
      for (int e = e0; e < e1; e += 4) {
        int i0 = col[e + 0], i1 = col[e + 1], i2 = col[e + 2], i3 = col[e + 3];
        float w0 = wn[e + 0];
        float w1 = (e + 1 < e1) ? wn[e + 1] : 0.f;
        float w2 = (e + 2 < e1) ? wn[e + 2] : 0.f;
        float w3 = (e + 3 < e1) ? wn[e + 3] : 0.f;
        uint2 v0 = *reinterpret_cast<const uint2*>(&base[(size_t)i0 * NCOUT + lc]);
        uint2 v1 = *reinterpret_cast<const uint2*>(&base[(size_t)i1 * NCOUT + lc]);
        uint2 v2 = *reinterpret_cast<const uint2*>(&base[(size_t)i2 * NCOUT + lc]);
        uint2 v3 = *reinterpret_cast<const uint2*>(&base[(size_t)i3 * NCOUT + lc]);
        a.x += w0 * blo(v0.x); a.y += w0 * bhi(v0.x); a.z += w0 * blo(v0.y); a.w += w0 * bhi(v0.y);
        a.x += w1 * blo(v1.x); a.y += w1 * bhi(v1.x); a.z += w1 * blo(v1.y); a.w += w1 * bhi(v1.y);
        a.x += w2 * blo(v2.x); a.y += w2 * bhi(v2.x); a.z += w2 * blo(v2.y); a.w += w2 * bhi(v2.y);
        a.x += w3 * blo(v3.x); a.y += w3 * bhi(v3.x); a.z += w3 * blo(v3.y); a.w += w3 * bhi(v3.y);
      }
      uint2 o = {pk2(a.x, a.y), pk2(a.z, a.w)};
      *reinterpret_cast<uint2*>(&agg2[((size_t)g * LNODES + d) * NCOUT + lc]) = o;
      s.x += a.x; s.y += a.y; s.z += a.z; s.w += a.w;
      qq.x += a.x * a.x; qq.y += a.y * a.y; qq.z += a.z * a.z; qq.w += a.w * a.w;
    }
    sumO = st + 4096; sqO = st + 6144; shard = (b2 & 7) * NCOUT;
  }
  *reinterpret_cast<float4*>(&lsum[wv][lc]) = s;
  *reinterpret_cast<float4*>(&lsq[wv][lc]) = qq;
  __syncthreads();
  float ts = lsum[0][t] + lsum[1][t] + lsum[2][t] + lsum[3][t];
  float tq = lsq[0][t] + lsq[1][t] + lsq[2][t] + lsq[3][t];
  atomicAdd(&sumO[shard + t], ts);
  atomicAdd(&sqO[shard + t], tq);
}

// ---------------- layer 2: fuse + transpose to channel-major fp32 d_out ----------------
__global__ __launch_bounds__(256) void fuse_tr_bf_k(const u16* __restrict__ A1,
                                                    const u16* __restrict__ A2,
                                                    const float* __restrict__ st,
                                                    const float* __restrict__ ga,
                                                    const float* __restrict__ be,
                                                    const float* __restrict__ gs,
                                                    const float* __restrict__ bes,
                                                    float* __restrict__ O) {
  __shared__ float T[64][65];  // [node_local][co_local]
  __shared__ float lk1[NCOUT], lk2[NCOUT], lcc[NCOUT];
  const int g = blockIdx.z;
  const int d0 = blockIdx.x * 64;
  const int c0 = blockIdx.y * 64;
  const int b = g >> 3;
  const int t = threadIdx.x;
  coef_ld(st, ga, be, gs, bes, lk1, lk2, lcc, t);
  __syncthreads();
  const int tr = t >> 4;
  const int tc = (t & 15) * 4;
#pragma unroll
  for (int p = 0; p < 4; ++p) {
    int d = d0 + tr + p * 16;
    uint2 a1 = *reinterpret_cast<const uint2*>(&A1[((size_t)g * LNODES + d) * NCOUT + c0 + tc]);
    uint2 a2 = *reinterpret_cast<const uint2*>(&A2[((size_t)b * LNODES + d) * NCOUT + c0 + tc]);
    int cb = c0 + tc;
    T[tr + p * 16][tc + 0] = fmaxf(lk1[cb+0] * blo(a1.x) + lk2[cb+0] * blo(a2.x) + lcc[cb+0], 0.f);
    T[tr + p * 16][tc + 1] = fmaxf(lk1[cb+1] * bhi(a1.x) + lk2[cb+1] * bhi(a2.x) + lcc[cb+1], 0.f);
    T[tr + p * 16][tc + 2] = fmaxf(lk1[cb+2] * blo(a1.y) + lk2[cb+2] * blo(a2.y) + lcc[cb+2], 0.f);
    T[tr + p * 16][tc + 3] = fmaxf(lk1[cb+3] * bhi(a1.y) + lk2[cb+3] * bhi(a2.y) + lcc[cb+3], 0.f);
  }
  __syncthreads();
#pragma unroll
  for (int p = 0; p < 4; ++p) {
    int c = tr + p * 16;
    float4 o = {T[tc + 0][c], T[tc + 1][c], T[tc + 2][c], T[tc + 3][c]};
    *reinterpret_cast<float4*>(&O[((size_t)g * NCOUT + c0 + c) * LNODES + d0 + tc]) = o;
  }
}

// ---------------- launch ----------------

extern "C" void kernel_launch(void* const* d_in, const int* in_sizes, int n_in,
                              void* d_out, int out_size, void* d_ws, size_t ws_size,
                              hipStream_t stream) {
  const float* x_in = (const float*)d_in[0];
  const int* ei = (const int*)d_in[1];
  const float* W[3]   = {(const float*)d_in[2],  (const float*)d_in[4],  (const float*)d_in[6]};
  const float* Wsym[3]= {(const float*)d_in[8],  (const float*)d_in[10], (const float*)d_in[12]};
  const float* ga[3]  = {(const float*)d_in[14], (const float*)d_in[16], (const float*)d_in[18]};
  const float* be[3]  = {(const float*)d_in[15], (const float*)d_in[17], (const float*)d_in[19]};
  const float* gs[3]  = {(const float*)d_in[20], (const float*)d_in[22], (const float*)d_in[24]};
  const float* bes[3] = {(const float*)d_in[21], (const float*)d_in[23], (const float*)d_in[25]};

  const size_t EBIG = (size_t)GBIG * LNODES * NCOUT;  // 16.7M elems
  const size_t ESM = (size_t)GSM * LNODES * NCOUT;
  char* p = (char*)d_ws;
  u16* XT0  = (u16*)p; p += (size_t)GBIG * LNODES * 128 * 2;  // 16 MiB layer-0 input
  u16* AGG1 = (u16*)p; p += EBIG * 2;   // 32 MiB
  u16* agg2 = (u16*)p; p += ESM * 2;    // 4 MiB
  u16* xp   = (u16*)p; p += (size_t)GSM * LNODES * 128 * 2;   // 2 MiB (layer-0 only)
  u16* hw2  = (u16*)p; p += ESM * 2;    // 4 MiB
  u16* WbT[3], *WsT[3];
  for (int i = 0; i < 3; ++i) { WbT[i] = (u16*)p; p += NCOUT * NCOUT * 2; }
  for (int i = 0; i < 3; ++i) { WsT[i] = (u16*)p; p += NCOUT * NCOUT * 2; }
  int*   rp   = (int*)p;   p += 2064 * 4;
  float* dis  = (float*)p; p += LNODES * 4;
  float* selfn= (float*)p; p += LNODES * 4;
  char* zbase = p;
  float* deg  = (float*)p; p += LNODES * 4;
  int*   cnt  = (int*)p;   p += LNODES * 4;
  int*   fillc= (int*)p;   p += LNODES * 4;
  int*   col  = (int*)p;   p += (NEDGE + 8) * 4;  // padded, zeroed
  float* wn   = (float*)p; p += (NEDGE + 8) * 4;  // padded, zeroed
  float* stats= (float*)p; p += 3 * 4 * 2048 * 4; // [3 layers][sum1|sq1|sum2|sq2][8][256]
  size_t zsize = (size_t)(p - zbase);

  u16* HW1 = (u16*)d_out;  // big GEMM out in d_out (dead by fuse_tr time)
  float* stL[3] = {stats, stats + 8192, stats + 16384};

  // ---- setup: CSR + weights + input transpose + layer-0 pool ----
  hipMemsetAsync(zbase, 0, zsize, stream);
  count_deg_k<<<NEDGE / 256, 256, 0, stream>>>(ei, deg, cnt);
  dis_k<<<LNODES / 256, 256, 0, stream>>>(deg, dis, selfn);
  scan_k<<<1, 256, 0, stream>>>(cnt, rp);
  fill_k<<<NEDGE / 256, 256, 0, stream>>>(ei, rp, fillc, dis, col, wn);
  WCvt wc;
  for (int i = 0; i < 3; ++i) {
    wc.src[i] = W[i];     wc.dst[i] = WbT[i];     wc.ci[i] = (i == 0) ? 128 : 256;
    wc.src[3 + i] = Wsym[i]; wc.dst[3 + i] = WsT[i]; wc.ci[3 + i] = (i == 0) ? 128 : 256;
  }
  cvtw_all_k<<<dim3(4, 4, 6), 256, 0, stream>>>(wc);
  trans_k<<<dim3(LNODES / 64, 128 / 64, GBIG), 256, 0, stream>>>(x_in, XT0, 128);
  pool_bf_k<<<GSM * 128 * LNODES / 8 / 256, 256, 0, stream>>>(XT0, xp, 128 * LNODES);

  dim3 ggrid(LNODES / 128, NCOUT / 128, GBIG + GSM);
  for (int l = 0; l < 3; ++l) {
    if (l == 0) {
      gemm_all_k<0><<<ggrid, 256, 0, stream>>>(XT0, xp, AGG1, agg2, nullptr,
                                               nullptr, nullptr, nullptr, nullptr,
                                               WbT[l], WsT[l], HW1, hw2, 128);
    } else {
      gemm_all_k<1><<<ggrid, 256, 0, stream>>>(XT0, xp, AGG1, agg2, stL[l - 1],
                                               ga[l - 1], be[l - 1], gs[l - 1], bes[l - 1],
                                               WbT[l], WsT[l], HW1, hw2, NCOUT);
    }
    agg_comb_k<<<1280, 256, 0, stream>>>(HW1, hw2, col, wn, rp, selfn,
                                         AGG1, agg2, stL[l]);
  }
  fuse_tr_bf_k<<<dim3(LNODES / 64, NCOUT / 64, GBIG), 256, 0, stream>>>(
      AGG1, agg2, stL[2], ga[2], be[2], gs[2], bes[2], (float*)d_out);
}

// Round 11
// 351.008 us; speedup vs baseline: 6.3149x; 1.0465x over previous
//
#include <hip/hip_runtime.h>
#include <math.h>

#define LNODES 2048
#define NEDGE 16384
#define GBIG 32
#define GSM 4
#define NCOUT 256
#define BN_EPS 1e-5f
#define ND 32  // dst nodes per agg block

typedef unsigned short u16;
typedef __attribute__((ext_vector_type(8))) short bf16x8;
typedef __attribute__((ext_vector_type(4))) float f32x4;

__device__ __forceinline__ unsigned pk2(float a, float b) {  // a->lo, b->hi
  unsigned ua = __float_as_uint(a); ua += 0x7fffu + ((ua >> 16) & 1u);
  unsigned ub = __float_as_uint(b); ub += 0x7fffu + ((ub >> 16) & 1u);
  return (ua >> 16) | (ub & 0xffff0000u);
}
__device__ __forceinline__ float blo(unsigned u) { return __uint_as_float(u << 16); }
__device__ __forceinline__ float bhi(unsigned u) { return __uint_as_float(u & 0xffff0000u); }

// ---------------- setup: degree, dis, CSR ----------------

__global__ __launch_bounds__(256) void count_deg_k(const int* __restrict__ ei,
                                                   float* __restrict__ deg,
                                                   int* __restrict__ cnt) {
  int e = blockIdx.x * 256 + threadIdx.x;
  if (e < NEDGE) {
    int d = ei[NEDGE + e];
    atomicAdd(&deg[d], 1.0f);
    atomicAdd(&cnt[d], 1);
  }
}

__global__ __launch_bounds__(256) void dis_k(const float* __restrict__ deg,
                                             float* __restrict__ dis,
                                             float* __restrict__ selfn) {
  int i = blockIdx.x * 256 + threadIdx.x;
  if (i < LNODES) {
    float di = rsqrtf(deg[i] + 2.0f);  // improved=True self loop weight 2
    dis[i] = di;
    selfn[i] = 2.0f * di * di;
  }
}

__global__ __launch_bounds__(256) void scan_k(const int* __restrict__ cnt,
                                              int* __restrict__ rp) {
  __shared__ int part[256];
  int t = threadIdx.x;
  int base = t * 8;
  int loc[8];
  int s = 0;
#pragma unroll
  for (int j = 0; j < 8; ++j) { loc[j] = s; s += cnt[base + j]; }
  part[t] = s;
  __syncthreads();
  for (int off = 1; off < 256; off <<= 1) {
    int v = (t >= off) ? part[t - off] : 0;
    __syncthreads();
    part[t] += v;
    __syncthreads();
  }
  int excl = (t == 0) ? 0 : part[t - 1];
#pragma unroll
  for (int j = 0; j < 8; ++j) rp[base + j] = excl + loc[j];
  if (t == 255) rp[LNODES] = part[255];
}

__global__ __launch_bounds__(256) void fill_k(const int* __restrict__ ei,
                                              const int* __restrict__ rp,
                                              int* __restrict__ fillc,
                                              const float* __restrict__ dis,
                                              int* __restrict__ col,
                                              float* __restrict__ wn) {
  int e = blockIdx.x * 256 + threadIdx.x;
  if (e < NEDGE) {
    int s = ei[e], d = ei[NEDGE + e];
    int pos = rp[d] + atomicAdd(&fillc[d], 1);
    col[pos] = s;
    wn[pos] = dis[s] * dis[d];
  }
}

// ---------------- x [G][Cin][L] f32 -> XT [G][L][Cin] bf16 ----------------
__global__ __launch_bounds__(256) void trans_k(const float* __restrict__ X,
                                               u16* __restrict__ XT, int Cin) {
  __shared__ float T[64][65];  // [ci_local][node_local]
  const int g = blockIdx.z;
  const int n0 = blockIdx.x * 64;
  const int c0 = blockIdx.y * 64;
  const int tr = threadIdx.x >> 4;
  const int tc = (threadIdx.x & 15) * 4;
#pragma unroll
  for (int p = 0; p < 4; ++p) {
    int ci = c0 + tr + p * 16;
    float4 v = *reinterpret_cast<const float4*>(&X[((size_t)g * Cin + ci) * LNODES + n0 + tc]);
    T[tr + p * 16][tc + 0] = v.x; T[tr + p * 16][tc + 1] = v.y;
    T[tr + p * 16][tc + 2] = v.z; T[tr + p * 16][tc + 3] = v.w;
  }
  __syncthreads();
#pragma unroll
  for (int p = 0; p < 4; ++p) {
    int nd = tr + p * 16;
    uint2 o = {pk2(T[tc + 0][nd], T[tc + 1][nd]), pk2(T[tc + 2][nd], T[tc + 3][nd])};
    *reinterpret_cast<uint2*>(&XT[((size_t)g * LNODES + n0 + nd) * Cin + c0 + tc]) = o;
  }
}

// ---------------- all 6 weights: W [Ci][256] f32 -> WT [256][Ci] bf16, one launch ----------------
struct WCvt {
  const float* src[6];
  u16* dst[6];
  int ci[6];
};
__global__ __launch_bounds__(256) void cvtw_all_k(WCvt wp) {
  __shared__ float T[64][65];
  const int w = blockIdx.z;
  const int Ci = wp.ci[w];
  const int ci0 = blockIdx.y * 64;
  if (ci0 >= Ci) return;
  const float* W = wp.src[w];
  u16* WT = wp.dst[w];
  const int co0 = blockIdx.x * 64;
  const int tr = threadIdx.x >> 4;
  const int tc = (threadIdx.x & 15) * 4;
#pragma unroll
  for (int p = 0; p < 4; ++p) {
    int ci = ci0 + tr + p * 16;
    float4 v = *reinterpret_cast<const float4*>(&W[(size_t)ci * NCOUT + co0 + tc]);
    T[tr + p * 16][tc + 0] = v.x; T[tr + p * 16][tc + 1] = v.y;
    T[tr + p * 16][tc + 2] = v.z; T[tr + p * 16][tc + 3] = v.w;
  }
  __syncthreads();
#pragma unroll
  for (int p = 0; p < 4; ++p) {
    int co = tr + p * 16;
    uint2 o = {pk2(T[tc + 0][co], T[tc + 1][co]), pk2(T[tc + 2][co], T[tc + 3][co])};
    *reinterpret_cast<uint2*>(&WT[(size_t)(co0 + co) * Ci + ci0 + tc]) = o;
  }
}

// ---------------- layer-0 max-pool over N=8 (raw bf16 input) ----------------
__global__ __launch_bounds__(256) void pool_bf_k(const u16* __restrict__ X,
                                                 u16* __restrict__ XP, int per) {
  int i = blockIdx.x * 256 + threadIdx.x;
  size_t f = (size_t)i * 8;
  int b = (int)(f / per);
  size_t rem = f - (size_t)b * per;
  const u16* base = X + (size_t)b * 8 * per + rem;
  uint4 u = *reinterpret_cast<const uint4*>(base);
  float m0 = blo(u.x), m1 = bhi(u.x), m2 = blo(u.y), m3 = bhi(u.y);
  float m4 = blo(u.z), m5 = bhi(u.z), m6 = blo(u.w), m7 = bhi(u.w);
#pragma unroll
  for (int j = 1; j < 8; ++j) {
    uint4 v = *reinterpret_cast<const uint4*>(base + (size_t)j * per);
    m0 = fmaxf(m0, blo(v.x)); m1 = fmaxf(m1, bhi(v.x));
    m2 = fmaxf(m2, blo(v.y)); m3 = fmaxf(m3, bhi(v.y));
    m4 = fmaxf(m4, blo(v.z)); m5 = fmaxf(m5, bhi(v.z));
    m6 = fmaxf(m6, blo(v.w)); m7 = fmaxf(m7, bhi(v.w));
  }
  uint4 o = {pk2(m0, m1), pk2(m2, m3), pk2(m4, m5), pk2(m6, m7)};
  *reinterpret_cast<uint4*>(XP + (size_t)b * per + rem) = o;
}

// ---------------- coef reduction helper: shards -> LDS k1/k2/cc ----------------
// st layout per layer: sum1[8][256] | sq1 | sum2 | sq2 (floats, 8192 total)
__device__ __forceinline__ void coef_ld(const float* __restrict__ st,
                                        const float* __restrict__ ga,
                                        const float* __restrict__ be,
                                        const float* __restrict__ gs,
                                        const float* __restrict__ bes,
                                        float* lk1, float* lk2, float* lcc, int t) {
  float sA = 0.f, qA = 0.f, sB = 0.f, qB = 0.f;
#pragma unroll
  for (int x = 0; x < 8; ++x) {
    sA += st[x * NCOUT + t];
    qA += st[2048 + x * NCOUT + t];
    sB += st[4096 + x * NCOUT + t];
    qB += st[6144 + x * NCOUT + t];
  }
  const float c1 = (float)(GBIG * LNODES), c2 = (float)(GSM * LNODES);
  float mA = sA / c1;
  float vA = qA / c1 - mA * mA;
  float kA = ga[t] * rsqrtf(vA + BN_EPS);
  float mB = sB / c2;
  float vB = qB / c2 - mB * mB;
  float kB = gs[t] * rsqrtf(vB + BN_EPS);
  lk1[t] = kA;
  lk2[t] = kB;
  lcc[t] = be[t] - kA * mA + bes[t] - kB * mB;
}

// ---------------- bf16 MFMA GEMM, combined sym+big, fused BN(+pool) staging ----------------
template <int MODE>
__global__ __launch_bounds__(256) void gemm_all_k(const u16* __restrict__ Xbig,
                                                  const u16* __restrict__ xp,
                                                  const u16* __restrict__ AGG1,
                                                  const u16* __restrict__ agg2,
                                                  const float* __restrict__ st,
                                                  const float* __restrict__ ga,
                                                  const float* __restrict__ be,
                                                  const float* __restrict__ gs,
                                                  const float* __restrict__ bes,
                                                  const u16* __restrict__ WbT,
                                                  const u16* __restrict__ WsT,
                                                  u16* __restrict__ HW1,
                                                  u16* __restrict__ hw2,
                                                  int Cin) {
  __shared__ u16 smem[17408];      // K-loop: 2x[128][40]; epilogue [128][136]
  __shared__ float lk1[NCOUT], lk2[NCOUT], lcc[NCOUT];
  u16* Wsh = smem;
  u16* Xsh = smem + 128 * 40;
  const int z = blockIdx.z;
  const bool sym = z < GSM;
  const int g = sym ? z : z - GSM;
  const u16* Wmat = sym ? WsT : WbT;
  u16* out = sym ? hw2 : HW1;
  const int n0 = blockIdx.x * 128;
  const int c0 = blockIdx.y * 128;
  const int t = threadIdx.x;
  if (MODE == 1) {
    coef_ld(st, ga, be, gs, bes, lk1, lk2, lcc, t);
    __syncthreads();
  }
  const int wv = t >> 6;
  const int lane = t & 63;
  const int q = lane >> 4, l = lane & 15;
  const int wm = wv >> 1, wn = wv & 1;
  f32x4 zero = {0.f, 0.f, 0.f, 0.f};
  f32x4 acc[4][4];
#pragma unroll
  for (int i = 0; i < 4; ++i)
#pragma unroll
    for (int j = 0; j < 4; ++j) acc[i][j] = zero;
  const int r0 = t >> 2;
  const int seg = (t & 3) * 8;
  const u16* Wg = Wmat + (size_t)(c0 + r0) * Cin + seg;
  const u16* Xplain = sym ? xp : Xbig;
  const u16* Xg = Xplain + ((size_t)g * LNODES + n0 + r0) * Cin + seg;
  const size_t rowd = (size_t)(n0 + r0);
  const size_t nstep = (size_t)LNODES * NCOUT;
  const size_t a1base = sym ? (((size_t)(g * 8) * LNODES + rowd) * NCOUT + seg)
                            : (((size_t)g * LNODES + rowd) * NCOUT + seg);
  const size_t a2base = sym ? (((size_t)g * LNODES + rowd) * NCOUT + seg)
                            : (((size_t)(g >> 3) * LNODES + rowd) * NCOUT + seg);
  for (int k0 = 0; k0 < Cin; k0 += 32) {
    uint4 w0 = *reinterpret_cast<const uint4*>(Wg + k0);
    uint4 w1 = *reinterpret_cast<const uint4*>(Wg + (size_t)64 * Cin + k0);
    uint4 x0, x1;
    if (MODE == 0) {
      x0 = *reinterpret_cast<const uint4*>(Xg + k0);
      x1 = *reinterpret_cast<const uint4*>(Xg + (size_t)64 * Cin + k0);
    } else {
      int kk = k0 + seg;
      float K10 = lk1[kk+0], K11 = lk1[kk+1], K12 = lk1[kk+2], K13 = lk1[kk+3];
      float K14 = lk1[kk+4], K15 = lk1[kk+5], K16 = lk1[kk+6], K17 = lk1[kk+7];
      if (!sym) {
        uint4 a1a = *reinterpret_cast<const uint4*>(&AGG1[a1base + k0]);
        uint4 a1b = *reinterpret_cast<const uint4*>(&AGG1[a1base + 64 * (size_t)NCOUT + k0]);
        uint4 a2a = *reinterpret_cast<const uint4*>(&agg2[a2base + k0]);
        uint4 a2b = *reinterpret_cast<const uint4*>(&agg2[a2base + 64 * (size_t)NCOUT + k0]);
        float o0 = fmaxf(K10*blo(a1a.x) + lk2[kk+0]*blo(a2a.x) + lcc[kk+0], 0.f);
        float o1 = fmaxf(K11*bhi(a1a.x) + lk2[kk+1]*bhi(a2a.x) + lcc[kk+1], 0.f);
        float o2 = fmaxf(K12*blo(a1a.y) + lk2[kk+2]*blo(a2a.y) + lcc[kk+2], 0.f);
        float o3 = fmaxf(K13*bhi(a1a.y) + lk2[kk+3]*bhi(a2a.y) + lcc[kk+3], 0.f);
        float o4 = fmaxf(K14*blo(a1a.z) + lk2[kk+4]*blo(a2a.z) + lcc[kk+4], 0.f);
        float o5 = fmaxf(K15*bhi(a1a.z) + lk2[kk+5]*bhi(a2a.z) + lcc[kk+5], 0.f);
        float o6 = fmaxf(K16*blo(a1a.w) + lk2[kk+6]*blo(a2a.w) + lcc[kk+6], 0.f);
        float o7 = fmaxf(K17*bhi(a1a.w) + lk2[kk+7]*bhi(a2a.w) + lcc[kk+7], 0.f);
        x0 = {pk2(o0, o1), pk2(o2, o3), pk2(o4, o5), pk2(o6, o7)};
        float p0 = fmaxf(K10*blo(a1b.x) + lk2[kk+0]*blo(a2b.x) + lcc[kk+0], 0.f);
        float p1 = fmaxf(K11*bhi(a1b.x) + lk2[kk+1]*bhi(a2b.x) + lcc[kk+1], 0.f);
        float p2 = fmaxf(K12*blo(a1b.y) + lk2[kk+2]*blo(a2b.y) + lcc[kk+2], 0.f);
        float p3 = fmaxf(K13*bhi(a1b.y) + lk2[kk+3]*bhi(a2b.y) + lcc[kk+3], 0.f);
        float p4 = fmaxf(K14*blo(a1b.z) + lk2[kk+4]*blo(a2b.z) + lcc[kk+4], 0.f);
        float p5 = fmaxf(K15*bhi(a1b.z) + lk2[kk+5]*bhi(a2b.z) + lcc[kk+5], 0.f);
        float p6 = fmaxf(K16*blo(a1b.w) + lk2[kk+6]*blo(a2b.w) + lcc[kk+6], 0.f);
        float p7 = fmaxf(K17*bhi(a1b.w) + lk2[kk+7]*bhi(a2b.w) + lcc[kk+7], 0.f);
        x1 = {pk2(p0, p1), pk2(p2, p3), pk2(p4, p5), pk2(p6, p7)};
      } else {
        // sym: pooled A = max(0, max_n(k1*a1_n + (k2*a2 + cc)))
        uint4 a2a = *reinterpret_cast<const uint4*>(&agg2[a2base + k0]);
        uint4 a2b = *reinterpret_cast<const uint4*>(&agg2[a2base + 64 * (size_t)NCOUT + k0]);
        float t0 = lk2[kk+0]*blo(a2a.x) + lcc[kk+0], t1 = lk2[kk+1]*bhi(a2a.x) + lcc[kk+1];
        float t2 = lk2[kk+2]*blo(a2a.y) + lcc[kk+2], t3 = lk2[kk+3]*bhi(a2a.y) + lcc[kk+3];
        float t4 = lk2[kk+4]*blo(a2a.z) + lcc[kk+4], t5 = lk2[kk+5]*bhi(a2a.z) + lcc[kk+5];
        float t6 = lk2[kk+6]*blo(a2a.w) + lcc[kk+6], t7 = lk2[kk+7]*bhi(a2a.w) + lcc[kk+7];
        float u0 = lk2[kk+0]*blo(a2b.x) + lcc[kk+0], u1 = lk2[kk+1]*bhi(a2b.x) + lcc[kk+1];
        float u2 = lk2[kk+2]*blo(a2b.y) + lcc[kk+2], u3 = lk2[kk+3]*bhi(a2b.y) + lcc[kk+3];
        float u4 = lk2[kk+4]*blo(a2b.z) + lcc[kk+4], u5 = lk2[kk+5]*bhi(a2b.z) + lcc[kk+5];
        float u6 = lk2[kk+6]*blo(a2b.w) + lcc[kk+6], u7 = lk2[kk+7]*bhi(a2b.w) + lcc[kk+7];
        float m0 = 0.f, m1 = 0.f, m2 = 0.f, m3 = 0.f, m4 = 0.f, m5 = 0.f, m6 = 0.f, m7 = 0.f;
        float e0 = 0.f, e1 = 0.f, e2 = 0.f, e3 = 0.f, e4 = 0.f, e5 = 0.f, e6 = 0.f, e7 = 0.f;
#pragma unroll
        for (int n = 0; n < 8; ++n) {
          uint4 a1a = *reinterpret_cast<const uint4*>(&AGG1[a1base + n * nstep + k0]);
          uint4 a1b = *reinterpret_cast<const uint4*>(&AGG1[a1base + n * nstep + 64 * (size_t)NCOUT + k0]);
          m0 = fmaxf(m0, K10*blo(a1a.x) + t0); m1 = fmaxf(m1, K11*bhi(a1a.x) + t1);
          m2 = fmaxf(m2, K12*blo(a1a.y) + t2); m3 = fmaxf(m3, K13*bhi(a1a.y) + t3);
          m4 = fmaxf(m4, K14*blo(a1a.z) + t4); m5 = fmaxf(m5, K15*bhi(a1a.z) + t5);
          m6 = fmaxf(m6, K16*blo(a1a.w) + t6); m7 = fmaxf(m7, K17*bhi(a1a.w) + t7);
          e0 = fmaxf(e0, K10*blo(a1b.x) + u0); e1 = fmaxf(e1, K11*bhi(a1b.x) + u1);
          e2 = fmaxf(e2, K12*blo(a1b.y) + u2); e3 = fmaxf(e3, K13*bhi(a1b.y) + u3);
          e4 = fmaxf(e4, K14*blo(a1b.z) + u4); e5 = fmaxf(e5, K15*bhi(a1b.z) + u5);
          e6 = fmaxf(e6, K16*blo(a1b.w) + u6); e7 = fmaxf(e7, K17*bhi(a1b.w) + u7);
        }
        x0 = {pk2(m0, m1), pk2(m2, m3), pk2(m4, m5), pk2(m6, m7)};
        x1 = {pk2(e0, e1), pk2(e2, e3), pk2(e4, e5), pk2(e6, e7)};
      }
    }
    __syncthreads();
    *reinterpret_cast<uint4*>(&Wsh[r0 * 40 + seg]) = w0;
    *reinterpret_cast<uint4*>(&Wsh[(r0 + 64) * 40 + seg]) = w1;
    *reinterpret_cast<uint4*>(&Xsh[r0 * 40 + seg]) = x0;
    *reinterpret_cast<uint4*>(&Xsh[(r0 + 64) * 40 + seg]) = x1;
    __syncthreads();
    bf16x8 af[4], bx[4];
#pragma unroll
    for (int fi = 0; fi < 4; ++fi)
      af[fi] = *reinterpret_cast<const bf16x8*>(&Wsh[(wm * 64 + fi * 16 + l) * 40 + q * 8]);
#pragma unroll
    for (int fj = 0; fj < 4; ++fj)
      bx[fj] = *reinterpret_cast<const bf16x8*>(&Xsh[(wn * 64 + fj * 16 + l) * 40 + q * 8]);
#pragma unroll
    for (int fi = 0; fi < 4; ++fi)
#pragma unroll
      for (int fj = 0; fj < 4; ++fj)
        acc[fi][fj] = __builtin_amdgcn_mfma_f32_16x16x32_bf16(af[fi], bx[fj], acc[fi][fj], 0, 0, 0);
  }
  __syncthreads();
  u16* Csh = smem;  // [128][136]
#pragma unroll
  for (int fi = 0; fi < 4; ++fi) {
#pragma unroll
    for (int fj = 0; fj < 4; ++fj) {
      int co_l = wm * 64 + fi * 16 + q * 4;
      int nd_l = wn * 64 + fj * 16 + l;
      uint2 pkd = {pk2(acc[fi][fj][0], acc[fi][fj][1]),
                   pk2(acc[fi][fj][2], acc[fi][fj][3])};
      *reinterpret_cast<uint2*>(&Csh[nd_l * 136 + co_l]) = pkd;
    }
  }
  __syncthreads();
#pragma unroll
  for (int p = 0; p < 8; ++p) {
    int idx = p * 256 + t;
    int nd = idx >> 4;
    int c8 = (idx & 15) * 8;
    uint4 v = *reinterpret_cast<const uint4*>(&Csh[nd * 136 + c8]);
    *reinterpret_cast<uint4*>(&out[((size_t)g * LNODES + n0 + nd) * NCOUT + c0 + c8]) = v;
  }
}

// ---------------- combined aggregation ----------------
// Big path (1024 blocks): HALF-WAVE G-SPLIT — lanes 0-31 handle g0, lanes 32-63
// handle g0+16 (same XCD). Lane = 8 channels (uint4): one dwordx4 gather per
// edge serves BOTH graph copies -> 4 gather insts per x4-iter (was 8).
// Exact remainder loop (predicated pads wasted ~20% gather traffic in R9).
// Sym path (256 blocks): unchanged uint2 layout.
__global__ __launch_bounds__(256) void agg_comb_k(const u16* __restrict__ HW1,
                                                  const u16* __restrict__ hw2,
                                                  const int* __restrict__ col,
                                                  const float* __restrict__ wn,
                                                  const int* __restrict__ rp,
                                                  const float* __restrict__ selfn,
                                                  u16* __restrict__ AGG1,
                                                  u16* __restrict__ agg2,
                                                  float* __restrict__ st) {
  __shared__ float lsum[8][NCOUT], lsq[8][NCOUT];
  const int bid = blockIdx.x;
  const int t = threadIdx.x;
  const int wv = t >> 6;
  float* sumO;
  float* sqO;
  int shard;
  if (bid < 1024) {
    int slot = bid >> 3;
    int chunk = slot & 63;
    int g0 = (bid & 7) + 8 * (slot >> 6);
    const int d0 = chunk * ND;
    const int h = (t >> 5) & 1;   // half-wave: which graph copy
    const int ch = (t & 31) * 8;  // channel octet
    const u16* baseh = HW1 + (size_t)(g0 + 16 * h) * LNODES * NCOUT;
    u16* outh = AGG1 + (size_t)(g0 + 16 * h) * LNODES * NCOUT;
    float s0 = 0.f, s1 = 0.f, s2 = 0.f, s3 = 0.f, s4 = 0.f, s5 = 0.f, s6 = 0.f, s7 = 0.f;
    float q0 = 0.f, q1 = 0.f, q2 = 0.f, q3 = 0.f, q4 = 0.f, q5 = 0.f, q6 = 0.f, q7 = 0.f;
    for (int i = wv; i < ND; i += 4) {
      int d = d0 + i;
      int e0 = rp[d], e1 = rp[d + 1];
      float sw = selfn[d];
      uint4 u = *reinterpret_cast<const uint4*>(&baseh[(size_t)d * NCOUT + ch]);
      float a0 = sw * blo(u.x), a1 = sw * bhi(u.x), a2 = sw * blo(u.y), a3 = sw * bhi(u.y);
      float a4 = sw * blo(u.z), a5 = sw * bhi(u.z), a6 = sw * blo(u.w), a7 = sw * bhi(u.w);
      int e = e0;
      const int e4 = e0 + ((e1 - e0) & ~3);
      for (; e < e4; e += 4) {
        int i0 = col[e + 0], i1 = col[e + 1], i2 = col[e + 2], i3 = col[e + 3];
        float w0 = wn[e + 0], w1 = wn[e + 1], w2 = wn[e + 2], w3 = wn[e + 3];
        uint4 v0 = *reinterpret_cast<const uint4*>(&baseh[(size_t)i0 * NCOUT + ch]);
        uint4 v1 = *reinterpret_cast<const uint4*>(&baseh[(size_t)i1 * NCOUT + ch]);
        uint4 v2 = *reinterpret_cast<const uint4*>(&baseh[(size_t)i2 * NCOUT + ch]);
        uint4 v3 = *reinterpret_cast<const uint4*>(&baseh[(size_t)i3 * NCOUT + ch]);
        a0 += w0 * blo(v0.x); a1 += w0 * bhi(v0.x); a2 += w0 * blo(v0.y); a3 += w0 * bhi(v0.y);
        a4 += w0 * blo(v0.z); a5 += w0 * bhi(v0.z); a6 += w0 * blo(v0.w); a7 += w0 * bhi(v0.w);
        a0 += w1 * blo(v1.x); a1 += w1 * bhi(v1.x); a2 += w1 * blo(v1.y); a3 += w1 * bhi(v1.y);
        a4 += w1 * blo(v1.z); a5 += w1 * bhi(v1.z); a6 += w1 * blo(v1.w); a7 += w1 * bhi(v1.w);
        a0 += w2 * blo(v2.x); a1 += w2 * bhi(v2.x); a2 += w2 * blo(v2.y); a3 += w2 * bhi(v2.y);
        a4 += w2 * blo(v2.z); a5 += w2 * bhi(v2.z); a6 += w2 * blo(v2.w); a7 += w2 * bhi(v2.w);
        a0 += w3 * blo(v3.x); a1 += w3 * bhi(v3.x); a2 += w3 * blo(v3.y); a3 += w3 * bhi(v3.y);
        a4 += w3 * blo(v3.z); a5 += w3 * bhi(v3.z); a6 += w3 * blo(v3.w); a7 += w3 * bhi(v3.w);
      }
      for (; e < e1; ++e) {
        int ci = col[e];
        float w = wn[e];
        uint4 v = *reinterpret_cast<const uint4*>(&baseh[(size_t)ci * NCOUT + ch]);
        a0 += w * blo(v.x); a1 += w * bhi(v.x); a2 += w * blo(v.y); a3 += w * bhi(v.y);
        a4 += w * blo(v.z); a5 += w * bhi(v.z); a6 += w * blo(v.w); a7 += w * bhi(v.w);
      }
      uint4 o = {pk2(a0, a1), pk2(a2, a3), pk2(a4, a5), pk2(a6, a7)};
      *reinterpret_cast<uint4*>(&outh[(size_t)d * NCOUT + ch]) = o;
      s0 += a0; s1 += a1; s2 += a2; s3 += a3; s4 += a4; s5 += a5; s6 += a6; s7 += a7;
      q0 += a0 * a0; q1 += a1 * a1; q2 += a2 * a2; q3 += a3 * a3;
      q4 += a4 * a4; q5 += a5 * a5; q6 += a6 * a6; q7 += a7 * a7;
    }
    int row = wv * 2 + h;
    float4 sa = {s0, s1, s2, s3}, sb = {s4, s5, s6, s7};
    float4 qa = {q0, q1, q2, q3}, qb = {q4, q5, q6, q7};
    *reinterpret_cast<float4*>(&lsum[row][ch]) = sa;
    *reinterpret_cast<float4*>(&lsum[row][ch + 4]) = sb;
    *reinterpret_cast<float4*>(&lsq[row][ch]) = qa;
    *reinterpret_cast<float4*>(&lsq[row][ch + 4]) = qb;
    sumO = st; sqO = st + 2048; shard = (bid & 7) * NCOUT;
  } else {
    int b2 = bid - 1024;
    int g = b2 & (GSM - 1);
    int chunk = b2 >> 2;
    const int d0 = chunk * ND;
    const int lc = (t & 63) * 4;
    const u16* base = hw2 + (size_t)g * LNODES * NCOUT;
    float4 s = {0.f, 0.f, 0.f, 0.f}, qq = {0.f, 0.f, 0.f, 0.f};
    for (int i = wv; i < ND; i += 4) {
      int d = d0 + i;
      int e0 = rp[d], e1 = rp[d + 1];
      float sw = selfn[d];
      uint2 u = *reinterpret_cast<const uint2*>(&base[(size_t)d * NCOUT + lc]);
      float4 a = {sw * blo(u.x), sw * bhi(u.x), sw * blo(u.y), sw * bhi(u.y)};
      int e = e0;
      const int e4 = e0 + ((e1 - e0) & ~3);
      for (; e < e4; e += 4) {
        int i0 = col[e + 0], i1 = col[e + 1], i2 = col[e + 2], i3 = col[e + 3];
        float w0 = wn[e + 0], w1 = wn[e + 1], w2 = wn[e + 2], w3 = wn[e + 3];
        uint2 v0 = *reinterpret_cast<const uint2*>(&base[(size_t)i0 * NCOUT + lc]);
        uint2 v1 = *reinterpret_cast<const uint2*>(&base[(size_t)i1 * NCOUT + lc]);
        uint2 v2 = *reinterpret_cast<const uint2*>(&base[(size_t)i2 * NCOUT + lc]);
        uint2 v3 = *reinterpret_cast<const uint2*>(&base[(size_t)i3 * NCOUT + lc]);
        a.x += w0 * blo(v0.x); a.y += w0 * bhi(v0.x); a.z += w0 * blo(v0.y); a.w += w0 * bhi(v0.y);
        a.x += w1 * blo(v1.x); a.y += w1 * bhi(v1.x); a.z += w1 * blo(v1.y); a.w += w1 * bhi(v1.y);
        a.x += w2 * blo(v2.x); a.y += w2 * bhi(v2.x); a.z += w2 * blo(v2.y); a.w += w2 * bhi(v2.y);
        a.x += w3 * blo(v3.x); a.y += w3 * bhi(v3.x); a.z += w3 * blo(v3.y); a.w += w3 * bhi(v3.y);
      }
      for (; e < e1; ++e) {
        float w = wn[e];
        uint2 v = *reinterpret_cast<const uint2*>(&base[(size_t)col[e] * NCOUT + lc]);
        a.x += w * blo(v.x); a.y += w * bhi(v.x); a.z += w * blo(v.y); a.w += w * bhi(v.y);
      }
      uint2 o = {pk2(a.x, a.y), pk2(a.z, a.w)};
      *reinterpret_cast<uint2*>(&agg2[((size_t)g * LNODES + d) * NCOUT + lc]) = o;
      s.x += a.x; s.y += a.y; s.z += a.z; s.w += a.w;
      qq.x += a.x * a.x; qq.y += a.y * a.y; qq.z += a.z * a.z; qq.w += a.w * a.w;
    }
    *reinterpret_cast<float4*>(&lsum[wv][lc]) = s;
    *reinterpret_cast<float4*>(&lsq[wv][lc]) = qq;
    float4 z4 = {0.f, 0.f, 0.f, 0.f};
    *reinterpret_cast<float4*>(&lsum[wv + 4][lc]) = z4;
    *reinterpret_cast<float4*>(&lsq[wv + 4][lc]) = z4;
    sumO = st + 4096; sqO = st + 6144; shard = (b2 & 7) * NCOUT;
  }
  __syncthreads();
  float ts = 0.f, tq = 0.f;
#pragma unroll
  for (int r = 0; r < 8; ++r) {
    ts += lsum[r][t];
    tq += lsq[r][t];
  }
  atomicAdd(&sumO[shard + t], ts);
  atomicAdd(&sqO[shard + t], tq);
}

// ---------------- layer 2: fuse + transpose to channel-major fp32 d_out ----------------
__global__ __launch_bounds__(256) void fuse_tr_bf_k(const u16* __restrict__ A1,
                                                    const u16* __restrict__ A2,
                                                    const float* __restrict__ st,
                                                    const float* __restrict__ ga,
                                                    const float* __restrict__ be,
                                                    const float* __restrict__ gs,
                                                    const float* __restrict__ bes,
                                                    float* __restrict__ O) {
  __shared__ float T[64][65];  // [node_local][co_local]
  __shared__ float lk1[NCOUT], lk2[NCOUT], lcc[NCOUT];
  const int g = blockIdx.z;
  const int d0 = blockIdx.x * 64;
  const int c0 = blockIdx.y * 64;
  const int b = g >> 3;
  const int t = threadIdx.x;
  coef_ld(st, ga, be, gs, bes, lk1, lk2, lcc, t);
  __syncthreads();
  const int tr = t >> 4;
  const int tc = (t & 15) * 4;
#pragma unroll
  for (int p = 0; p < 4; ++p) {
    int d = d0 + tr + p * 16;
    uint2 a1 = *reinterpret_cast<const uint2*>(&A1[((size_t)g * LNODES + d) * NCOUT + c0 + tc]);
    uint2 a2 = *reinterpret_cast<const uint2*>(&A2[((size_t)b * LNODES + d) * NCOUT + c0 + tc]);
    int cb = c0 + tc;
    T[tr + p * 16][tc + 0] = fmaxf(lk1[cb+0] * blo(a1.x) + lk2[cb+0] * blo(a2.x) + lcc[cb+0], 0.f);
    T[tr + p * 16][tc + 1] = fmaxf(lk1[cb+1] * bhi(a1.x) + lk2[cb+1] * bhi(a2.x) + lcc[cb+1], 0.f);
    T[tr + p * 16][tc + 2] = fmaxf(lk1[cb+2] * blo(a1.y) + lk2[cb+2] * blo(a2.y) + lcc[cb+2], 0.f);
    T[tr + p * 16][tc + 3] = fmaxf(lk1[cb+3] * bhi(a1.y) + lk2[cb+3] * bhi(a2.y) + lcc[cb+3], 0.f);
  }
  __syncthreads();
#pragma unroll
  for (int p = 0; p < 4; ++p) {
    int c = tr + p * 16;
    float4 o = {T[tc + 0][c], T[tc + 1][c], T[tc + 2][c], T[tc + 3][c]};
    *reinterpret_cast<float4*>(&O[((size_t)g * NCOUT + c0 + c) * LNODES + d0 + tc]) = o;
  }
}

// ---------------- launch ----------------

extern "C" void kernel_launch(void* const* d_in, const int* in_sizes, int n_in,
                              void* d_out, int out_size, void* d_ws, size_t ws_size,
                              hipStream_t stream) {
  const float* x_in = (const float*)d_in[0];
  const int* ei = (const int*)d_in[1];
  const float* W[3]   = {(const float*)d_in[2],  (const float*)d_in[4],  (const float*)d_in[6]};
  const float* Wsym[3]= {(const float*)d_in[8],  (const float*)d_in[10], (const float*)d_in[12]};
  const float* ga[3]  = {(const float*)d_in[14], (const float*)d_in[16], (const float*)d_in[18]};
  const float* be[3]  = {(const float*)d_in[15], (const float*)d_in[17], (const float*)d_in[19]};
  const float* gs[3]  = {(const float*)d_in[20], (const float*)d_in[22], (const float*)d_in[24]};
  const float* bes[3] = {(const float*)d_in[21], (const float*)d_in[23], (const float*)d_in[25]};

  const size_t EBIG = (size_t)GBIG * LNODES * NCOUT;  // 16.7M elems
  const size_t ESM = (size_t)GSM * LNODES * NCOUT;
  char* p = (char*)d_ws;
  u16* XT0  = (u16*)p; p += (size_t)GBIG * LNODES * 128 * 2;  // 16 MiB layer-0 input
  u16* AGG1 = (u16*)p; p += EBIG * 2;   // 32 MiB
  u16* agg2 = (u16*)p; p += ESM * 2;    // 4 MiB
  u16* xp   = (u16*)p; p += (size_t)GSM * LNODES * 128 * 2;   // 2 MiB (layer-0 only)
  u16* hw2  = (u16*)p; p += ESM * 2;    // 4 MiB
  u16* WbT[3], *WsT[3];
  for (int i = 0; i < 3; ++i) { WbT[i] = (u16*)p; p += NCOUT * NCOUT * 2; }
  for (int i = 0; i < 3; ++i) { WsT[i] = (u16*)p; p += NCOUT * NCOUT * 2; }
  int*   rp   = (int*)p;   p += 2064 * 4;
  float* dis  = (float*)p; p += LNODES * 4;
  float* selfn= (float*)p; p += LNODES * 4;
  char* zbase = p;
  float* deg  = (float*)p; p += LNODES * 4;
  int*   cnt  = (int*)p;   p += LNODES * 4;
  int*   fillc= (int*)p;   p += LNODES * 4;
  int*   col  = (int*)p;   p += (NEDGE + 8) * 4;  // padded, zeroed
  float* wn   = (float*)p; p += (NEDGE + 8) * 4;  // padded, zeroed
  float* stats= (float*)p; p += 3 * 4 * 2048 * 4; // [3 layers][sum1|sq1|sum2|sq2][8][256]
  size_t zsize = (size_t)(p - zbase);

  u16* HW1 = (u16*)d_out;  // big GEMM out in d_out (dead by fuse_tr time)
  float* stL[3] = {stats, stats + 8192, stats + 16384};

  // ---- setup: CSR + weights + input transpose + layer-0 pool ----
  hipMemsetAsync(zbase, 0, zsize, stream);
  count_deg_k<<<NEDGE / 256, 256, 0, stream>>>(ei, deg, cnt);
  dis_k<<<LNODES / 256, 256, 0, stream>>>(deg, dis, selfn);
  scan_k<<<1, 256, 0, stream>>>(cnt, rp);
  fill_k<<<NEDGE / 256, 256, 0, stream>>>(ei, rp, fillc, dis, col, wn);
  WCvt wc;
  for (int i = 0; i < 3; ++i) {
    wc.src[i] = W[i];     wc.dst[i] = WbT[i];     wc.ci[i] = (i == 0) ? 128 : 256;
    wc.src[3 + i] = Wsym[i]; wc.dst[3 + i] = WsT[i]; wc.ci[3 + i] = (i == 0) ? 128 : 256;
  }
  cvtw_all_k<<<dim3(4, 4, 6), 256, 0, stream>>>(wc);
  trans_k<<<dim3(LNODES / 64, 128 / 64, GBIG), 256, 0, stream>>>(x_in, XT0, 128);
  pool_bf_k<<<GSM * 128 * LNODES / 8 / 256, 256, 0, stream>>>(XT0, xp, 128 * LNODES);

  dim3 ggrid(LNODES / 128, NCOUT / 128, GBIG + GSM);
  for (int l = 0; l < 3; ++l) {
    if (l == 0) {
      gemm_all_k<0><<<ggrid, 256, 0, stream>>>(XT0, xp, AGG1, agg2, nullptr,
                                               nullptr, nullptr, nullptr, nullptr,
                                               WbT[l], WsT[l], HW1, hw2, 128);
    } else {
      gemm_all_k<1><<<ggrid, 256, 0, stream>>>(XT0, xp, AGG1, agg2, stL[l - 1],
                                               ga[l - 1], be[l - 1], gs[l - 1], bes[l - 1],
                                               WbT[l], WsT[l], HW1, hw2, NCOUT);
    }
    agg_comb_k<<<1280, 256, 0, stream>>>(HW1, hw2, col, wn, rp, selfn,
                                         AGG1, agg2, stL[l]);
  }
  fuse_tr_bf_k<<<dim3(LNODES / 64, NCOUT / 64, GBIG), 256, 0, stream>>>(
      AGG1, agg2, stL[2], ga[2], be[2], gs[2], bes[2], (float*)d_out);
}